// Round 6
// baseline (293.595 us; speedup 1.0000x reference)
//
#include <hip/hip_runtime.h>
#include <hip/hip_bf16.h>

#define B_ 4
#define M_ 5
#define N_ 1000
#define FIN 64
#define H_ 4
#define D_ 64
#define HD 256
#define SH 128
#define OUTD 5
#define NW 16  // u64 words per dest row (1024/64)
#define THRESH_ 0.97f

typedef unsigned short u16;
typedef u16 us8 __attribute__((ext_vector_type(8)));
typedef short s16x8 __attribute__((ext_vector_type(8)));
typedef float f32x4 __attribute__((ext_vector_type(4)));

__device__ inline u16 bf16_bits(float v) {
  __hip_bfloat16 h = __float2bfloat16(v);
  return *reinterpret_cast<u16*>(&h);
}
__device__ inline float bf16_val(u16 b) {
  __hip_bfloat16 h;
  *reinterpret_cast<u16*>(&h) = b;
  return __bfloat162float(h);
}
__device__ inline void split2(float v, u16& h, u16& l) {
  h = bf16_bits(v);
  l = bf16_bits(v - bf16_val(h));
}

// ---------------------------------------------------------------------------
// prep_all: one launch doing (a) bit-packed transposed edge mask build and
// (b) all weight transpose+split jobs, selected by block range.
// Grid layout: [0,5120) mask ; then fc1T(80), fc2T(320), sW1_1T(32), sW1_2T(32).
// ---------------------------------------------------------------------------
__device__ void splitT_body(const float* __restrict__ s, u16* __restrict__ hiT,
                            u16* __restrict__ loT, int K, int N, int k0, int n0,
                            char* smem) {
  float(*tile)[33] = (float(*)[33])smem;
  int tid = threadIdx.x;
  int kl = tid >> 3, nq = (tid & 7) * 4;
  *(float4*)&tile[kl][nq] = *(const float4*)(s + (size_t)(k0 + kl) * N + n0 + nq);
  __syncthreads();
  int nl = tid >> 3, kq = (tid & 7) * 4;
  ushort4 h, l;
  split2(tile[kq + 0][nl], h.x, l.x);
  split2(tile[kq + 1][nl], h.y, l.y);
  split2(tile[kq + 2][nl], h.z, l.z);
  split2(tile[kq + 3][nl], h.w, l.w);
  size_t o = (size_t)(n0 + nl) * K + k0 + kq;
  *(ushort4*)(hiT + o) = h;
  *(ushort4*)(loT + o) = l;
}

__global__ __launch_bounds__(256) void prep_all(
    const float* __restrict__ adj, const int* __restrict__ node_nums,
    unsigned long long* __restrict__ maskW,
    const float* __restrict__ fc1, u16* __restrict__ fc1Th, u16* __restrict__ fc1Tl,
    const float* __restrict__ fc2, u16* __restrict__ fc2Th, u16* __restrict__ fc2Tl,
    const float* __restrict__ sW1_1, u16* __restrict__ sW1Th1, u16* __restrict__ sW1Tl1,
    const float* __restrict__ sW1_2, u16* __restrict__ sW1Th2, u16* __restrict__ sW1Tl2) {
  __shared__ __align__(16) char smem[4608];
  int bi = blockIdx.x;
  int tid = threadIdx.x;
  if (bi < 5120) {
    // ---- edge-mask build ----
    int bx = bi & 15, by = (bi >> 4) & 15, bm = bi >> 8;
    int b = bm / M_;
    int s0 = bx * 64, d0 = by * 64;
    int nn = node_nums[b];
    unsigned char(*tile)[65] = (unsigned char(*)[65])smem;
    const float* arow = adj + (size_t)bm * N_ * N_;
#pragma unroll
    for (int k = 0; k < 16; ++k) {
      int idx = k * 256 + tid;
      int sl = idx >> 6, dl = idx & 63;
      int s = s0 + sl, d = d0 + dl;
      unsigned char v = 0;
      if (s < nn && d < nn && s < N_ && d < N_)
        v = (arow[(size_t)s * N_ + d] > THRESH_) ? 1 : 0;
      tile[sl][dl] = v;
    }
    __syncthreads();
    int w = tid >> 6, lane = tid & 63;
#pragma unroll
    for (int j = 0; j < 16; ++j) {
      int dl = w * 16 + j;
      bool act = tile[lane][dl] != 0;
      unsigned long long word = __ballot(act);
      int d = d0 + dl;
      if (lane == 0 && d < N_)
        maskW[((size_t)bm * N_ + d) * NW + bx] = word;
    }
    return;
  }
  bi -= 5120;
  if (bi < 80) {  // fc1 (M, FIN, HD) -> (M, HD, FIN) hi/lo
    int kx = bi % 2, ny = (bi / 2) % 8, z = bi / 16;
    splitT_body(fc1 + (size_t)z * FIN * HD, fc1Th + (size_t)z * HD * FIN,
                fc1Tl + (size_t)z * HD * FIN, FIN, HD, kx * 32, ny * 32, smem);
    return;
  }
  bi -= 80;
  if (bi < 320) {  // fc2 (M, HD, HD) -> (M, HD, HD)T hi/lo
    int kx = bi % 8, ny = (bi / 8) % 8, z = bi / 64;
    splitT_body(fc2 + (size_t)z * HD * HD, fc2Th + (size_t)z * HD * HD,
                fc2Tl + (size_t)z * HD * HD, HD, HD, kx * 32, ny * 32, smem);
    return;
  }
  bi -= 320;
  if (bi < 32) {  // sW1_1 (HD, SH) -> (SH, HD) hi/lo
    int kx = bi % 8, ny = bi / 8;
    splitT_body(sW1_1, sW1Th1, sW1Tl1, HD, SH, kx * 32, ny * 32, smem);
    return;
  }
  bi -= 32;
  {  // sW1_2
    int kx = bi % 8, ny = bi / 8;
    splitT_body(sW1_2, sW1Th2, sW1Tl2, HD, SH, kx * 32, ny * 32, smem);
  }
}

// ---------------------------------------------------------------------------
// Split-bf16 MFMA GEMM (feat): C[z] = A[z] @ B[z]^T-stored.
// A is fp32; hi/lo split happens in registers during LDS staging (same bytes
// as reading a pre-split pair). 3 mfma/product (hh+hl+lh) = fp32-grade.
// ---------------------------------------------------------------------------
__global__ __launch_bounds__(256) void gemm_mfma3(
    const float* __restrict__ A, int Mz, size_t aZ,
    const u16* __restrict__ Bh, const u16* __restrict__ Bl, size_t bZ,
    float* __restrict__ C, size_t cZ, int Mrows, int K, int Nc) {
  __shared__ u16 sAh[64][40], sAl[64][40], sBh[64][40], sBl[64][40];
  int z = blockIdx.z;
  const float* Ab = A + (size_t)(z / Mz) * aZ;
  const u16* Bhb = Bh + (size_t)(z % Mz) * bZ;
  const u16* Blb = Bl + (size_t)(z % Mz) * bZ;
  float* Cb = C + (size_t)z * cZ;
  int row0 = blockIdx.x * 64, col0 = blockIdx.y * 64;
  int tid = threadIdx.x;
  int arow = tid >> 2, akq = (tid & 3) * 8;
  int wid = tid >> 6, lane = tid & 63;
  int wr = (wid >> 1) * 32, wc = (wid & 1) * 32;
  int lrow = lane & 15, kseg = (lane >> 4) * 8;
  f32x4 zero4 = {0.f, 0.f, 0.f, 0.f};
  f32x4 acc[2][2];
  acc[0][0] = zero4; acc[0][1] = zero4; acc[1][0] = zero4; acc[1][1] = zero4;
  for (int k0 = 0; k0 < K; k0 += 32) {
    float4 a0 = make_float4(0.f, 0.f, 0.f, 0.f), a1 = a0;
    int gr = row0 + arow;
    if (gr < Mrows) {
      const float* ap = Ab + (size_t)gr * K + k0 + akq;
      a0 = *(const float4*)ap;
      a1 = *(const float4*)(ap + 4);
    }
    us8 hv, lv;
    {
      u16 th, tl;
      split2(a0.x, th, tl); hv[0] = th; lv[0] = tl;
      split2(a0.y, th, tl); hv[1] = th; lv[1] = tl;
      split2(a0.z, th, tl); hv[2] = th; lv[2] = tl;
      split2(a0.w, th, tl); hv[3] = th; lv[3] = tl;
      split2(a1.x, th, tl); hv[4] = th; lv[4] = tl;
      split2(a1.y, th, tl); hv[5] = th; lv[5] = tl;
      split2(a1.z, th, tl); hv[6] = th; lv[6] = tl;
      split2(a1.w, th, tl); hv[7] = th; lv[7] = tl;
    }
    *(us8*)&sAh[arow][akq] = hv;
    *(us8*)&sAl[arow][akq] = lv;
    us8 bv = *(const us8*)(Bhb + (size_t)(col0 + arow) * K + k0 + akq);
    us8 blv = *(const us8*)(Blb + (size_t)(col0 + arow) * K + k0 + akq);
    *(us8*)&sBh[arow][akq] = bv;
    *(us8*)&sBl[arow][akq] = blv;
    __syncthreads();
    s16x8 aH[2], aL[2], bH[2], bL[2];
#pragma unroll
    for (int i = 0; i < 2; ++i) {
      aH[i] = *(const s16x8*)&sAh[wr + 16 * i + lrow][kseg];
      aL[i] = *(const s16x8*)&sAl[wr + 16 * i + lrow][kseg];
      bH[i] = *(const s16x8*)&sBh[wc + 16 * i + lrow][kseg];
      bL[i] = *(const s16x8*)&sBl[wc + 16 * i + lrow][kseg];
    }
#pragma unroll
    for (int i = 0; i < 2; ++i)
#pragma unroll
      for (int j = 0; j < 2; ++j) {
        acc[i][j] = __builtin_amdgcn_mfma_f32_16x16x32_bf16(aH[i], bH[j], acc[i][j], 0, 0, 0);
        acc[i][j] = __builtin_amdgcn_mfma_f32_16x16x32_bf16(aH[i], bL[j], acc[i][j], 0, 0, 0);
        acc[i][j] = __builtin_amdgcn_mfma_f32_16x16x32_bf16(aL[i], bH[j], acc[i][j], 0, 0, 0);
      }
    __syncthreads();
  }
#pragma unroll
  for (int i = 0; i < 2; ++i)
#pragma unroll
    for (int j = 0; j < 2; ++j) {
      int ccol = col0 + wc + 16 * j + lrow;
#pragma unroll
      for (int r = 0; r < 4; ++r) {
        int crow = row0 + wr + 16 * i + (lane >> 4) * 4 + r;
        if (crow < Mrows) Cb[(size_t)crow * Nc + ccol] = acc[i][j][r];
      }
    }
}

// ---------------------------------------------------------------------------
// GAT aggregation with FUSED el/er: one wave per destination, barrier-free.
// el[s]/er[d] computed on the fly from feat rows already being loaded
// (4 FMA + 4 shuffles per edge). Direct exp (logits bounded, no max needed).
// Writes zb fp32 + zbh bf16. Also zeroes p and the gemm_sem block counter.
// ---------------------------------------------------------------------------
__global__ __launch_bounds__(256) void gat_agg_f(
    const unsigned long long* __restrict__ maskW, const float* __restrict__ feat,
    const float* __restrict__ al, const float* __restrict__ ar,
    const float* __restrict__ gb, float* __restrict__ zout,
    u16* __restrict__ zbh, float* __restrict__ p, int* __restrict__ counter) {
  int wid = threadIdx.x >> 6, lane = threadIdx.x & 63;
  int gw = blockIdx.x * 4 + wid;
  if (blockIdx.x == 0 && threadIdx.x == 0) *counter = 0;
  if (lane == 0) p[gw] = 0.f;
  int d = gw % N_, bm = gw / N_;
  int m = bm % M_, b = bm / M_;
  __shared__ int slist_all[4][1024];
  int* slist = slist_all[wid];

  const unsigned long long* mrow = maskW + ((size_t)bm * N_ + d) * NW;
  int cnt = 0;
#pragma unroll
  for (int w16 = 0; w16 < NW; ++w16) {
    unsigned long long word = mrow[w16];
    if (word) {
      if ((word >> lane) & 1ull) {
        int pos = cnt + (int)__popcll(word & ((1ull << lane) - 1ull));
        slist[pos] = w16 * 64 + lane;
      }
      cnt += (int)__popcll(word);
    }
  }

  float4 bias4 = *(const float4*)(gb + m * HD + lane * 4);
  size_t zoff = ((size_t)(b * N_ + d) * M_ + m) * HD + lane * 4;
  float4 o;
  if (cnt == 0) {
    o.x = bias4.x > 0.f ? bias4.x : (__expf(bias4.x) - 1.f);
    o.y = bias4.y > 0.f ? bias4.y : (__expf(bias4.y) - 1.f);
    o.z = bias4.z > 0.f ? bias4.z : (__expf(bias4.z) - 1.f);
    o.w = bias4.w > 0.f ? bias4.w : (__expf(bias4.w) - 1.f);
  } else {
    size_t bmN = (size_t)bm * N_;
    const float* fb = feat + bmN * HD;
    float4 al4 = *(const float4*)(al + m * HD + lane * 4);
    float4 ar4 = *(const float4*)(ar + m * HD + lane * 4);
    // er[d, h] : dot(feat[d], ar) reduced over the 16 lanes of this head
    float4 fd = *(const float4*)(fb + (size_t)d * HD + lane * 4);
    float erp = fd.x * ar4.x + fd.y * ar4.y + fd.z * ar4.z + fd.w * ar4.w;
#pragma unroll
    for (int t = 1; t < 16; t <<= 1) erp += __shfl_xor(erp, t, 64);
    float den = 0.f, ax = 0.f, ay = 0.f, az = 0.f, aw = 0.f;
    float4 f = *(const float4*)(fb + (size_t)slist[0] * HD + lane * 4);
    for (int i = 0; i < cnt; ++i) {
      float4 fn;
      if (i + 1 < cnt)
        fn = *(const float4*)(fb + (size_t)slist[i + 1] * HD + lane * 4);
      float elp = f.x * al4.x + f.y * al4.y + f.z * al4.z + f.w * al4.w;
#pragma unroll
      for (int t = 1; t < 16; t <<= 1) elp += __shfl_xor(elp, t, 64);
      float v = elp + erp;
      v = v > 0.f ? v : 0.2f * v;  // leaky_relu
      float w = __expf(v);         // no max needed: |v| bounded << 80
      den += w;
      ax += w * f.x; ay += w * f.y; az += w * f.z; aw += w * f.w;
      f = fn;
    }
    float inv = 1.f / den;
    float vx = ax * inv + bias4.x;
    float vy = ay * inv + bias4.y;
    float vz = az * inv + bias4.z;
    float vw = aw * inv + bias4.w;
    o.x = vx > 0.f ? vx : (__expf(vx) - 1.f);
    o.y = vy > 0.f ? vy : (__expf(vy) - 1.f);
    o.z = vz > 0.f ? vz : (__expf(vz) - 1.f);
    o.w = vw > 0.f ? vw : (__expf(vw) - 1.f);
  }
  *(float4*)(zout + zoff) = o;
  ushort4 hh;
  hh.x = bf16_bits(o.x);
  hh.y = bf16_bits(o.y);
  hh.z = bf16_bits(o.z);
  hh.w = bf16_bits(o.w);
  *(ushort4*)(zbh + zoff) = hh;
}

// ---------------------------------------------------------------------------
// Semantic GEMM + beta, fused: p[row] += sum_col tanh(A@W1+b1)*W2 (atomics),
// then the LAST block (atomic counter) reduces p -> beta softmax.
// ---------------------------------------------------------------------------
__global__ __launch_bounds__(256) void gemm_sem_beta(
    const u16* __restrict__ Ah, const u16* __restrict__ Bh,
    const float* __restrict__ bias, const float* __restrict__ W2,
    float* __restrict__ p, int Mrows, int* __restrict__ counter,
    const int* __restrict__ node_nums, float* __restrict__ beta) {
  __shared__ u16 sA[64][40], sB[64][40];
  __shared__ int isLast;
  int row0 = blockIdx.x * 64, col0 = blockIdx.y * 64;
  int tid = threadIdx.x;
  int arow = tid >> 2, akq = (tid & 3) * 8;
  int wid = tid >> 6, lane = tid & 63;
  int wr = (wid >> 1) * 32, wc = (wid & 1) * 32;
  int lrow = lane & 15, kseg = (lane >> 4) * 8;
  f32x4 zero4 = {0.f, 0.f, 0.f, 0.f};
  f32x4 acc[2][2];
  acc[0][0] = zero4; acc[0][1] = zero4; acc[1][0] = zero4; acc[1][1] = zero4;
  for (int k0 = 0; k0 < HD; k0 += 32) {
    us8 av = {0, 0, 0, 0, 0, 0, 0, 0};
    int gr = row0 + arow;
    if (gr < Mrows) av = *(const us8*)(Ah + (size_t)gr * HD + k0 + akq);
    *(us8*)&sA[arow][akq] = av;
    us8 bv = *(const us8*)(Bh + (size_t)(col0 + arow) * HD + k0 + akq);
    *(us8*)&sB[arow][akq] = bv;
    __syncthreads();
    s16x8 aH[2], bH[2];
#pragma unroll
    for (int i = 0; i < 2; ++i) {
      aH[i] = *(const s16x8*)&sA[wr + 16 * i + lrow][kseg];
      bH[i] = *(const s16x8*)&sB[wc + 16 * i + lrow][kseg];
    }
#pragma unroll
    for (int i = 0; i < 2; ++i)
#pragma unroll
      for (int j = 0; j < 2; ++j)
        acc[i][j] = __builtin_amdgcn_mfma_f32_16x16x32_bf16(aH[i], bH[j], acc[i][j], 0, 0, 0);
    __syncthreads();
  }
#pragma unroll
  for (int i = 0; i < 2; ++i) {
#pragma unroll
    for (int r = 0; r < 4; ++r) {
      float part = 0.f;
#pragma unroll
      for (int j = 0; j < 2; ++j) {
        int ccol = col0 + wc + 16 * j + lrow;
        float v = tanhf(acc[i][j][r] + bias[ccol]);
        part += v * W2[ccol];
      }
#pragma unroll
      for (int s = 1; s < 16; s <<= 1) part += __shfl_xor(part, s, 64);
      int crow = row0 + wr + 16 * i + (lane >> 4) * 4 + r;
      if (lrow == 0 && crow < Mrows) atomicAdd(&p[crow], part);
    }
  }
  // ---- last-block beta reduction ----
  __threadfence();
  __syncthreads();
  if (tid == 0)
    isLast = (atomicAdd(counter, 1) == (int)(gridDim.x * gridDim.y) - 1);
  __syncthreads();
  if (!isLast) return;
  float* red = (float*)sA;  // 5120 B >= 256*5 floats
  const volatile float* pv = p;
  float loc[M_] = {};
  int nn0 = node_nums[0], nn1 = node_nums[1], nn2 = node_nums[2], nn3 = node_nums[3];
  for (int r = tid; r < B_ * N_ * M_; r += 256) {
    int mm = r % M_;
    int bn = r / M_;
    int bb = bn / N_, n = bn % N_;
    int nn = (bb == 0) ? nn0 : (bb == 1) ? nn1 : (bb == 2) ? nn2 : nn3;
    if (n < nn) loc[mm] += pv[r];
  }
#pragma unroll
  for (int mm = 0; mm < M_; ++mm) red[tid * M_ + mm] = loc[mm];
  __syncthreads();
  for (int st = 128; st > 0; st >>= 1) {
    if (tid < st)
#pragma unroll
      for (int mm = 0; mm < M_; ++mm) red[tid * M_ + mm] += red[(tid + st) * M_ + mm];
    __syncthreads();
  }
  if (tid == 0) {
    float tot = (float)(nn0 + nn1 + nn2 + nn3);
    float w[M_], mx = -1e30f;
    for (int mm = 0; mm < M_; ++mm) {
      w[mm] = red[mm] / tot;
      mx = fmaxf(mx, w[mm]);
    }
    float s = 0.f;
    for (int mm = 0; mm < M_; ++mm) {
      w[mm] = __expf(w[mm] - mx);
      s += w[mm];
    }
    for (int mm = 0; mm < M_; ++mm) beta[mm] = w[mm] / s;
  }
}

// ---------------------------------------------------------------------------
// h[b,n,hd] = sum_m beta[m] * z[b,n,m,hd]  (fp32 out; L2 GEMM splits itself)
// ---------------------------------------------------------------------------
__global__ __launch_bounds__(256) void sem_combine(const float* __restrict__ zb,
                                                   const float* __restrict__ beta,
                                                   float* __restrict__ hout) {
  int idx = blockIdx.x * 256 + threadIdx.x;
  int hd = idx & (HD - 1);
  int bn = idx >> 8;
  const float* zr = zb + (size_t)bn * M_ * HD + hd;
  float v = beta[0] * zr[0] + beta[1] * zr[HD] + beta[2] * zr[2 * HD] +
            beta[3] * zr[3 * HD] + beta[4] * zr[4 * HD];
  hout[idx] = v;
}

// ---------------------------------------------------------------------------
// Layer-2 combine fused with prediction head: one wave per row.
// ---------------------------------------------------------------------------
__global__ __launch_bounds__(256) void sem_combine_pred(
    const float* __restrict__ zb, const float* __restrict__ beta,
    const float* __restrict__ W, const float* __restrict__ bias,
    const int* __restrict__ node_nums, float* __restrict__ out) {
  int row = blockIdx.x * 4 + (threadIdx.x >> 6);
  int lane = threadIdx.x & 63;
  int b = row / N_, n = row % N_;
  const float* zr = zb + (size_t)row * M_ * HD + lane * 4;
  float b0 = beta[0], b1 = beta[1], b2 = beta[2], b3 = beta[3], b4 = beta[4];
  float4 z0 = *(const float4*)(zr);
  float4 z1 = *(const float4*)(zr + HD);
  float4 z2 = *(const float4*)(zr + 2 * HD);
  float4 z3 = *(const float4*)(zr + 3 * HD);
  float4 z4 = *(const float4*)(zr + 4 * HD);
  float hx = b0 * z0.x + b1 * z1.x + b2 * z2.x + b3 * z3.x + b4 * z4.x;
  float hy = b0 * z0.y + b1 * z1.y + b2 * z2.y + b3 * z3.y + b4 * z4.y;
  float hz = b0 * z0.z + b1 * z1.z + b2 * z2.z + b3 * z3.z + b4 * z4.z;
  float hw = b0 * z0.w + b1 * z1.w + b2 * z2.w + b3 * z3.w + b4 * z4.w;
  int k = lane * 4;
  float res[OUTD];
#pragma unroll
  for (int o = 0; o < OUTD; ++o) {
    float v = hx * W[(k + 0) * OUTD + o] + hy * W[(k + 1) * OUTD + o] +
              hz * W[(k + 2) * OUTD + o] + hw * W[(k + 3) * OUTD + o];
#pragma unroll
    for (int s = 1; s < 64; s <<= 1) v += __shfl_xor(v, s, 64);
    res[o] = v;
  }
  if (lane == 0) {
    float nm = (n < node_nums[b]) ? 1.f : 0.f;
#pragma unroll
    for (int o = 0; o < OUTD; ++o)
      out[(size_t)row * OUTD + o] = (res[o] + bias[o]) * nm;
  }
}

extern "C" void kernel_launch(void* const* d_in, const int* in_sizes, int n_in,
                              void* d_out, int out_size, void* d_ws, size_t ws_size,
                              hipStream_t stream) {
  const float* x = (const float*)d_in[0];
  const float* adj = (const float*)d_in[1];
  const int* node_nums = (const int*)d_in[2];
  const float* fc1 = (const float*)d_in[3];
  const float* al1 = (const float*)d_in[4];
  const float* ar1 = (const float*)d_in[5];
  const float* gb1 = (const float*)d_in[6];
  const float* sW1_1 = (const float*)d_in[7];
  const float* sb1_1 = (const float*)d_in[8];
  const float* sW2_1 = (const float*)d_in[9];
  const float* fc2 = (const float*)d_in[10];
  const float* al2 = (const float*)d_in[11];
  const float* ar2 = (const float*)d_in[12];
  const float* gb2 = (const float*)d_in[13];
  const float* sW1_2 = (const float*)d_in[14];
  const float* sb1_2 = (const float*)d_in[15];
  const float* sW2_2 = (const float*)d_in[16];
  const float* predW = (const float*)d_in[17];
  const float* predb = (const float*)d_in[18];
  float* out = (float*)d_out;

  char* ws = (char*)d_ws;
  size_t off = 0;
  unsigned long long* maskW = (unsigned long long*)(ws + off);
  off += (size_t)B_ * M_ * N_ * NW * 8;
  float* feat = (float*)(ws + off); off += (size_t)B_ * M_ * N_ * HD * 4;
  float* zb = (float*)(ws + off); off += (size_t)B_ * N_ * M_ * HD * 4;
  float* h1 = (float*)(ws + off); off += (size_t)B_ * N_ * HD * 4;
  float* p = (float*)(ws + off); off += (size_t)B_ * N_ * M_ * 4;
  float* beta = (float*)(ws + off); off += 64;
  int* counter = (int*)(ws + off); off += 64;
  u16* fc1Th = (u16*)(ws + off); off += (size_t)M_ * HD * FIN * 2;
  u16* fc1Tl = (u16*)(ws + off); off += (size_t)M_ * HD * FIN * 2;
  u16* fc2Th = (u16*)(ws + off); off += (size_t)M_ * HD * HD * 2;
  u16* fc2Tl = (u16*)(ws + off); off += (size_t)M_ * HD * HD * 2;
  u16* sW1Th1 = (u16*)(ws + off); off += (size_t)SH * HD * 2;
  u16* sW1Tl1 = (u16*)(ws + off); off += (size_t)SH * HD * 2;
  u16* sW1Th2 = (u16*)(ws + off); off += (size_t)SH * HD * 2;
  u16* sW1Tl2 = (u16*)(ws + off); off += (size_t)SH * HD * 2;
  u16* zbh = (u16*)(ws + off); off += (size_t)B_ * N_ * M_ * HD * 2;

  const int ROWS = B_ * N_ * M_;  // 20000
  const int PREP_BLOCKS = 5120 + 80 + 320 + 32 + 32;  // 5584

  prep_all<<<dim3(PREP_BLOCKS), 256, 0, stream>>>(
      adj, node_nums, maskW, fc1, fc1Th, fc1Tl, fc2, fc2Th, fc2Tl,
      sW1_1, sW1Th1, sW1Tl1, sW1_2, sW1Th2, sW1Tl2);

  // ---- layer 1 ----
  gemm_mfma3<<<dim3(16, HD / 64, B_ * M_), 256, 0, stream>>>(
      x, M_, (size_t)M_ * N_ * FIN, fc1Th, fc1Tl, (size_t)HD * FIN,
      feat, (size_t)N_ * HD, N_, FIN, HD);
  gat_agg_f<<<dim3(ROWS / 4), 256, 0, stream>>>(
      maskW, feat, al1, ar1, gb1, zb, zbh, p, counter);
  gemm_sem_beta<<<dim3((ROWS + 63) / 64, SH / 64), 256, 0, stream>>>(
      zbh, sW1Th1, sb1_1, sW2_1, p, ROWS, counter, node_nums, beta);
  sem_combine<<<dim3(B_ * N_ * HD / 256), 256, 0, stream>>>(zb, beta, h1);

  // ---- layer 2 ----
  gemm_mfma3<<<dim3(16, HD / 64, B_ * M_), 256, 0, stream>>>(
      h1, M_, (size_t)N_ * HD, fc2Th, fc2Tl, (size_t)HD * HD,
      feat, (size_t)N_ * HD, N_, HD, HD);
  gat_agg_f<<<dim3(ROWS / 4), 256, 0, stream>>>(
      maskW, feat, al2, ar2, gb2, zb, zbh, p, counter);
  gemm_sem_beta<<<dim3((ROWS + 63) / 64, SH / 64), 256, 0, stream>>>(
      zbh, sW1Th2, sb1_2, sW2_2, p, ROWS, counter, node_nums, beta);
  sem_combine_pred<<<dim3(B_ * N_ / 4), 256, 0, stream>>>(
      zb, beta, predW, predb, node_nums, out);
}

// Round 7
// 226.640 us; speedup vs baseline: 1.2954x; 1.2954x over previous
//
#include <hip/hip_runtime.h>
#include <hip/hip_bf16.h>

#define B_ 4
#define M_ 5
#define N_ 1000
#define FIN 64
#define H_ 4
#define D_ 64
#define HD 256
#define SH 128
#define OUTD 5
#define NW 16  // u64 words per dest row (1024/64)
#define THRESH_ 0.97f

typedef unsigned short u16;
typedef u16 us8 __attribute__((ext_vector_type(8)));
typedef short s16x8 __attribute__((ext_vector_type(8)));
typedef float f32x4 __attribute__((ext_vector_type(4)));

__device__ inline u16 bf16_bits(float v) {
  __hip_bfloat16 h = __float2bfloat16(v);
  return *reinterpret_cast<u16*>(&h);
}
__device__ inline float bf16_val(u16 b) {
  __hip_bfloat16 h;
  *reinterpret_cast<u16*>(&h) = b;
  return __bfloat162float(h);
}
__device__ inline void split2(float v, u16& h, u16& l) {
  h = bf16_bits(v);
  l = bf16_bits(v - bf16_val(h));
}

// ---------------------------------------------------------------------------
// prep_all: one launch doing (a) bit-packed transposed edge mask build and
// (b) all weight transpose+split jobs, selected by block range.
// ---------------------------------------------------------------------------
__device__ void splitT_body(const float* __restrict__ s, u16* __restrict__ hiT,
                            u16* __restrict__ loT, int K, int N, int k0, int n0,
                            char* smem) {
  float(*tile)[33] = (float(*)[33])smem;
  int tid = threadIdx.x;
  int kl = tid >> 3, nq = (tid & 7) * 4;
  *(float4*)&tile[kl][nq] = *(const float4*)(s + (size_t)(k0 + kl) * N + n0 + nq);
  __syncthreads();
  int nl = tid >> 3, kq = (tid & 7) * 4;
  ushort4 h, l;
  split2(tile[kq + 0][nl], h.x, l.x);
  split2(tile[kq + 1][nl], h.y, l.y);
  split2(tile[kq + 2][nl], h.z, l.z);
  split2(tile[kq + 3][nl], h.w, l.w);
  size_t o = (size_t)(n0 + nl) * K + k0 + kq;
  *(ushort4*)(hiT + o) = h;
  *(ushort4*)(loT + o) = l;
}

__global__ __launch_bounds__(256) void prep_all(
    const float* __restrict__ adj, const int* __restrict__ node_nums,
    unsigned long long* __restrict__ maskW,
    const float* __restrict__ fc1, u16* __restrict__ fc1Th, u16* __restrict__ fc1Tl,
    const float* __restrict__ fc2, u16* __restrict__ fc2Th, u16* __restrict__ fc2Tl,
    const float* __restrict__ sW1_1, u16* __restrict__ sW1Th1, u16* __restrict__ sW1Tl1,
    const float* __restrict__ sW1_2, u16* __restrict__ sW1Th2, u16* __restrict__ sW1Tl2) {
  __shared__ __align__(16) char smem[4608];
  int bi = blockIdx.x;
  int tid = threadIdx.x;
  if (bi < 5120) {
    // ---- edge-mask build ----
    int bx = bi & 15, by = (bi >> 4) & 15, bm = bi >> 8;
    int b = bm / M_;
    int s0 = bx * 64, d0 = by * 64;
    int nn = node_nums[b];
    unsigned char(*tile)[65] = (unsigned char(*)[65])smem;
    const float* arow = adj + (size_t)bm * N_ * N_;
#pragma unroll
    for (int k = 0; k < 16; ++k) {
      int idx = k * 256 + tid;
      int sl = idx >> 6, dl = idx & 63;
      int s = s0 + sl, d = d0 + dl;
      unsigned char v = 0;
      if (s < nn && d < nn && s < N_ && d < N_)
        v = (arow[(size_t)s * N_ + d] > THRESH_) ? 1 : 0;
      tile[sl][dl] = v;
    }
    __syncthreads();
    int w = tid >> 6, lane = tid & 63;
#pragma unroll
    for (int j = 0; j < 16; ++j) {
      int dl = w * 16 + j;
      bool act = tile[lane][dl] != 0;
      unsigned long long word = __ballot(act);
      int d = d0 + dl;
      if (lane == 0 && d < N_)
        maskW[((size_t)bm * N_ + d) * NW + bx] = word;
    }
    return;
  }
  bi -= 5120;
  if (bi < 80) {  // fc1 (M, FIN, HD) -> (M, HD, FIN) hi/lo
    int kx = bi % 2, ny = (bi / 2) % 8, z = bi / 16;
    splitT_body(fc1 + (size_t)z * FIN * HD, fc1Th + (size_t)z * HD * FIN,
                fc1Tl + (size_t)z * HD * FIN, FIN, HD, kx * 32, ny * 32, smem);
    return;
  }
  bi -= 80;
  if (bi < 320) {  // fc2 (M, HD, HD) -> (M, HD, HD)T hi/lo
    int kx = bi % 8, ny = (bi / 8) % 8, z = bi / 64;
    splitT_body(fc2 + (size_t)z * HD * HD, fc2Th + (size_t)z * HD * HD,
                fc2Tl + (size_t)z * HD * HD, HD, HD, kx * 32, ny * 32, smem);
    return;
  }
  bi -= 320;
  if (bi < 32) {  // sW1_1 (HD, SH) -> (SH, HD) hi/lo
    int kx = bi % 8, ny = bi / 8;
    splitT_body(sW1_1, sW1Th1, sW1Tl1, HD, SH, kx * 32, ny * 32, smem);
    return;
  }
  bi -= 32;
  {  // sW1_2
    int kx = bi % 8, ny = bi / 8;
    splitT_body(sW1_2, sW1Th2, sW1Tl2, HD, SH, kx * 32, ny * 32, smem);
  }
}

// ---------------------------------------------------------------------------
// Split-bf16 MFMA GEMM (feat): C[z] = A[z] @ B[z]^T-stored.
// A is fp32; hi/lo split happens in registers during LDS staging.
// 3 mfma/product (hh+hl+lh) = fp32-grade accuracy.
// ---------------------------------------------------------------------------
__global__ __launch_bounds__(256) void gemm_mfma3(
    const float* __restrict__ A, int Mz, size_t aZ,
    const u16* __restrict__ Bh, const u16* __restrict__ Bl, size_t bZ,
    float* __restrict__ C, size_t cZ, int Mrows, int K, int Nc) {
  __shared__ u16 sAh[64][40], sAl[64][40], sBh[64][40], sBl[64][40];
  int z = blockIdx.z;
  const float* Ab = A + (size_t)(z / Mz) * aZ;
  const u16* Bhb = Bh + (size_t)(z % Mz) * bZ;
  const u16* Blb = Bl + (size_t)(z % Mz) * bZ;
  float* Cb = C + (size_t)z * cZ;
  int row0 = blockIdx.x * 64, col0 = blockIdx.y * 64;
  int tid = threadIdx.x;
  int arow = tid >> 2, akq = (tid & 3) * 8;
  int wid = tid >> 6, lane = tid & 63;
  int wr = (wid >> 1) * 32, wc = (wid & 1) * 32;
  int lrow = lane & 15, kseg = (lane >> 4) * 8;
  f32x4 zero4 = {0.f, 0.f, 0.f, 0.f};
  f32x4 acc[2][2];
  acc[0][0] = zero4; acc[0][1] = zero4; acc[1][0] = zero4; acc[1][1] = zero4;
  for (int k0 = 0; k0 < K; k0 += 32) {
    float4 a0 = make_float4(0.f, 0.f, 0.f, 0.f), a1 = a0;
    int gr = row0 + arow;
    if (gr < Mrows) {
      const float* ap = Ab + (size_t)gr * K + k0 + akq;
      a0 = *(const float4*)ap;
      a1 = *(const float4*)(ap + 4);
    }
    us8 hv, lv;
    {
      u16 th, tl;
      split2(a0.x, th, tl); hv[0] = th; lv[0] = tl;
      split2(a0.y, th, tl); hv[1] = th; lv[1] = tl;
      split2(a0.z, th, tl); hv[2] = th; lv[2] = tl;
      split2(a0.w, th, tl); hv[3] = th; lv[3] = tl;
      split2(a1.x, th, tl); hv[4] = th; lv[4] = tl;
      split2(a1.y, th, tl); hv[5] = th; lv[5] = tl;
      split2(a1.z, th, tl); hv[6] = th; lv[6] = tl;
      split2(a1.w, th, tl); hv[7] = th; lv[7] = tl;
    }
    *(us8*)&sAh[arow][akq] = hv;
    *(us8*)&sAl[arow][akq] = lv;
    us8 bv = *(const us8*)(Bhb + (size_t)(col0 + arow) * K + k0 + akq);
    us8 blv = *(const us8*)(Blb + (size_t)(col0 + arow) * K + k0 + akq);
    *(us8*)&sBh[arow][akq] = bv;
    *(us8*)&sBl[arow][akq] = blv;
    __syncthreads();
    s16x8 aH[2], aL[2], bH[2], bL[2];
#pragma unroll
    for (int i = 0; i < 2; ++i) {
      aH[i] = *(const s16x8*)&sAh[wr + 16 * i + lrow][kseg];
      aL[i] = *(const s16x8*)&sAl[wr + 16 * i + lrow][kseg];
      bH[i] = *(const s16x8*)&sBh[wc + 16 * i + lrow][kseg];
      bL[i] = *(const s16x8*)&sBl[wc + 16 * i + lrow][kseg];
    }
#pragma unroll
    for (int i = 0; i < 2; ++i)
#pragma unroll
      for (int j = 0; j < 2; ++j) {
        acc[i][j] = __builtin_amdgcn_mfma_f32_16x16x32_bf16(aH[i], bH[j], acc[i][j], 0, 0, 0);
        acc[i][j] = __builtin_amdgcn_mfma_f32_16x16x32_bf16(aH[i], bL[j], acc[i][j], 0, 0, 0);
        acc[i][j] = __builtin_amdgcn_mfma_f32_16x16x32_bf16(aL[i], bH[j], acc[i][j], 0, 0, 0);
      }
    __syncthreads();
  }
#pragma unroll
  for (int i = 0; i < 2; ++i)
#pragma unroll
    for (int j = 0; j < 2; ++j) {
      int ccol = col0 + wc + 16 * j + lrow;
#pragma unroll
      for (int r = 0; r < 4; ++r) {
        int crow = row0 + wr + 16 * i + (lane >> 4) * 4 + r;
        if (crow < Mrows) Cb[(size_t)crow * Nc + ccol] = acc[i][j][r];
      }
    }
}

// ---------------------------------------------------------------------------
// GAT aggregation with FUSED el/er: one wave per destination, barrier-free.
// Direct exp (logits bounded). Writes zb fp32 + zbh bf16. Zeroes p.
// ---------------------------------------------------------------------------
__global__ __launch_bounds__(256) void gat_agg_f(
    const unsigned long long* __restrict__ maskW, const float* __restrict__ feat,
    const float* __restrict__ al, const float* __restrict__ ar,
    const float* __restrict__ gb, float* __restrict__ zout,
    u16* __restrict__ zbh, float* __restrict__ p) {
  int wid = threadIdx.x >> 6, lane = threadIdx.x & 63;
  int gw = blockIdx.x * 4 + wid;
  if (lane == 0) p[gw] = 0.f;
  int d = gw % N_, bm = gw / N_;
  int m = bm % M_, b = bm / M_;
  __shared__ int slist_all[4][1024];
  int* slist = slist_all[wid];

  const unsigned long long* mrow = maskW + ((size_t)bm * N_ + d) * NW;
  int cnt = 0;
#pragma unroll
  for (int w16 = 0; w16 < NW; ++w16) {
    unsigned long long word = mrow[w16];
    if (word) {
      if ((word >> lane) & 1ull) {
        int pos = cnt + (int)__popcll(word & ((1ull << lane) - 1ull));
        slist[pos] = w16 * 64 + lane;
      }
      cnt += (int)__popcll(word);
    }
  }

  float4 bias4 = *(const float4*)(gb + m * HD + lane * 4);
  size_t zoff = ((size_t)(b * N_ + d) * M_ + m) * HD + lane * 4;
  float4 o;
  if (cnt == 0) {
    o.x = bias4.x > 0.f ? bias4.x : (__expf(bias4.x) - 1.f);
    o.y = bias4.y > 0.f ? bias4.y : (__expf(bias4.y) - 1.f);
    o.z = bias4.z > 0.f ? bias4.z : (__expf(bias4.z) - 1.f);
    o.w = bias4.w > 0.f ? bias4.w : (__expf(bias4.w) - 1.f);
  } else {
    size_t bmN = (size_t)bm * N_;
    const float* fb = feat + bmN * HD;
    float4 al4 = *(const float4*)(al + m * HD + lane * 4);
    float4 ar4 = *(const float4*)(ar + m * HD + lane * 4);
    // er[d, h] : dot(feat[d], ar) reduced over the 16 lanes of this head
    float4 fd = *(const float4*)(fb + (size_t)d * HD + lane * 4);
    float erp = fd.x * ar4.x + fd.y * ar4.y + fd.z * ar4.z + fd.w * ar4.w;
#pragma unroll
    for (int t = 1; t < 16; t <<= 1) erp += __shfl_xor(erp, t, 64);
    float den = 0.f, ax = 0.f, ay = 0.f, az = 0.f, aw = 0.f;
    float4 f = *(const float4*)(fb + (size_t)slist[0] * HD + lane * 4);
    for (int i = 0; i < cnt; ++i) {
      float4 fn;
      if (i + 1 < cnt)
        fn = *(const float4*)(fb + (size_t)slist[i + 1] * HD + lane * 4);
      float elp = f.x * al4.x + f.y * al4.y + f.z * al4.z + f.w * al4.w;
#pragma unroll
      for (int t = 1; t < 16; t <<= 1) elp += __shfl_xor(elp, t, 64);
      float v = elp + erp;
      v = v > 0.f ? v : 0.2f * v;  // leaky_relu
      float w = __expf(v);         // no max needed: |v| bounded << 80
      den += w;
      ax += w * f.x; ay += w * f.y; az += w * f.z; aw += w * f.w;
      f = fn;
    }
    float inv = 1.f / den;
    float vx = ax * inv + bias4.x;
    float vy = ay * inv + bias4.y;
    float vz = az * inv + bias4.z;
    float vw = aw * inv + bias4.w;
    o.x = vx > 0.f ? vx : (__expf(vx) - 1.f);
    o.y = vy > 0.f ? vy : (__expf(vy) - 1.f);
    o.z = vz > 0.f ? vz : (__expf(vz) - 1.f);
    o.w = vw > 0.f ? vw : (__expf(vw) - 1.f);
  }
  *(float4*)(zout + zoff) = o;
  ushort4 hh;
  hh.x = bf16_bits(o.x);
  hh.y = bf16_bits(o.y);
  hh.z = bf16_bits(o.z);
  hh.w = bf16_bits(o.w);
  *(ushort4*)(zbh + zoff) = hh;
}

// ---------------------------------------------------------------------------
// Semantic GEMM: p[row] += sum_col tanh(A@W1+b1)[row,col] * W2[col].
// A bf16-only (1 mfma). Epilogue: 16-lane shuffle reduce + atomicAdd into p.
// NO device fence — the following kernel boundary provides ordering.
// ---------------------------------------------------------------------------
__global__ __launch_bounds__(256) void gemm_sem(
    const u16* __restrict__ Ah, const u16* __restrict__ Bh,
    const float* __restrict__ bias, const float* __restrict__ W2,
    float* __restrict__ p, int Mrows) {
  __shared__ u16 sA[64][40], sB[64][40];
  int row0 = blockIdx.x * 64, col0 = blockIdx.y * 64;
  int tid = threadIdx.x;
  int arow = tid >> 2, akq = (tid & 3) * 8;
  int wid = tid >> 6, lane = tid & 63;
  int wr = (wid >> 1) * 32, wc = (wid & 1) * 32;
  int lrow = lane & 15, kseg = (lane >> 4) * 8;
  f32x4 zero4 = {0.f, 0.f, 0.f, 0.f};
  f32x4 acc[2][2];
  acc[0][0] = zero4; acc[0][1] = zero4; acc[1][0] = zero4; acc[1][1] = zero4;
  for (int k0 = 0; k0 < HD; k0 += 32) {
    us8 av = {0, 0, 0, 0, 0, 0, 0, 0};
    int gr = row0 + arow;
    if (gr < Mrows) av = *(const us8*)(Ah + (size_t)gr * HD + k0 + akq);
    *(us8*)&sA[arow][akq] = av;
    us8 bv = *(const us8*)(Bh + (size_t)(col0 + arow) * HD + k0 + akq);
    *(us8*)&sB[arow][akq] = bv;
    __syncthreads();
    s16x8 aH[2], bH[2];
#pragma unroll
    for (int i = 0; i < 2; ++i) {
      aH[i] = *(const s16x8*)&sA[wr + 16 * i + lrow][kseg];
      bH[i] = *(const s16x8*)&sB[wc + 16 * i + lrow][kseg];
    }
#pragma unroll
    for (int i = 0; i < 2; ++i)
#pragma unroll
      for (int j = 0; j < 2; ++j)
        acc[i][j] = __builtin_amdgcn_mfma_f32_16x16x32_bf16(aH[i], bH[j], acc[i][j], 0, 0, 0);
    __syncthreads();
  }
#pragma unroll
  for (int i = 0; i < 2; ++i) {
#pragma unroll
    for (int r = 0; r < 4; ++r) {
      float part = 0.f;
#pragma unroll
      for (int j = 0; j < 2; ++j) {
        int ccol = col0 + wc + 16 * j + lrow;
        float v = tanhf(acc[i][j][r] + bias[ccol]);
        part += v * W2[ccol];
      }
#pragma unroll
      for (int s = 1; s < 16; s <<= 1) part += __shfl_xor(part, s, 64);
      int crow = row0 + wr + 16 * i + (lane >> 4) * 4 + r;
      if (lrow == 0 && crow < Mrows) atomicAdd(&p[crow], part);
    }
  }
}

// ---------------------------------------------------------------------------
// beta = softmax_m( sum_{b,n valid} p[b,n,m] / sum(node_nums) )  — 1 block
// ---------------------------------------------------------------------------
__global__ __launch_bounds__(256) void sem_beta(const float* __restrict__ p,
                                                const int* __restrict__ node_nums,
                                                float* __restrict__ beta) {
  __shared__ float red[256][M_];
  int tid = threadIdx.x;
  float loc[M_] = {};
  int nn0 = node_nums[0], nn1 = node_nums[1], nn2 = node_nums[2], nn3 = node_nums[3];
  for (int r = tid; r < B_ * N_ * M_; r += 256) {
    int m = r % M_;
    int bn = r / M_;
    int b = bn / N_, n = bn % N_;
    int nn = (b == 0) ? nn0 : (b == 1) ? nn1 : (b == 2) ? nn2 : nn3;
    if (n < nn) loc[m] += p[r];
  }
  for (int m = 0; m < M_; ++m) red[tid][m] = loc[m];
  __syncthreads();
  for (int st = 128; st > 0; st >>= 1) {
    if (tid < st)
      for (int m = 0; m < M_; ++m) red[tid][m] += red[tid + st][m];
    __syncthreads();
  }
  if (tid == 0) {
    float tot = (float)(nn0 + nn1 + nn2 + nn3);
    float w[M_], mx = -1e30f;
    for (int m = 0; m < M_; ++m) {
      w[m] = red[0][m] / tot;
      mx = fmaxf(mx, w[m]);
    }
    float s = 0.f;
    for (int m = 0; m < M_; ++m) {
      w[m] = __expf(w[m] - mx);
      s += w[m];
    }
    for (int m = 0; m < M_; ++m) beta[m] = w[m] / s;
  }
}

// ---------------------------------------------------------------------------
// h[b,n,hd] = sum_m beta[m] * z[b,n,m,hd]  (fp32 out; L2 GEMM splits itself)
// ---------------------------------------------------------------------------
__global__ __launch_bounds__(256) void sem_combine(const float* __restrict__ zb,
                                                   const float* __restrict__ beta,
                                                   float* __restrict__ hout) {
  int idx = blockIdx.x * 256 + threadIdx.x;
  int hd = idx & (HD - 1);
  int bn = idx >> 8;
  const float* zr = zb + (size_t)bn * M_ * HD + hd;
  float v = beta[0] * zr[0] + beta[1] * zr[HD] + beta[2] * zr[2 * HD] +
            beta[3] * zr[3 * HD] + beta[4] * zr[4 * HD];
  hout[idx] = v;
}

// ---------------------------------------------------------------------------
// Layer-2 combine fused with prediction head: one wave per row.
// ---------------------------------------------------------------------------
__global__ __launch_bounds__(256) void sem_combine_pred(
    const float* __restrict__ zb, const float* __restrict__ beta,
    const float* __restrict__ W, const float* __restrict__ bias,
    const int* __restrict__ node_nums, float* __restrict__ out) {
  int row = blockIdx.x * 4 + (threadIdx.x >> 6);
  int lane = threadIdx.x & 63;
  int b = row / N_, n = row % N_;
  const float* zr = zb + (size_t)row * M_ * HD + lane * 4;
  float b0 = beta[0], b1 = beta[1], b2 = beta[2], b3 = beta[3], b4 = beta[4];
  float4 z0 = *(const float4*)(zr);
  float4 z1 = *(const float4*)(zr + HD);
  float4 z2 = *(const float4*)(zr + 2 * HD);
  float4 z3 = *(const float4*)(zr + 3 * HD);
  float4 z4 = *(const float4*)(zr + 4 * HD);
  float hx = b0 * z0.x + b1 * z1.x + b2 * z2.x + b3 * z3.x + b4 * z4.x;
  float hy = b0 * z0.y + b1 * z1.y + b2 * z2.y + b3 * z3.y + b4 * z4.y;
  float hz = b0 * z0.z + b1 * z1.z + b2 * z2.z + b3 * z3.z + b4 * z4.z;
  float hw = b0 * z0.w + b1 * z1.w + b2 * z2.w + b3 * z3.w + b4 * z4.w;
  int k = lane * 4;
  float res[OUTD];
#pragma unroll
  for (int o = 0; o < OUTD; ++o) {
    float v = hx * W[(k + 0) * OUTD + o] + hy * W[(k + 1) * OUTD + o] +
              hz * W[(k + 2) * OUTD + o] + hw * W[(k + 3) * OUTD + o];
#pragma unroll
    for (int s = 1; s < 64; s <<= 1) v += __shfl_xor(v, s, 64);
    res[o] = v;
  }
  if (lane == 0) {
    float nm = (n < node_nums[b]) ? 1.f : 0.f;
#pragma unroll
    for (int o = 0; o < OUTD; ++o)
      out[(size_t)row * OUTD + o] = (res[o] + bias[o]) * nm;
  }
}

extern "C" void kernel_launch(void* const* d_in, const int* in_sizes, int n_in,
                              void* d_out, int out_size, void* d_ws, size_t ws_size,
                              hipStream_t stream) {
  const float* x = (const float*)d_in[0];
  const float* adj = (const float*)d_in[1];
  const int* node_nums = (const int*)d_in[2];
  const float* fc1 = (const float*)d_in[3];
  const float* al1 = (const float*)d_in[4];
  const float* ar1 = (const float*)d_in[5];
  const float* gb1 = (const float*)d_in[6];
  const float* sW1_1 = (const float*)d_in[7];
  const float* sb1_1 = (const float*)d_in[8];
  const float* sW2_1 = (const float*)d_in[9];
  const float* fc2 = (const float*)d_in[10];
  const float* al2 = (const float*)d_in[11];
  const float* ar2 = (const float*)d_in[12];
  const float* gb2 = (const float*)d_in[13];
  const float* sW1_2 = (const float*)d_in[14];
  const float* sb1_2 = (const float*)d_in[15];
  const float* sW2_2 = (const float*)d_in[16];
  const float* predW = (const float*)d_in[17];
  const float* predb = (const float*)d_in[18];
  float* out = (float*)d_out;

  char* ws = (char*)d_ws;
  size_t off = 0;
  unsigned long long* maskW = (unsigned long long*)(ws + off);
  off += (size_t)B_ * M_ * N_ * NW * 8;
  float* feat = (float*)(ws + off); off += (size_t)B_ * M_ * N_ * HD * 4;
  float* zb = (float*)(ws + off); off += (size_t)B_ * N_ * M_ * HD * 4;
  float* h1 = (float*)(ws + off); off += (size_t)B_ * N_ * HD * 4;
  float* p = (float*)(ws + off); off += (size_t)B_ * N_ * M_ * 4;
  float* beta = (float*)(ws + off); off += 64;
  u16* fc1Th = (u16*)(ws + off); off += (size_t)M_ * HD * FIN * 2;
  u16* fc1Tl = (u16*)(ws + off); off += (size_t)M_ * HD * FIN * 2;
  u16* fc2Th = (u16*)(ws + off); off += (size_t)M_ * HD * HD * 2;
  u16* fc2Tl = (u16*)(ws + off); off += (size_t)M_ * HD * HD * 2;
  u16* sW1Th1 = (u16*)(ws + off); off += (size_t)SH * HD * 2;
  u16* sW1Tl1 = (u16*)(ws + off); off += (size_t)SH * HD * 2;
  u16* sW1Th2 = (u16*)(ws + off); off += (size_t)SH * HD * 2;
  u16* sW1Tl2 = (u16*)(ws + off); off += (size_t)SH * HD * 2;
  u16* zbh = (u16*)(ws + off); off += (size_t)B_ * N_ * M_ * HD * 2;

  const int ROWS = B_ * N_ * M_;  // 20000
  const int PREP_BLOCKS = 5120 + 80 + 320 + 32 + 32;  // 5584

  prep_all<<<dim3(PREP_BLOCKS), 256, 0, stream>>>(
      adj, node_nums, maskW, fc1, fc1Th, fc1Tl, fc2, fc2Th, fc2Tl,
      sW1_1, sW1Th1, sW1Tl1, sW1_2, sW1Th2, sW1Tl2);

  // ---- layer 1 ----
  gemm_mfma3<<<dim3(16, HD / 64, B_ * M_), 256, 0, stream>>>(
      x, M_, (size_t)M_ * N_ * FIN, fc1Th, fc1Tl, (size_t)HD * FIN,
      feat, (size_t)N_ * HD, N_, FIN, HD);
  gat_agg_f<<<dim3(ROWS / 4), 256, 0, stream>>>(
      maskW, feat, al1, ar1, gb1, zb, zbh, p);
  gemm_sem<<<dim3((ROWS + 63) / 64, SH / 64), 256, 0, stream>>>(
      zbh, sW1Th1, sb1_1, sW2_1, p, ROWS);
  sem_beta<<<dim3(1), 256, 0, stream>>>(p, node_nums, beta);
  sem_combine<<<dim3(B_ * N_ * HD / 256), 256, 0, stream>>>(zb, beta, h1);

  // ---- layer 2 ----
  gemm_mfma3<<<dim3(16, HD / 64, B_ * M_), 256, 0, stream>>>(
      h1, M_, (size_t)N_ * HD, fc2Th, fc2Tl, (size_t)HD * HD,
      feat, (size_t)N_ * HD, N_, HD, HD);
  gat_agg_f<<<dim3(ROWS / 4), 256, 0, stream>>>(
      maskW, feat, al2, ar2, gb2, zb, zbh, p);
  gemm_sem<<<dim3((ROWS + 63) / 64, SH / 64), 256, 0, stream>>>(
      zbh, sW1Th2, sb1_2, sW2_2, p, ROWS);
  sem_beta<<<dim3(1), 256, 0, stream>>>(p, node_nums, beta);
  sem_combine_pred<<<dim3(B_ * N_ / 4), 256, 0, stream>>>(
      zb, beta, predW, predb, node_nums, out);
}

// Round 8
// 226.417 us; speedup vs baseline: 1.2967x; 1.0010x over previous
//
#include <hip/hip_runtime.h>
#include <hip/hip_bf16.h>

#define B_ 4
#define M_ 5
#define N_ 1000
#define FIN 64
#define H_ 4
#define D_ 64
#define HD 256
#define SH 128
#define OUTD 5
#define NW 16  // u64 words per dest row (1024/64)
#define THRESH_ 0.97f

typedef unsigned short u16;
typedef u16 us8 __attribute__((ext_vector_type(8)));
typedef short s16x8 __attribute__((ext_vector_type(8)));
typedef float f32x4 __attribute__((ext_vector_type(4)));

__device__ inline u16 bf16_bits(float v) {
  __hip_bfloat16 h = __float2bfloat16(v);
  return *reinterpret_cast<u16*>(&h);
}
__device__ inline float bf16_val(u16 b) {
  __hip_bfloat16 h;
  *reinterpret_cast<u16*>(&h) = b;
  return __bfloat162float(h);
}
__device__ inline void split2(float v, u16& h, u16& l) {
  h = bf16_bits(v);
  l = bf16_bits(v - bf16_val(h));
}

// ---------------------------------------------------------------------------
// prep_all: one launch doing (a) bit-packed transposed edge mask build and
// (b) all weight transpose+split jobs, selected by block range.
// ---------------------------------------------------------------------------
__device__ void splitT_body(const float* __restrict__ s, u16* __restrict__ hiT,
                            u16* __restrict__ loT, int K, int N, int k0, int n0,
                            char* smem) {
  float(*tile)[33] = (float(*)[33])smem;
  int tid = threadIdx.x;
  int kl = tid >> 3, nq = (tid & 7) * 4;
  *(float4*)&tile[kl][nq] = *(const float4*)(s + (size_t)(k0 + kl) * N + n0 + nq);
  __syncthreads();
  int nl = tid >> 3, kq = (tid & 7) * 4;
  ushort4 h, l;
  split2(tile[kq + 0][nl], h.x, l.x);
  split2(tile[kq + 1][nl], h.y, l.y);
  split2(tile[kq + 2][nl], h.z, l.z);
  split2(tile[kq + 3][nl], h.w, l.w);
  size_t o = (size_t)(n0 + nl) * K + k0 + kq;
  *(ushort4*)(hiT + o) = h;
  *(ushort4*)(loT + o) = l;
}

__global__ __launch_bounds__(256) void prep_all(
    const float* __restrict__ adj, const int* __restrict__ node_nums,
    unsigned long long* __restrict__ maskW,
    const float* __restrict__ fc1, u16* __restrict__ fc1Th, u16* __restrict__ fc1Tl,
    const float* __restrict__ fc2, u16* __restrict__ fc2Th, u16* __restrict__ fc2Tl,
    const float* __restrict__ sW1_1, u16* __restrict__ sW1Th1, u16* __restrict__ sW1Tl1,
    const float* __restrict__ sW1_2, u16* __restrict__ sW1Th2, u16* __restrict__ sW1Tl2) {
  __shared__ __align__(16) char smem[4608];
  int bi = blockIdx.x;
  int tid = threadIdx.x;
  if (bi < 5120) {
    // ---- edge-mask build ----
    int bx = bi & 15, by = (bi >> 4) & 15, bm = bi >> 8;
    int b = bm / M_;
    int s0 = bx * 64, d0 = by * 64;
    int nn = node_nums[b];
    unsigned char(*tile)[65] = (unsigned char(*)[65])smem;
    const float* arow = adj + (size_t)bm * N_ * N_;
#pragma unroll
    for (int k = 0; k < 16; ++k) {
      int idx = k * 256 + tid;
      int sl = idx >> 6, dl = idx & 63;
      int s = s0 + sl, d = d0 + dl;
      unsigned char v = 0;
      if (s < nn && d < nn && s < N_ && d < N_)
        v = (arow[(size_t)s * N_ + d] > THRESH_) ? 1 : 0;
      tile[sl][dl] = v;
    }
    __syncthreads();
    int w = tid >> 6, lane = tid & 63;
#pragma unroll
    for (int j = 0; j < 16; ++j) {
      int dl = w * 16 + j;
      bool act = tile[lane][dl] != 0;
      unsigned long long word = __ballot(act);
      int d = d0 + dl;
      if (lane == 0 && d < N_)
        maskW[((size_t)bm * N_ + d) * NW + bx] = word;
    }
    return;
  }
  bi -= 5120;
  if (bi < 80) {  // fc1 (M, FIN, HD) -> (M, HD, FIN) hi/lo
    int kx = bi % 2, ny = (bi / 2) % 8, z = bi / 16;
    splitT_body(fc1 + (size_t)z * FIN * HD, fc1Th + (size_t)z * HD * FIN,
                fc1Tl + (size_t)z * HD * FIN, FIN, HD, kx * 32, ny * 32, smem);
    return;
  }
  bi -= 80;
  if (bi < 320) {  // fc2 (M, HD, HD) -> (M, HD, HD)T hi/lo
    int kx = bi % 8, ny = (bi / 8) % 8, z = bi / 64;
    splitT_body(fc2 + (size_t)z * HD * HD, fc2Th + (size_t)z * HD * HD,
                fc2Tl + (size_t)z * HD * HD, HD, HD, kx * 32, ny * 32, smem);
    return;
  }
  bi -= 320;
  if (bi < 32) {  // sW1_1 (HD, SH) -> (SH, HD) hi/lo
    int kx = bi % 8, ny = bi / 8;
    splitT_body(sW1_1, sW1Th1, sW1Tl1, HD, SH, kx * 32, ny * 32, smem);
    return;
  }
  bi -= 32;
  {  // sW1_2
    int kx = bi % 8, ny = bi / 8;
    splitT_body(sW1_2, sW1Th2, sW1Tl2, HD, SH, kx * 32, ny * 32, smem);
  }
}

// ---------------------------------------------------------------------------
// Split-bf16 MFMA GEMM (feat): C[z] = A[z] @ B[z]^T-stored.
// A is fp32; hi/lo split happens in registers during LDS staging.
// 3 mfma/product (hh+hl+lh) = fp32-grade accuracy.
// ---------------------------------------------------------------------------
__global__ __launch_bounds__(256) void gemm_mfma3(
    const float* __restrict__ A, int Mz, size_t aZ,
    const u16* __restrict__ Bh, const u16* __restrict__ Bl, size_t bZ,
    float* __restrict__ C, size_t cZ, int Mrows, int K, int Nc) {
  __shared__ u16 sAh[64][40], sAl[64][40], sBh[64][40], sBl[64][40];
  int z = blockIdx.z;
  const float* Ab = A + (size_t)(z / Mz) * aZ;
  const u16* Bhb = Bh + (size_t)(z % Mz) * bZ;
  const u16* Blb = Bl + (size_t)(z % Mz) * bZ;
  float* Cb = C + (size_t)z * cZ;
  int row0 = blockIdx.x * 64, col0 = blockIdx.y * 64;
  int tid = threadIdx.x;
  int arow = tid >> 2, akq = (tid & 3) * 8;
  int wid = tid >> 6, lane = tid & 63;
  int wr = (wid >> 1) * 32, wc = (wid & 1) * 32;
  int lrow = lane & 15, kseg = (lane >> 4) * 8;
  f32x4 zero4 = {0.f, 0.f, 0.f, 0.f};
  f32x4 acc[2][2];
  acc[0][0] = zero4; acc[0][1] = zero4; acc[1][0] = zero4; acc[1][1] = zero4;
  for (int k0 = 0; k0 < K; k0 += 32) {
    float4 a0 = make_float4(0.f, 0.f, 0.f, 0.f), a1 = a0;
    int gr = row0 + arow;
    if (gr < Mrows) {
      const float* ap = Ab + (size_t)gr * K + k0 + akq;
      a0 = *(const float4*)ap;
      a1 = *(const float4*)(ap + 4);
    }
    us8 hv, lv;
    {
      u16 th, tl;
      split2(a0.x, th, tl); hv[0] = th; lv[0] = tl;
      split2(a0.y, th, tl); hv[1] = th; lv[1] = tl;
      split2(a0.z, th, tl); hv[2] = th; lv[2] = tl;
      split2(a0.w, th, tl); hv[3] = th; lv[3] = tl;
      split2(a1.x, th, tl); hv[4] = th; lv[4] = tl;
      split2(a1.y, th, tl); hv[5] = th; lv[5] = tl;
      split2(a1.z, th, tl); hv[6] = th; lv[6] = tl;
      split2(a1.w, th, tl); hv[7] = th; lv[7] = tl;
    }
    *(us8*)&sAh[arow][akq] = hv;
    *(us8*)&sAl[arow][akq] = lv;
    us8 bv = *(const us8*)(Bhb + (size_t)(col0 + arow) * K + k0 + akq);
    us8 blv = *(const us8*)(Blb + (size_t)(col0 + arow) * K + k0 + akq);
    *(us8*)&sBh[arow][akq] = bv;
    *(us8*)&sBl[arow][akq] = blv;
    __syncthreads();
    s16x8 aH[2], aL[2], bH[2], bL[2];
#pragma unroll
    for (int i = 0; i < 2; ++i) {
      aH[i] = *(const s16x8*)&sAh[wr + 16 * i + lrow][kseg];
      aL[i] = *(const s16x8*)&sAl[wr + 16 * i + lrow][kseg];
      bH[i] = *(const s16x8*)&sBh[wc + 16 * i + lrow][kseg];
      bL[i] = *(const s16x8*)&sBl[wc + 16 * i + lrow][kseg];
    }
#pragma unroll
    for (int i = 0; i < 2; ++i)
#pragma unroll
      for (int j = 0; j < 2; ++j) {
        acc[i][j] = __builtin_amdgcn_mfma_f32_16x16x32_bf16(aH[i], bH[j], acc[i][j], 0, 0, 0);
        acc[i][j] = __builtin_amdgcn_mfma_f32_16x16x32_bf16(aH[i], bL[j], acc[i][j], 0, 0, 0);
        acc[i][j] = __builtin_amdgcn_mfma_f32_16x16x32_bf16(aL[i], bH[j], acc[i][j], 0, 0, 0);
      }
    __syncthreads();
  }
#pragma unroll
  for (int i = 0; i < 2; ++i)
#pragma unroll
    for (int j = 0; j < 2; ++j) {
      int ccol = col0 + wc + 16 * j + lrow;
#pragma unroll
      for (int r = 0; r < 4; ++r) {
        int crow = row0 + wr + 16 * i + (lane >> 4) * 4 + r;
        if (crow < Mrows) Cb[(size_t)crow * Nc + ccol] = acc[i][j][r];
      }
    }
}

// ---------------------------------------------------------------------------
// el/er: wave-per-row, 16-lane reduce per head. Also zeroes p for gemm_sem.
// ---------------------------------------------------------------------------
__global__ __launch_bounds__(256) void elr_kernel(
    const float* __restrict__ feat, const float* __restrict__ al,
    const float* __restrict__ ar, float* __restrict__ el,
    float* __restrict__ er, float* __restrict__ p) {
  int b = blockIdx.z, m = blockIdx.y;
  int wid = threadIdx.x >> 6, lane = threadIdx.x & 63;
  if (blockIdx.y == 0 && blockIdx.z == 0) {
    int idx = blockIdx.x * 256 + threadIdx.x;
    if (idx < B_ * N_ * M_) p[idx] = 0.f;
  }
  int n = blockIdx.x * 4 + wid;
  size_t bmN = (size_t)(b * M_ + m) * N_;
  float4 f = *(const float4*)(feat + (bmN + n) * HD + lane * 4);
  float4 a4 = *(const float4*)(al + m * HD + lane * 4);
  float4 r4 = *(const float4*)(ar + m * HD + lane * 4);
  float vl = f.x * a4.x + f.y * a4.y + f.z * a4.z + f.w * a4.w;
  float vr = f.x * r4.x + f.y * r4.y + f.z * r4.z + f.w * r4.w;
#pragma unroll
  for (int s = 1; s < 16; s <<= 1) {
    vl += __shfl_xor(vl, s, 64);
    vr += __shfl_xor(vr, s, 64);
  }
  if ((lane & 15) == 0) {
    int h = lane >> 4;
    el[(bmN + n) * H_ + h] = vl;
    er[(bmN + n) * H_ + h] = vr;
  }
}

// ---------------------------------------------------------------------------
// GAT aggregation: one wave per destination, barrier-free, direct exp.
// el/er loaded from precomputed buffers (broadcast L2 hits).
// XCD-chunked block swizzle: consecutive dests of one (b,m) slice share an
// XCD's L2 (feat slice = 1 MB < 4 MB per-XCD L2). nwg=5000=8*625 (bijective).
// Writes zb fp32 + zbh bf16.
// ---------------------------------------------------------------------------
__global__ __launch_bounds__(256) void gat_agg(
    const unsigned long long* __restrict__ maskW, const float* __restrict__ feat,
    const float* __restrict__ el, const float* __restrict__ er,
    const float* __restrict__ gb, float* __restrict__ zout,
    u16* __restrict__ zbh) {
  int wid = threadIdx.x >> 6, lane = threadIdx.x & 63;
  const int NWGQ = (B_ * M_ * N_ / 4) / 8;  // 625
  int orig = blockIdx.x;
  int bid = (orig & 7) * NWGQ + (orig >> 3);  // XCD-chunked, bijective
  int gw = bid * 4 + wid;
  int d = gw % N_, bm = gw / N_;
  int m = bm % M_, b = bm / M_;
  __shared__ int slist_all[4][1024];
  int* slist = slist_all[wid];

  const unsigned long long* mrow = maskW + ((size_t)bm * N_ + d) * NW;
  int cnt = 0;
#pragma unroll
  for (int w16 = 0; w16 < NW; ++w16) {
    unsigned long long word = mrow[w16];
    if (word) {
      if ((word >> lane) & 1ull) {
        int pos = cnt + (int)__popcll(word & ((1ull << lane) - 1ull));
        slist[pos] = w16 * 64 + lane;
      }
      cnt += (int)__popcll(word);
    }
  }

  int h = lane >> 4;
  float4 bias4 = *(const float4*)(gb + m * HD + lane * 4);
  size_t zoff = ((size_t)(b * N_ + d) * M_ + m) * HD + lane * 4;
  float4 o;
  if (cnt == 0) {
    o.x = bias4.x > 0.f ? bias4.x : (__expf(bias4.x) - 1.f);
    o.y = bias4.y > 0.f ? bias4.y : (__expf(bias4.y) - 1.f);
    o.z = bias4.z > 0.f ? bias4.z : (__expf(bias4.z) - 1.f);
    o.w = bias4.w > 0.f ? bias4.w : (__expf(bias4.w) - 1.f);
  } else {
    size_t bmN = (size_t)bm * N_;
    float erv = er[(bmN + d) * H_ + h];
    const float* elb = el + bmN * H_;
    const float* fb = feat + bmN * HD;
    float den = 0.f, ax = 0.f, ay = 0.f, az = 0.f, aw = 0.f;
    float4 f = *(const float4*)(fb + (size_t)slist[0] * HD + lane * 4);
    for (int i = 0; i < cnt; ++i) {
      float4 fn;
      if (i + 1 < cnt)
        fn = *(const float4*)(fb + (size_t)slist[i + 1] * HD + lane * 4);
      float v = elb[(size_t)slist[i] * H_ + h] + erv;
      v = v > 0.f ? v : 0.2f * v;  // leaky_relu
      float w = __expf(v);         // no max needed: |v| bounded << 80
      den += w;
      ax += w * f.x; ay += w * f.y; az += w * f.z; aw += w * f.w;
      f = fn;
    }
    float inv = 1.f / den;
    float vx = ax * inv + bias4.x;
    float vy = ay * inv + bias4.y;
    float vz = az * inv + bias4.z;
    float vw = aw * inv + bias4.w;
    o.x = vx > 0.f ? vx : (__expf(vx) - 1.f);
    o.y = vy > 0.f ? vy : (__expf(vy) - 1.f);
    o.z = vz > 0.f ? vz : (__expf(vz) - 1.f);
    o.w = vw > 0.f ? vw : (__expf(vw) - 1.f);
  }
  *(float4*)(zout + zoff) = o;
  ushort4 hh;
  hh.x = bf16_bits(o.x);
  hh.y = bf16_bits(o.y);
  hh.z = bf16_bits(o.z);
  hh.w = bf16_bits(o.w);
  *(ushort4*)(zbh + zoff) = hh;
}

// ---------------------------------------------------------------------------
// Semantic GEMM: p[row] += sum_col tanh(A@W1+b1)[row,col] * W2[col].
// A bf16-only (1 mfma). Epilogue: 16-lane shuffle reduce + atomicAdd into p.
// ---------------------------------------------------------------------------
__global__ __launch_bounds__(256) void gemm_sem(
    const u16* __restrict__ Ah, const u16* __restrict__ Bh,
    const float* __restrict__ bias, const float* __restrict__ W2,
    float* __restrict__ p, int Mrows) {
  __shared__ u16 sA[64][40], sB[64][40];
  int row0 = blockIdx.x * 64, col0 = blockIdx.y * 64;
  int tid = threadIdx.x;
  int arow = tid >> 2, akq = (tid & 3) * 8;
  int wid = tid >> 6, lane = tid & 63;
  int wr = (wid >> 1) * 32, wc = (wid & 1) * 32;
  int lrow = lane & 15, kseg = (lane >> 4) * 8;
  f32x4 zero4 = {0.f, 0.f, 0.f, 0.f};
  f32x4 acc[2][2];
  acc[0][0] = zero4; acc[0][1] = zero4; acc[1][0] = zero4; acc[1][1] = zero4;
  for (int k0 = 0; k0 < HD; k0 += 32) {
    us8 av = {0, 0, 0, 0, 0, 0, 0, 0};
    int gr = row0 + arow;
    if (gr < Mrows) av = *(const us8*)(Ah + (size_t)gr * HD + k0 + akq);
    *(us8*)&sA[arow][akq] = av;
    us8 bv = *(const us8*)(Bh + (size_t)(col0 + arow) * HD + k0 + akq);
    *(us8*)&sB[arow][akq] = bv;
    __syncthreads();
    s16x8 aH[2], bH[2];
#pragma unroll
    for (int i = 0; i < 2; ++i) {
      aH[i] = *(const s16x8*)&sA[wr + 16 * i + lrow][kseg];
      bH[i] = *(const s16x8*)&sB[wc + 16 * i + lrow][kseg];
    }
#pragma unroll
    for (int i = 0; i < 2; ++i)
#pragma unroll
      for (int j = 0; j < 2; ++j)
        acc[i][j] = __builtin_amdgcn_mfma_f32_16x16x32_bf16(aH[i], bH[j], acc[i][j], 0, 0, 0);
    __syncthreads();
  }
#pragma unroll
  for (int i = 0; i < 2; ++i) {
#pragma unroll
    for (int r = 0; r < 4; ++r) {
      float part = 0.f;
#pragma unroll
      for (int j = 0; j < 2; ++j) {
        int ccol = col0 + wc + 16 * j + lrow;
        float v = tanhf(acc[i][j][r] + bias[ccol]);
        part += v * W2[ccol];
      }
#pragma unroll
      for (int s = 1; s < 16; s <<= 1) part += __shfl_xor(part, s, 64);
      int crow = row0 + wr + 16 * i + (lane >> 4) * 4 + r;
      if (lrow == 0 && crow < Mrows) atomicAdd(&p[crow], part);
    }
  }
}

// ---------------------------------------------------------------------------
// beta = softmax_m( sum_{b,n valid} p[b,n,m] / sum(node_nums) )  — 1 block
// ---------------------------------------------------------------------------
__global__ __launch_bounds__(256) void sem_beta(const float* __restrict__ p,
                                                const int* __restrict__ node_nums,
                                                float* __restrict__ beta) {
  __shared__ float red[256][M_];
  int tid = threadIdx.x;
  float loc[M_] = {};
  int nn0 = node_nums[0], nn1 = node_nums[1], nn2 = node_nums[2], nn3 = node_nums[3];
  for (int r = tid; r < B_ * N_ * M_; r += 256) {
    int m = r % M_;
    int bn = r / M_;
    int b = bn / N_, n = bn % N_;
    int nn = (b == 0) ? nn0 : (b == 1) ? nn1 : (b == 2) ? nn2 : nn3;
    if (n < nn) loc[m] += p[r];
  }
  for (int m = 0; m < M_; ++m) red[tid][m] = loc[m];
  __syncthreads();
  for (int st = 128; st > 0; st >>= 1) {
    if (tid < st)
      for (int m = 0; m < M_; ++m) red[tid][m] += red[tid + st][m];
    __syncthreads();
  }
  if (tid == 0) {
    float tot = (float)(nn0 + nn1 + nn2 + nn3);
    float w[M_], mx = -1e30f;
    for (int m = 0; m < M_; ++m) {
      w[m] = red[0][m] / tot;
      mx = fmaxf(mx, w[m]);
    }
    float s = 0.f;
    for (int m = 0; m < M_; ++m) {
      w[m] = __expf(w[m] - mx);
      s += w[m];
    }
    for (int m = 0; m < M_; ++m) beta[m] = w[m] / s;
  }
}

// ---------------------------------------------------------------------------
// h[b,n,hd] = sum_m beta[m] * z[b,n,m,hd]  (fp32 out; L2 GEMM splits itself)
// ---------------------------------------------------------------------------
__global__ __launch_bounds__(256) void sem_combine(const float* __restrict__ zb,
                                                   const float* __restrict__ beta,
                                                   float* __restrict__ hout) {
  int idx = blockIdx.x * 256 + threadIdx.x;
  int hd = idx & (HD - 1);
  int bn = idx >> 8;
  const float* zr = zb + (size_t)bn * M_ * HD + hd;
  float v = beta[0] * zr[0] + beta[1] * zr[HD] + beta[2] * zr[2 * HD] +
            beta[3] * zr[3 * HD] + beta[4] * zr[4 * HD];
  hout[idx] = v;
}

// ---------------------------------------------------------------------------
// Layer-2 combine fused with prediction head: one wave per row.
// ---------------------------------------------------------------------------
__global__ __launch_bounds__(256) void sem_combine_pred(
    const float* __restrict__ zb, const float* __restrict__ beta,
    const float* __restrict__ W, const float* __restrict__ bias,
    const int* __restrict__ node_nums, float* __restrict__ out) {
  int row = blockIdx.x * 4 + (threadIdx.x >> 6);
  int lane = threadIdx.x & 63;
  int b = row / N_, n = row % N_;
  const float* zr = zb + (size_t)row * M_ * HD + lane * 4;
  float b0 = beta[0], b1 = beta[1], b2 = beta[2], b3 = beta[3], b4 = beta[4];
  float4 z0 = *(const float4*)(zr);
  float4 z1 = *(const float4*)(zr + HD);
  float4 z2 = *(const float4*)(zr + 2 * HD);
  float4 z3 = *(const float4*)(zr + 3 * HD);
  float4 z4 = *(const float4*)(zr + 4 * HD);
  float hx = b0 * z0.x + b1 * z1.x + b2 * z2.x + b3 * z3.x + b4 * z4.x;
  float hy = b0 * z0.y + b1 * z1.y + b2 * z2.y + b3 * z3.y + b4 * z4.y;
  float hz = b0 * z0.z + b1 * z1.z + b2 * z2.z + b3 * z3.z + b4 * z4.z;
  float hw = b0 * z0.w + b1 * z1.w + b2 * z2.w + b3 * z3.w + b4 * z4.w;
  int k = lane * 4;
  float res[OUTD];
#pragma unroll
  for (int o = 0; o < OUTD; ++o) {
    float v = hx * W[(k + 0) * OUTD + o] + hy * W[(k + 1) * OUTD + o] +
              hz * W[(k + 2) * OUTD + o] + hw * W[(k + 3) * OUTD + o];
#pragma unroll
    for (int s = 1; s < 64; s <<= 1) v += __shfl_xor(v, s, 64);
    res[o] = v;
  }
  if (lane == 0) {
    float nm = (n < node_nums[b]) ? 1.f : 0.f;
#pragma unroll
    for (int o = 0; o < OUTD; ++o)
      out[(size_t)row * OUTD + o] = (res[o] + bias[o]) * nm;
  }
}

extern "C" void kernel_launch(void* const* d_in, const int* in_sizes, int n_in,
                              void* d_out, int out_size, void* d_ws, size_t ws_size,
                              hipStream_t stream) {
  const float* x = (const float*)d_in[0];
  const float* adj = (const float*)d_in[1];
  const int* node_nums = (const int*)d_in[2];
  const float* fc1 = (const float*)d_in[3];
  const float* al1 = (const float*)d_in[4];
  const float* ar1 = (const float*)d_in[5];
  const float* gb1 = (const float*)d_in[6];
  const float* sW1_1 = (const float*)d_in[7];
  const float* sb1_1 = (const float*)d_in[8];
  const float* sW2_1 = (const float*)d_in[9];
  const float* fc2 = (const float*)d_in[10];
  const float* al2 = (const float*)d_in[11];
  const float* ar2 = (const float*)d_in[12];
  const float* gb2 = (const float*)d_in[13];
  const float* sW1_2 = (const float*)d_in[14];
  const float* sb1_2 = (const float*)d_in[15];
  const float* sW2_2 = (const float*)d_in[16];
  const float* predW = (const float*)d_in[17];
  const float* predb = (const float*)d_in[18];
  float* out = (float*)d_out;

  char* ws = (char*)d_ws;
  size_t off = 0;
  unsigned long long* maskW = (unsigned long long*)(ws + off);
  off += (size_t)B_ * M_ * N_ * NW * 8;
  float* feat = (float*)(ws + off); off += (size_t)B_ * M_ * N_ * HD * 4;
  float* el = (float*)(ws + off); off += (size_t)B_ * M_ * N_ * H_ * 4;
  float* er = (float*)(ws + off); off += (size_t)B_ * M_ * N_ * H_ * 4;
  float* zb = (float*)(ws + off); off += (size_t)B_ * N_ * M_ * HD * 4;
  float* h1 = (float*)(ws + off); off += (size_t)B_ * N_ * HD * 4;
  float* p = (float*)(ws + off); off += (size_t)B_ * N_ * M_ * 4;
  float* beta = (float*)(ws + off); off += 64;
  u16* fc1Th = (u16*)(ws + off); off += (size_t)M_ * HD * FIN * 2;
  u16* fc1Tl = (u16*)(ws + off); off += (size_t)M_ * HD * FIN * 2;
  u16* fc2Th = (u16*)(ws + off); off += (size_t)M_ * HD * HD * 2;
  u16* fc2Tl = (u16*)(ws + off); off += (size_t)M_ * HD * HD * 2;
  u16* sW1Th1 = (u16*)(ws + off); off += (size_t)SH * HD * 2;
  u16* sW1Tl1 = (u16*)(ws + off); off += (size_t)SH * HD * 2;
  u16* sW1Th2 = (u16*)(ws + off); off += (size_t)SH * HD * 2;
  u16* sW1Tl2 = (u16*)(ws + off); off += (size_t)SH * HD * 2;
  u16* zbh = (u16*)(ws + off); off += (size_t)B_ * N_ * M_ * HD * 2;

  const int ROWS = B_ * N_ * M_;  // 20000
  const int PREP_BLOCKS = 5120 + 80 + 320 + 32 + 32;  // 5584

  prep_all<<<dim3(PREP_BLOCKS), 256, 0, stream>>>(
      adj, node_nums, maskW, fc1, fc1Th, fc1Tl, fc2, fc2Th, fc2Tl,
      sW1_1, sW1Th1, sW1Tl1, sW1_2, sW1Th2, sW1Tl2);

  // ---- layer 1 ----
  gemm_mfma3<<<dim3(16, HD / 64, B_ * M_), 256, 0, stream>>>(
      x, M_, (size_t)M_ * N_ * FIN, fc1Th, fc1Tl, (size_t)HD * FIN,
      feat, (size_t)N_ * HD, N_, FIN, HD);
  elr_kernel<<<dim3(N_ / 4, M_, B_), 256, 0, stream>>>(feat, al1, ar1, el, er, p);
  gat_agg<<<dim3(ROWS / 4), 256, 0, stream>>>(maskW, feat, el, er, gb1, zb, zbh);
  gemm_sem<<<dim3((ROWS + 63) / 64, SH / 64), 256, 0, stream>>>(
      zbh, sW1Th1, sb1_1, sW2_1, p, ROWS);
  sem_beta<<<dim3(1), 256, 0, stream>>>(p, node_nums, beta);
  sem_combine<<<dim3(B_ * N_ * HD / 256), 256, 0, stream>>>(zb, beta, h1);

  // ---- layer 2 ----
  gemm_mfma3<<<dim3(16, HD / 64, B_ * M_), 256, 0, stream>>>(
      h1, M_, (size_t)N_ * HD, fc2Th, fc2Tl, (size_t)HD * HD,
      feat, (size_t)N_ * HD, N_, HD, HD);
  elr_kernel<<<dim3(N_ / 4, M_, B_), 256, 0, stream>>>(feat, al2, ar2, el, er, p);
  gat_agg<<<dim3(ROWS / 4), 256, 0, stream>>>(maskW, feat, el, er, gb2, zb, zbh);
  gemm_sem<<<dim3((ROWS + 63) / 64, SH / 64), 256, 0, stream>>>(
      zbh, sW1Th2, sb1_2, sW2_2, p, ROWS);
  sem_beta<<<dim3(1), 256, 0, stream>>>(p, node_nums, beta);
  sem_combine_pred<<<dim3(B_ * N_ / 4), 256, 0, stream>>>(
      zb, beta, predW, predb, node_nums, out);
}

// Round 9
// 214.970 us; speedup vs baseline: 1.3658x; 1.0533x over previous
//
#include <hip/hip_runtime.h>
#include <hip/hip_bf16.h>

#define B_ 4
#define M_ 5
#define N_ 1000
#define FIN 64
#define H_ 4
#define D_ 64
#define HD 256
#define SH 128
#define OUTD 5
#define NW 16  // u64 words per dest row (1024/64)
#define THRESH_ 0.97f

typedef unsigned short u16;
typedef u16 us8 __attribute__((ext_vector_type(8)));
typedef short s16x8 __attribute__((ext_vector_type(8)));
typedef float f32x4 __attribute__((ext_vector_type(4)));

__device__ inline u16 bf16_bits(float v) {
  __hip_bfloat16 h = __float2bfloat16(v);
  return *reinterpret_cast<u16*>(&h);
}
__device__ inline float bf16_val(u16 b) {
  __hip_bfloat16 h;
  *reinterpret_cast<u16*>(&h) = b;
  return __bfloat162float(h);
}
__device__ inline void split2(float v, u16& h, u16& l) {
  h = bf16_bits(v);
  l = bf16_bits(v - bf16_val(h));
}

// ---------------------------------------------------------------------------
// prep_all: one launch doing (a) bit-packed transposed edge mask build and
// (b) all weight transpose+split jobs, selected by block range.
// ---------------------------------------------------------------------------
__device__ void splitT_body(const float* __restrict__ s, u16* __restrict__ hiT,
                            u16* __restrict__ loT, int K, int N, int k0, int n0,
                            char* smem) {
  float(*tile)[33] = (float(*)[33])smem;
  int tid = threadIdx.x;
  int kl = tid >> 3, nq = (tid & 7) * 4;
  *(float4*)&tile[kl][nq] = *(const float4*)(s + (size_t)(k0 + kl) * N + n0 + nq);
  __syncthreads();
  int nl = tid >> 3, kq = (tid & 7) * 4;
  ushort4 h, l;
  split2(tile[kq + 0][nl], h.x, l.x);
  split2(tile[kq + 1][nl], h.y, l.y);
  split2(tile[kq + 2][nl], h.z, l.z);
  split2(tile[kq + 3][nl], h.w, l.w);
  size_t o = (size_t)(n0 + nl) * K + k0 + kq;
  *(ushort4*)(hiT + o) = h;
  *(ushort4*)(loT + o) = l;
}

__global__ __launch_bounds__(256) void prep_all(
    const float* __restrict__ adj, const int* __restrict__ node_nums,
    unsigned long long* __restrict__ maskW,
    const float* __restrict__ fc1, u16* __restrict__ fc1Th, u16* __restrict__ fc1Tl,
    const float* __restrict__ fc2, u16* __restrict__ fc2Th, u16* __restrict__ fc2Tl,
    const float* __restrict__ sW1_1, u16* __restrict__ sW1Th1, u16* __restrict__ sW1Tl1,
    const float* __restrict__ sW1_2, u16* __restrict__ sW1Th2, u16* __restrict__ sW1Tl2) {
  __shared__ __align__(16) char smem[4608];
  int bi = blockIdx.x;
  int tid = threadIdx.x;
  if (bi < 5120) {
    // ---- edge-mask build ----
    int bx = bi & 15, by = (bi >> 4) & 15, bm = bi >> 8;
    int b = bm / M_;
    int s0 = bx * 64, d0 = by * 64;
    int nn = node_nums[b];
    unsigned char(*tile)[65] = (unsigned char(*)[65])smem;
    const float* arow = adj + (size_t)bm * N_ * N_;
#pragma unroll
    for (int k = 0; k < 16; ++k) {
      int idx = k * 256 + tid;
      int sl = idx >> 6, dl = idx & 63;
      int s = s0 + sl, d = d0 + dl;
      unsigned char v = 0;
      if (s < nn && d < nn && s < N_ && d < N_)
        v = (arow[(size_t)s * N_ + d] > THRESH_) ? 1 : 0;
      tile[sl][dl] = v;
    }
    __syncthreads();
    int w = tid >> 6, lane = tid & 63;
#pragma unroll
    for (int j = 0; j < 16; ++j) {
      int dl = w * 16 + j;
      bool act = tile[lane][dl] != 0;
      unsigned long long word = __ballot(act);
      int d = d0 + dl;
      if (lane == 0 && d < N_)
        maskW[((size_t)bm * N_ + d) * NW + bx] = word;
    }
    return;
  }
  bi -= 5120;
  if (bi < 80) {  // fc1 (M, FIN, HD) -> (M, HD, FIN) hi/lo
    int kx = bi % 2, ny = (bi / 2) % 8, z = bi / 16;
    splitT_body(fc1 + (size_t)z * FIN * HD, fc1Th + (size_t)z * HD * FIN,
                fc1Tl + (size_t)z * HD * FIN, FIN, HD, kx * 32, ny * 32, smem);
    return;
  }
  bi -= 80;
  if (bi < 320) {  // fc2 (M, HD, HD) -> (M, HD, HD)T hi/lo
    int kx = bi % 8, ny = (bi / 8) % 8, z = bi / 64;
    splitT_body(fc2 + (size_t)z * HD * HD, fc2Th + (size_t)z * HD * HD,
                fc2Tl + (size_t)z * HD * HD, HD, HD, kx * 32, ny * 32, smem);
    return;
  }
  bi -= 320;
  if (bi < 32) {  // sW1_1 (HD, SH) -> (SH, HD) hi/lo
    int kx = bi % 8, ny = bi / 8;
    splitT_body(sW1_1, sW1Th1, sW1Tl1, HD, SH, kx * 32, ny * 32, smem);
    return;
  }
  bi -= 32;
  {  // sW1_2
    int kx = bi % 8, ny = bi / 8;
    splitT_body(sW1_2, sW1Th2, sW1Tl2, HD, SH, kx * 32, ny * 32, smem);
  }
}

// ---------------------------------------------------------------------------
// Split-bf16 MFMA GEMM (feat): C[z] = A[z] @ B[z]^T-stored.
// A is fp32; hi/lo split happens in registers during LDS staging.
// 3 mfma/product (hh+hl+lh) = fp32-grade accuracy.
// ---------------------------------------------------------------------------
__global__ __launch_bounds__(256) void gemm_mfma3(
    const float* __restrict__ A, int Mz, size_t aZ,
    const u16* __restrict__ Bh, const u16* __restrict__ Bl, size_t bZ,
    float* __restrict__ C, size_t cZ, int Mrows, int K, int Nc) {
  __shared__ u16 sAh[64][40], sAl[64][40], sBh[64][40], sBl[64][40];
  int z = blockIdx.z;
  const float* Ab = A + (size_t)(z / Mz) * aZ;
  const u16* Bhb = Bh + (size_t)(z % Mz) * bZ;
  const u16* Blb = Bl + (size_t)(z % Mz) * bZ;
  float* Cb = C + (size_t)z * cZ;
  int row0 = blockIdx.x * 64, col0 = blockIdx.y * 64;
  int tid = threadIdx.x;
  int arow = tid >> 2, akq = (tid & 3) * 8;
  int wid = tid >> 6, lane = tid & 63;
  int wr = (wid >> 1) * 32, wc = (wid & 1) * 32;
  int lrow = lane & 15, kseg = (lane >> 4) * 8;
  f32x4 zero4 = {0.f, 0.f, 0.f, 0.f};
  f32x4 acc[2][2];
  acc[0][0] = zero4; acc[0][1] = zero4; acc[1][0] = zero4; acc[1][1] = zero4;
  for (int k0 = 0; k0 < K; k0 += 32) {
    float4 a0 = make_float4(0.f, 0.f, 0.f, 0.f), a1 = a0;
    int gr = row0 + arow;
    if (gr < Mrows) {
      const float* ap = Ab + (size_t)gr * K + k0 + akq;
      a0 = *(const float4*)ap;
      a1 = *(const float4*)(ap + 4);
    }
    us8 hv, lv;
    {
      u16 th, tl;
      split2(a0.x, th, tl); hv[0] = th; lv[0] = tl;
      split2(a0.y, th, tl); hv[1] = th; lv[1] = tl;
      split2(a0.z, th, tl); hv[2] = th; lv[2] = tl;
      split2(a0.w, th, tl); hv[3] = th; lv[3] = tl;
      split2(a1.x, th, tl); hv[4] = th; lv[4] = tl;
      split2(a1.y, th, tl); hv[5] = th; lv[5] = tl;
      split2(a1.z, th, tl); hv[6] = th; lv[6] = tl;
      split2(a1.w, th, tl); hv[7] = th; lv[7] = tl;
    }
    *(us8*)&sAh[arow][akq] = hv;
    *(us8*)&sAl[arow][akq] = lv;
    us8 bv = *(const us8*)(Bhb + (size_t)(col0 + arow) * K + k0 + akq);
    us8 blv = *(const us8*)(Blb + (size_t)(col0 + arow) * K + k0 + akq);
    *(us8*)&sBh[arow][akq] = bv;
    *(us8*)&sBl[arow][akq] = blv;
    __syncthreads();
    s16x8 aH[2], aL[2], bH[2], bL[2];
#pragma unroll
    for (int i = 0; i < 2; ++i) {
      aH[i] = *(const s16x8*)&sAh[wr + 16 * i + lrow][kseg];
      aL[i] = *(const s16x8*)&sAl[wr + 16 * i + lrow][kseg];
      bH[i] = *(const s16x8*)&sBh[wc + 16 * i + lrow][kseg];
      bL[i] = *(const s16x8*)&sBl[wc + 16 * i + lrow][kseg];
    }
#pragma unroll
    for (int i = 0; i < 2; ++i)
#pragma unroll
      for (int j = 0; j < 2; ++j) {
        acc[i][j] = __builtin_amdgcn_mfma_f32_16x16x32_bf16(aH[i], bH[j], acc[i][j], 0, 0, 0);
        acc[i][j] = __builtin_amdgcn_mfma_f32_16x16x32_bf16(aH[i], bL[j], acc[i][j], 0, 0, 0);
        acc[i][j] = __builtin_amdgcn_mfma_f32_16x16x32_bf16(aL[i], bH[j], acc[i][j], 0, 0, 0);
      }
    __syncthreads();
  }
#pragma unroll
  for (int i = 0; i < 2; ++i)
#pragma unroll
    for (int j = 0; j < 2; ++j) {
      int ccol = col0 + wc + 16 * j + lrow;
#pragma unroll
      for (int r = 0; r < 4; ++r) {
        int crow = row0 + wr + 16 * i + (lane >> 4) * 4 + r;
        if (crow < Mrows) Cb[(size_t)crow * Nc + ccol] = acc[i][j][r];
      }
    }
}

// ---------------------------------------------------------------------------
// el/er: wave-per-row, 16-lane reduce per head. Also zeroes p for gemm_sem.
// ---------------------------------------------------------------------------
__global__ __launch_bounds__(256) void elr_kernel(
    const float* __restrict__ feat, const float* __restrict__ al,
    const float* __restrict__ ar, float* __restrict__ el,
    float* __restrict__ er, float* __restrict__ p) {
  int b = blockIdx.z, m = blockIdx.y;
  int wid = threadIdx.x >> 6, lane = threadIdx.x & 63;
  if (blockIdx.y == 0 && blockIdx.z == 0) {
    int idx = blockIdx.x * 256 + threadIdx.x;
    if (idx < B_ * N_ * M_) p[idx] = 0.f;
  }
  int n = blockIdx.x * 4 + wid;
  size_t bmN = (size_t)(b * M_ + m) * N_;
  float4 f = *(const float4*)(feat + (bmN + n) * HD + lane * 4);
  float4 a4 = *(const float4*)(al + m * HD + lane * 4);
  float4 r4 = *(const float4*)(ar + m * HD + lane * 4);
  float vl = f.x * a4.x + f.y * a4.y + f.z * a4.z + f.w * a4.w;
  float vr = f.x * r4.x + f.y * r4.y + f.z * r4.z + f.w * r4.w;
#pragma unroll
  for (int s = 1; s < 16; s <<= 1) {
    vl += __shfl_xor(vl, s, 64);
    vr += __shfl_xor(vr, s, 64);
  }
  if ((lane & 15) == 0) {
    int h = lane >> 4;
    el[(bmN + n) * H_ + h] = vl;
    er[(bmN + n) * H_ + h] = vr;
  }
}

// ---------------------------------------------------------------------------
// GAT aggregation: one wave per destination, barrier-free, direct exp.
// 4-edge batched inner loop: one int4 slist read + 8 loads (4 el + 4 feat)
// issued together, then 4 independent accumulation chains — exposes 1 memory
// round-trip per 4 edges instead of per edge. Tail handled by zero-masking.
// XCD-chunked block swizzle for feat L2 locality.
// ---------------------------------------------------------------------------
__global__ __launch_bounds__(256) void gat_agg(
    const unsigned long long* __restrict__ maskW, const float* __restrict__ feat,
    const float* __restrict__ el, const float* __restrict__ er,
    const float* __restrict__ gb, float* __restrict__ zout,
    u16* __restrict__ zbh) {
  int wid = threadIdx.x >> 6, lane = threadIdx.x & 63;
  const int NWGQ = (B_ * M_ * N_ / 4) / 8;  // 625
  int orig = blockIdx.x;
  int bid = (orig & 7) * NWGQ + (orig >> 3);  // XCD-chunked, bijective
  int gw = bid * 4 + wid;
  int d = gw % N_, bm = gw / N_;
  int m = bm % M_, b = bm / M_;
  __shared__ int slist_all[4][1024];
  int* slist = slist_all[wid];

  const unsigned long long* mrow = maskW + ((size_t)bm * N_ + d) * NW;
  int cnt = 0;
#pragma unroll
  for (int w16 = 0; w16 < NW; ++w16) {
    unsigned long long word = mrow[w16];
    if (word) {
      if ((word >> lane) & 1ull) {
        int pos = cnt + (int)__popcll(word & ((1ull << lane) - 1ull));
        slist[pos] = w16 * 64 + lane;
      }
      cnt += (int)__popcll(word);
    }
  }

  int h = lane >> 4;
  float4 bias4 = *(const float4*)(gb + m * HD + lane * 4);
  size_t zoff = ((size_t)(b * N_ + d) * M_ + m) * HD + lane * 4;
  float4 o;
  if (cnt == 0) {
    o.x = bias4.x > 0.f ? bias4.x : (__expf(bias4.x) - 1.f);
    o.y = bias4.y > 0.f ? bias4.y : (__expf(bias4.y) - 1.f);
    o.z = bias4.z > 0.f ? bias4.z : (__expf(bias4.z) - 1.f);
    o.w = bias4.w > 0.f ? bias4.w : (__expf(bias4.w) - 1.f);
  } else {
    if (lane < 4) slist[cnt + lane] = slist[0];  // pad to safe multiple of 4
    size_t bmN = (size_t)bm * N_;
    float erv = er[(bmN + d) * H_ + h];
    const float* elb = el + bmN * H_;
    const float* fb = feat + bmN * HD;
    int lane4 = lane * 4;
    float den0 = 0.f, den1 = 0.f, den2 = 0.f, den3 = 0.f;
    f32x4 A0 = {0.f, 0.f, 0.f, 0.f}, A1 = A0, A2 = A0, A3 = A0;
    for (int i = 0; i < cnt; i += 4) {
      int4 s4 = *(const int4*)&slist[i];
      // issue all 8 loads up front (independent)
      float e0 = elb[(size_t)s4.x * H_ + h];
      float e1 = elb[(size_t)s4.y * H_ + h];
      float e2 = elb[(size_t)s4.z * H_ + h];
      float e3 = elb[(size_t)s4.w * H_ + h];
      f32x4 f0 = *(const f32x4*)(fb + (size_t)s4.x * HD + lane4);
      f32x4 f1 = *(const f32x4*)(fb + (size_t)s4.y * HD + lane4);
      f32x4 f2 = *(const f32x4*)(fb + (size_t)s4.z * HD + lane4);
      f32x4 f3 = *(const f32x4*)(fb + (size_t)s4.w * HD + lane4);
      float v0 = e0 + erv; v0 = v0 > 0.f ? v0 : 0.2f * v0;
      float v1 = e1 + erv; v1 = v1 > 0.f ? v1 : 0.2f * v1;
      float v2 = e2 + erv; v2 = v2 > 0.f ? v2 : 0.2f * v2;
      float v3 = e3 + erv; v3 = v3 > 0.f ? v3 : 0.2f * v3;
      float w0 = __expf(v0);
      float w1 = __expf(v1) * ((i + 1 < cnt) ? 1.f : 0.f);
      float w2 = __expf(v2) * ((i + 2 < cnt) ? 1.f : 0.f);
      float w3 = __expf(v3) * ((i + 3 < cnt) ? 1.f : 0.f);
      den0 += w0; den1 += w1; den2 += w2; den3 += w3;
      A0 += w0 * f0; A1 += w1 * f1; A2 += w2 * f2; A3 += w3 * f3;
    }
    float den = (den0 + den1) + (den2 + den3);
    f32x4 A = (A0 + A1) + (A2 + A3);
    float inv = 1.f / den;
    float vx = A[0] * inv + bias4.x;
    float vy = A[1] * inv + bias4.y;
    float vz = A[2] * inv + bias4.z;
    float vw = A[3] * inv + bias4.w;
    o.x = vx > 0.f ? vx : (__expf(vx) - 1.f);
    o.y = vy > 0.f ? vy : (__expf(vy) - 1.f);
    o.z = vz > 0.f ? vz : (__expf(vz) - 1.f);
    o.w = vw > 0.f ? vw : (__expf(vw) - 1.f);
  }
  *(float4*)(zout + zoff) = o;
  ushort4 hh;
  hh.x = bf16_bits(o.x);
  hh.y = bf16_bits(o.y);
  hh.z = bf16_bits(o.z);
  hh.w = bf16_bits(o.w);
  *(ushort4*)(zbh + zoff) = hh;
}

// ---------------------------------------------------------------------------
// Semantic GEMM: p[row] += sum_col tanh(A@W1+b1)[row,col] * W2[col].
// A bf16-only (1 mfma). Epilogue: 16-lane shuffle reduce + atomicAdd into p.
// ---------------------------------------------------------------------------
__global__ __launch_bounds__(256) void gemm_sem(
    const u16* __restrict__ Ah, const u16* __restrict__ Bh,
    const float* __restrict__ bias, const float* __restrict__ W2,
    float* __restrict__ p, int Mrows) {
  __shared__ u16 sA[64][40], sB[64][40];
  int row0 = blockIdx.x * 64, col0 = blockIdx.y * 64;
  int tid = threadIdx.x;
  int arow = tid >> 2, akq = (tid & 3) * 8;
  int wid = tid >> 6, lane = tid & 63;
  int wr = (wid >> 1) * 32, wc = (wid & 1) * 32;
  int lrow = lane & 15, kseg = (lane >> 4) * 8;
  f32x4 zero4 = {0.f, 0.f, 0.f, 0.f};
  f32x4 acc[2][2];
  acc[0][0] = zero4; acc[0][1] = zero4; acc[1][0] = zero4; acc[1][1] = zero4;
  for (int k0 = 0; k0 < HD; k0 += 32) {
    us8 av = {0, 0, 0, 0, 0, 0, 0, 0};
    int gr = row0 + arow;
    if (gr < Mrows) av = *(const us8*)(Ah + (size_t)gr * HD + k0 + akq);
    *(us8*)&sA[arow][akq] = av;
    us8 bv = *(const us8*)(Bh + (size_t)(col0 + arow) * HD + k0 + akq);
    *(us8*)&sB[arow][akq] = bv;
    __syncthreads();
    s16x8 aH[2], bH[2];
#pragma unroll
    for (int i = 0; i < 2; ++i) {
      aH[i] = *(const s16x8*)&sA[wr + 16 * i + lrow][kseg];
      bH[i] = *(const s16x8*)&sB[wc + 16 * i + lrow][kseg];
    }
#pragma unroll
    for (int i = 0; i < 2; ++i)
#pragma unroll
      for (int j = 0; j < 2; ++j)
        acc[i][j] = __builtin_amdgcn_mfma_f32_16x16x32_bf16(aH[i], bH[j], acc[i][j], 0, 0, 0);
    __syncthreads();
  }
#pragma unroll
  for (int i = 0; i < 2; ++i) {
#pragma unroll
    for (int r = 0; r < 4; ++r) {
      float part = 0.f;
#pragma unroll
      for (int j = 0; j < 2; ++j) {
        int ccol = col0 + wc + 16 * j + lrow;
        float v = tanhf(acc[i][j][r] + bias[ccol]);
        part += v * W2[ccol];
      }
#pragma unroll
      for (int s = 1; s < 16; s <<= 1) part += __shfl_xor(part, s, 64);
      int crow = row0 + wr + 16 * i + (lane >> 4) * 4 + r;
      if (lrow == 0 && crow < Mrows) atomicAdd(&p[crow], part);
    }
  }
}

// ---------------------------------------------------------------------------
// beta = softmax_m( sum_{b,n valid} p[b,n,m] / sum(node_nums) )  — 1 block
// ---------------------------------------------------------------------------
__global__ __launch_bounds__(256) void sem_beta(const float* __restrict__ p,
                                                const int* __restrict__ node_nums,
                                                float* __restrict__ beta) {
  __shared__ float red[256][M_];
  int tid = threadIdx.x;
  float loc[M_] = {};
  int nn0 = node_nums[0], nn1 = node_nums[1], nn2 = node_nums[2], nn3 = node_nums[3];
  for (int r = tid; r < B_ * N_ * M_; r += 256) {
    int m = r % M_;
    int bn = r / M_;
    int b = bn / N_, n = bn % N_;
    int nn = (b == 0) ? nn0 : (b == 1) ? nn1 : (b == 2) ? nn2 : nn3;
    if (n < nn) loc[m] += p[r];
  }
  for (int m = 0; m < M_; ++m) red[tid][m] = loc[m];
  __syncthreads();
  for (int st = 128; st > 0; st >>= 1) {
    if (tid < st)
      for (int m = 0; m < M_; ++m) red[tid][m] += red[tid + st][m];
    __syncthreads();
  }
  if (tid == 0) {
    float tot = (float)(nn0 + nn1 + nn2 + nn3);
    float w[M_], mx = -1e30f;
    for (int m = 0; m < M_; ++m) {
      w[m] = red[0][m] / tot;
      mx = fmaxf(mx, w[m]);
    }
    float s = 0.f;
    for (int m = 0; m < M_; ++m) {
      w[m] = __expf(w[m] - mx);
      s += w[m];
    }
    for (int m = 0; m < M_; ++m) beta[m] = w[m] / s;
  }
}

// ---------------------------------------------------------------------------
// h[b,n,hd] = sum_m beta[m] * z[b,n,m,hd]  (fp32 out; L2 GEMM splits itself)
// ---------------------------------------------------------------------------
__global__ __launch_bounds__(256) void sem_combine(const float* __restrict__ zb,
                                                   const float* __restrict__ beta,
                                                   float* __restrict__ hout) {
  int idx = blockIdx.x * 256 + threadIdx.x;
  int hd = idx & (HD - 1);
  int bn = idx >> 8;
  const float* zr = zb + (size_t)bn * M_ * HD + hd;
  float v = beta[0] * zr[0] + beta[1] * zr[HD] + beta[2] * zr[2 * HD] +
            beta[3] * zr[3 * HD] + beta[4] * zr[4 * HD];
  hout[idx] = v;
}

// ---------------------------------------------------------------------------
// Layer-2 combine fused with prediction head: one wave per row.
// ---------------------------------------------------------------------------
__global__ __launch_bounds__(256) void sem_combine_pred(
    const float* __restrict__ zb, const float* __restrict__ beta,
    const float* __restrict__ W, const float* __restrict__ bias,
    const int* __restrict__ node_nums, float* __restrict__ out) {
  int row = blockIdx.x * 4 + (threadIdx.x >> 6);
  int lane = threadIdx.x & 63;
  int b = row / N_, n = row % N_;
  const float* zr = zb + (size_t)row * M_ * HD + lane * 4;
  float b0 = beta[0], b1 = beta[1], b2 = beta[2], b3 = beta[3], b4 = beta[4];
  float4 z0 = *(const float4*)(zr);
  float4 z1 = *(const float4*)(zr + HD);
  float4 z2 = *(const float4*)(zr + 2 * HD);
  float4 z3 = *(const float4*)(zr + 3 * HD);
  float4 z4 = *(const float4*)(zr + 4 * HD);
  float hx = b0 * z0.x + b1 * z1.x + b2 * z2.x + b3 * z3.x + b4 * z4.x;
  float hy = b0 * z0.y + b1 * z1.y + b2 * z2.y + b3 * z3.y + b4 * z4.y;
  float hz = b0 * z0.z + b1 * z1.z + b2 * z2.z + b3 * z3.z + b4 * z4.z;
  float hw = b0 * z0.w + b1 * z1.w + b2 * z2.w + b3 * z3.w + b4 * z4.w;
  int k = lane * 4;
  float res[OUTD];
#pragma unroll
  for (int o = 0; o < OUTD; ++o) {
    float v = hx * W[(k + 0) * OUTD + o] + hy * W[(k + 1) * OUTD + o] +
              hz * W[(k + 2) * OUTD + o] + hw * W[(k + 3) * OUTD + o];
#pragma unroll
    for (int s = 1; s < 64; s <<= 1) v += __shfl_xor(v, s, 64);
    res[o] = v;
  }
  if (lane == 0) {
    float nm = (n < node_nums[b]) ? 1.f : 0.f;
#pragma unroll
    for (int o = 0; o < OUTD; ++o)
      out[(size_t)row * OUTD + o] = (res[o] + bias[o]) * nm;
  }
}

extern "C" void kernel_launch(void* const* d_in, const int* in_sizes, int n_in,
                              void* d_out, int out_size, void* d_ws, size_t ws_size,
                              hipStream_t stream) {
  const float* x = (const float*)d_in[0];
  const float* adj = (const float*)d_in[1];
  const int* node_nums = (const int*)d_in[2];
  const float* fc1 = (const float*)d_in[3];
  const float* al1 = (const float*)d_in[4];
  const float* ar1 = (const float*)d_in[5];
  const float* gb1 = (const float*)d_in[6];
  const float* sW1_1 = (const float*)d_in[7];
  const float* sb1_1 = (const float*)d_in[8];
  const float* sW2_1 = (const float*)d_in[9];
  const float* fc2 = (const float*)d_in[10];
  const float* al2 = (const float*)d_in[11];
  const float* ar2 = (const float*)d_in[12];
  const float* gb2 = (const float*)d_in[13];
  const float* sW1_2 = (const float*)d_in[14];
  const float* sb1_2 = (const float*)d_in[15];
  const float* sW2_2 = (const float*)d_in[16];
  const float* predW = (const float*)d_in[17];
  const float* predb = (const float*)d_in[18];
  float* out = (float*)d_out;

  char* ws = (char*)d_ws;
  size_t off = 0;
  unsigned long long* maskW = (unsigned long long*)(ws + off);
  off += (size_t)B_ * M_ * N_ * NW * 8;
  float* feat = (float*)(ws + off); off += (size_t)B_ * M_ * N_ * HD * 4;
  float* el = (float*)(ws + off); off += (size_t)B_ * M_ * N_ * H_ * 4;
  float* er = (float*)(ws + off); off += (size_t)B_ * M_ * N_ * H_ * 4;
  float* zb = (float*)(ws + off); off += (size_t)B_ * N_ * M_ * HD * 4;
  float* h1 = (float*)(ws + off); off += (size_t)B_ * N_ * HD * 4;
  float* p = (float*)(ws + off); off += (size_t)B_ * N_ * M_ * 4;
  float* beta = (float*)(ws + off); off += 64;
  u16* fc1Th = (u16*)(ws + off); off += (size_t)M_ * HD * FIN * 2;
  u16* fc1Tl = (u16*)(ws + off); off += (size_t)M_ * HD * FIN * 2;
  u16* fc2Th = (u16*)(ws + off); off += (size_t)M_ * HD * HD * 2;
  u16* fc2Tl = (u16*)(ws + off); off += (size_t)M_ * HD * HD * 2;
  u16* sW1Th1 = (u16*)(ws + off); off += (size_t)SH * HD * 2;
  u16* sW1Tl1 = (u16*)(ws + off); off += (size_t)SH * HD * 2;
  u16* sW1Th2 = (u16*)(ws + off); off += (size_t)SH * HD * 2;
  u16* sW1Tl2 = (u16*)(ws + off); off += (size_t)SH * HD * 2;
  u16* zbh = (u16*)(ws + off); off += (size_t)B_ * N_ * M_ * HD * 2;

  const int ROWS = B_ * N_ * M_;  // 20000
  const int PREP_BLOCKS = 5120 + 80 + 320 + 32 + 32;  // 5584

  prep_all<<<dim3(PREP_BLOCKS), 256, 0, stream>>>(
      adj, node_nums, maskW, fc1, fc1Th, fc1Tl, fc2, fc2Th, fc2Tl,
      sW1_1, sW1Th1, sW1Tl1, sW1_2, sW1Th2, sW1Tl2);

  // ---- layer 1 ----
  gemm_mfma3<<<dim3(16, HD / 64, B_ * M_), 256, 0, stream>>>(
      x, M_, (size_t)M_ * N_ * FIN, fc1Th, fc1Tl, (size_t)HD * FIN,
      feat, (size_t)N_ * HD, N_, FIN, HD);
  elr_kernel<<<dim3(N_ / 4, M_, B_), 256, 0, stream>>>(feat, al1, ar1, el, er, p);
  gat_agg<<<dim3(ROWS / 4), 256, 0, stream>>>(maskW, feat, el, er, gb1, zb, zbh);
  gemm_sem<<<dim3((ROWS + 63) / 64, SH / 64), 256, 0, stream>>>(
      zbh, sW1Th1, sb1_1, sW2_1, p, ROWS);
  sem_beta<<<dim3(1), 256, 0, stream>>>(p, node_nums, beta);
  sem_combine<<<dim3(B_ * N_ * HD / 256), 256, 0, stream>>>(zb, beta, h1);

  // ---- layer 2 ----
  gemm_mfma3<<<dim3(16, HD / 64, B_ * M_), 256, 0, stream>>>(
      h1, M_, (size_t)N_ * HD, fc2Th, fc2Tl, (size_t)HD * HD,
      feat, (size_t)N_ * HD, N_, HD, HD);
  elr_kernel<<<dim3(N_ / 4, M_, B_), 256, 0, stream>>>(feat, al2, ar2, el, er, p);
  gat_agg<<<dim3(ROWS / 4), 256, 0, stream>>>(maskW, feat, el, er, gb2, zb, zbh);
  gemm_sem<<<dim3((ROWS + 63) / 64, SH / 64), 256, 0, stream>>>(
      zbh, sW1Th2, sb1_2, sW2_2, p, ROWS);
  sem_beta<<<dim3(1), 256, 0, stream>>>(p, node_nums, beta);
  sem_combine_pred<<<dim3(B_ * N_ / 4), 256, 0, stream>>>(
      zb, beta, predW, predb, node_nums, out);
}

// Round 10
// 211.019 us; speedup vs baseline: 1.3913x; 1.0187x over previous
//
#include <hip/hip_runtime.h>
#include <hip/hip_bf16.h>

#define B_ 4
#define M_ 5
#define N_ 1000
#define FIN 64
#define H_ 4
#define D_ 64
#define HD 256
#define SH 128
#define OUTD 5
#define NW 16  // u64 words per dest row (1024/64)
#define THRESH_ 0.97f

typedef unsigned short u16;
typedef u16 us8 __attribute__((ext_vector_type(8)));
typedef short s16x8 __attribute__((ext_vector_type(8)));
typedef float f32x4 __attribute__((ext_vector_type(4)));

__device__ inline u16 bf16_bits(float v) {
  __hip_bfloat16 h = __float2bfloat16(v);
  return *reinterpret_cast<u16*>(&h);
}
__device__ inline float bf16_val(u16 b) {
  __hip_bfloat16 h;
  *reinterpret_cast<u16*>(&h) = b;
  return __bfloat162float(h);
}
__device__ inline float b2f(u16 u) {
  union { unsigned int i; float f; } c;
  c.i = ((unsigned int)u) << 16;
  return c.f;
}
__device__ inline void split2(float v, u16& h, u16& l) {
  h = bf16_bits(v);
  l = bf16_bits(v - bf16_val(h));
}

// ---------------------------------------------------------------------------
// prep_all: one launch doing (a) bit-packed transposed edge mask build and
// (b) all weight transpose+split jobs, selected by block range.
// ---------------------------------------------------------------------------
__device__ void splitT_body(const float* __restrict__ s, u16* __restrict__ hiT,
                            u16* __restrict__ loT, int K, int N, int k0, int n0,
                            char* smem) {
  float(*tile)[33] = (float(*)[33])smem;
  int tid = threadIdx.x;
  int kl = tid >> 3, nq = (tid & 7) * 4;
  *(float4*)&tile[kl][nq] = *(const float4*)(s + (size_t)(k0 + kl) * N + n0 + nq);
  __syncthreads();
  int nl = tid >> 3, kq = (tid & 7) * 4;
  ushort4 h, l;
  split2(tile[kq + 0][nl], h.x, l.x);
  split2(tile[kq + 1][nl], h.y, l.y);
  split2(tile[kq + 2][nl], h.z, l.z);
  split2(tile[kq + 3][nl], h.w, l.w);
  size_t o = (size_t)(n0 + nl) * K + k0 + kq;
  *(ushort4*)(hiT + o) = h;
  *(ushort4*)(loT + o) = l;
}

__global__ __launch_bounds__(256) void prep_all(
    const float* __restrict__ adj, const int* __restrict__ node_nums,
    unsigned long long* __restrict__ maskW,
    const float* __restrict__ fc1, u16* __restrict__ fc1Th, u16* __restrict__ fc1Tl,
    const float* __restrict__ fc2, u16* __restrict__ fc2Th, u16* __restrict__ fc2Tl,
    const float* __restrict__ sW1_1, u16* __restrict__ sW1Th1, u16* __restrict__ sW1Tl1,
    const float* __restrict__ sW1_2, u16* __restrict__ sW1Th2, u16* __restrict__ sW1Tl2) {
  __shared__ __align__(16) char smem[4608];
  int bi = blockIdx.x;
  int tid = threadIdx.x;
  if (bi < 5120) {
    // ---- edge-mask build ----
    int bx = bi & 15, by = (bi >> 4) & 15, bm = bi >> 8;
    int b = bm / M_;
    int s0 = bx * 64, d0 = by * 64;
    int nn = node_nums[b];
    unsigned char(*tile)[65] = (unsigned char(*)[65])smem;
    const float* arow = adj + (size_t)bm * N_ * N_;
#pragma unroll
    for (int k = 0; k < 16; ++k) {
      int idx = k * 256 + tid;
      int sl = idx >> 6, dl = idx & 63;
      int s = s0 + sl, d = d0 + dl;
      unsigned char v = 0;
      if (s < nn && d < nn && s < N_ && d < N_)
        v = (arow[(size_t)s * N_ + d] > THRESH_) ? 1 : 0;
      tile[sl][dl] = v;
    }
    __syncthreads();
    int w = tid >> 6, lane = tid & 63;
#pragma unroll
    for (int j = 0; j < 16; ++j) {
      int dl = w * 16 + j;
      bool act = tile[lane][dl] != 0;
      unsigned long long word = __ballot(act);
      int d = d0 + dl;
      if (lane == 0 && d < N_)
        maskW[((size_t)bm * N_ + d) * NW + bx] = word;
    }
    return;
  }
  bi -= 5120;
  if (bi < 80) {  // fc1 (M, FIN, HD) -> (M, HD, FIN) hi/lo
    int kx = bi % 2, ny = (bi / 2) % 8, z = bi / 16;
    splitT_body(fc1 + (size_t)z * FIN * HD, fc1Th + (size_t)z * HD * FIN,
                fc1Tl + (size_t)z * HD * FIN, FIN, HD, kx * 32, ny * 32, smem);
    return;
  }
  bi -= 80;
  if (bi < 320) {  // fc2 (M, HD, HD) -> (M, HD, HD)T hi/lo
    int kx = bi % 8, ny = (bi / 8) % 8, z = bi / 64;
    splitT_body(fc2 + (size_t)z * HD * HD, fc2Th + (size_t)z * HD * HD,
                fc2Tl + (size_t)z * HD * HD, HD, HD, kx * 32, ny * 32, smem);
    return;
  }
  bi -= 320;
  if (bi < 32) {  // sW1_1 (HD, SH) -> (SH, HD) hi/lo
    int kx = bi % 8, ny = bi / 8;
    splitT_body(sW1_1, sW1Th1, sW1Tl1, HD, SH, kx * 32, ny * 32, smem);
    return;
  }
  bi -= 32;
  {  // sW1_2
    int kx = bi % 8, ny = bi / 8;
    splitT_body(sW1_2, sW1Th2, sW1Tl2, HD, SH, kx * 32, ny * 32, smem);
  }
}

// ---------------------------------------------------------------------------
// Split-bf16 MFMA GEMM (feat): C[z] = A[z] @ B[z]^T-stored.
// A is fp32; hi/lo split happens in registers during LDS staging.
// 3 mfma/product (hh+hl+lh) = fp32-grade accuracy.
// Epilogue also writes a bf16 copy (Cbf) for the request-bound consumer.
// ---------------------------------------------------------------------------
__global__ __launch_bounds__(256) void gemm_mfma3(
    const float* __restrict__ A, int Mz, size_t aZ,
    const u16* __restrict__ Bh, const u16* __restrict__ Bl, size_t bZ,
    float* __restrict__ C, u16* __restrict__ Cbf, size_t cZ,
    int Mrows, int K, int Nc) {
  __shared__ u16 sAh[64][40], sAl[64][40], sBh[64][40], sBl[64][40];
  int z = blockIdx.z;
  const float* Ab = A + (size_t)(z / Mz) * aZ;
  const u16* Bhb = Bh + (size_t)(z % Mz) * bZ;
  const u16* Blb = Bl + (size_t)(z % Mz) * bZ;
  float* Cb = C + (size_t)z * cZ;
  u16* Cfb = Cbf + (size_t)z * cZ;
  int row0 = blockIdx.x * 64, col0 = blockIdx.y * 64;
  int tid = threadIdx.x;
  int arow = tid >> 2, akq = (tid & 3) * 8;
  int wid = tid >> 6, lane = tid & 63;
  int wr = (wid >> 1) * 32, wc = (wid & 1) * 32;
  int lrow = lane & 15, kseg = (lane >> 4) * 8;
  f32x4 zero4 = {0.f, 0.f, 0.f, 0.f};
  f32x4 acc[2][2];
  acc[0][0] = zero4; acc[0][1] = zero4; acc[1][0] = zero4; acc[1][1] = zero4;
  for (int k0 = 0; k0 < K; k0 += 32) {
    float4 a0 = make_float4(0.f, 0.f, 0.f, 0.f), a1 = a0;
    int gr = row0 + arow;
    if (gr < Mrows) {
      const float* ap = Ab + (size_t)gr * K + k0 + akq;
      a0 = *(const float4*)ap;
      a1 = *(const float4*)(ap + 4);
    }
    us8 hv, lv;
    {
      u16 th, tl;
      split2(a0.x, th, tl); hv[0] = th; lv[0] = tl;
      split2(a0.y, th, tl); hv[1] = th; lv[1] = tl;
      split2(a0.z, th, tl); hv[2] = th; lv[2] = tl;
      split2(a0.w, th, tl); hv[3] = th; lv[3] = tl;
      split2(a1.x, th, tl); hv[4] = th; lv[4] = tl;
      split2(a1.y, th, tl); hv[5] = th; lv[5] = tl;
      split2(a1.z, th, tl); hv[6] = th; lv[6] = tl;
      split2(a1.w, th, tl); hv[7] = th; lv[7] = tl;
    }
    *(us8*)&sAh[arow][akq] = hv;
    *(us8*)&sAl[arow][akq] = lv;
    us8 bv = *(const us8*)(Bhb + (size_t)(col0 + arow) * K + k0 + akq);
    us8 blv = *(const us8*)(Blb + (size_t)(col0 + arow) * K + k0 + akq);
    *(us8*)&sBh[arow][akq] = bv;
    *(us8*)&sBl[arow][akq] = blv;
    __syncthreads();
    s16x8 aH[2], aL[2], bH[2], bL[2];
#pragma unroll
    for (int i = 0; i < 2; ++i) {
      aH[i] = *(const s16x8*)&sAh[wr + 16 * i + lrow][kseg];
      aL[i] = *(const s16x8*)&sAl[wr + 16 * i + lrow][kseg];
      bH[i] = *(const s16x8*)&sBh[wc + 16 * i + lrow][kseg];
      bL[i] = *(const s16x8*)&sBl[wc + 16 * i + lrow][kseg];
    }
#pragma unroll
    for (int i = 0; i < 2; ++i)
#pragma unroll
      for (int j = 0; j < 2; ++j) {
        acc[i][j] = __builtin_amdgcn_mfma_f32_16x16x32_bf16(aH[i], bH[j], acc[i][j], 0, 0, 0);
        acc[i][j] = __builtin_amdgcn_mfma_f32_16x16x32_bf16(aH[i], bL[j], acc[i][j], 0, 0, 0);
        acc[i][j] = __builtin_amdgcn_mfma_f32_16x16x32_bf16(aL[i], bH[j], acc[i][j], 0, 0, 0);
      }
    __syncthreads();
  }
#pragma unroll
  for (int i = 0; i < 2; ++i)
#pragma unroll
    for (int j = 0; j < 2; ++j) {
      int ccol = col0 + wc + 16 * j + lrow;
#pragma unroll
      for (int r = 0; r < 4; ++r) {
        int crow = row0 + wr + 16 * i + (lane >> 4) * 4 + r;
        if (crow < Mrows) {
          float v = acc[i][j][r];
          Cb[(size_t)crow * Nc + ccol] = v;
          Cfb[(size_t)crow * Nc + ccol] = bf16_bits(v);
        }
      }
    }
}

// ---------------------------------------------------------------------------
// el/er: wave-per-row, 16-lane reduce per head (fp32 feat — logit accuracy).
// Also zeroes p for gemm_sem.
// ---------------------------------------------------------------------------
__global__ __launch_bounds__(256) void elr_kernel(
    const float* __restrict__ feat, const float* __restrict__ al,
    const float* __restrict__ ar, float* __restrict__ el,
    float* __restrict__ er, float* __restrict__ p) {
  int b = blockIdx.z, m = blockIdx.y;
  int wid = threadIdx.x >> 6, lane = threadIdx.x & 63;
  if (blockIdx.y == 0 && blockIdx.z == 0) {
    int idx = blockIdx.x * 256 + threadIdx.x;
    if (idx < B_ * N_ * M_) p[idx] = 0.f;
  }
  int n = blockIdx.x * 4 + wid;
  size_t bmN = (size_t)(b * M_ + m) * N_;
  float4 f = *(const float4*)(feat + (bmN + n) * HD + lane * 4);
  float4 a4 = *(const float4*)(al + m * HD + lane * 4);
  float4 r4 = *(const float4*)(ar + m * HD + lane * 4);
  float vl = f.x * a4.x + f.y * a4.y + f.z * a4.z + f.w * a4.w;
  float vr = f.x * r4.x + f.y * r4.y + f.z * r4.z + f.w * r4.w;
#pragma unroll
  for (int s = 1; s < 16; s <<= 1) {
    vl += __shfl_xor(vl, s, 64);
    vr += __shfl_xor(vr, s, 64);
  }
  if ((lane & 15) == 0) {
    int h = lane >> 4;
    el[(bmN + n) * H_ + h] = vl;
    er[(bmN + n) * H_ + h] = vr;
  }
}

// ---------------------------------------------------------------------------
// GAT aggregation: one wave per destination, barrier-free, direct exp.
// bf16 feat rows (512B vs 1KB) halve L2 request count; mask read as
// ulonglong2 (8 requests vs 16); 4-edge batched inner loop for ILP.
// XCD-chunked block swizzle for feat L2 locality.
// ---------------------------------------------------------------------------
__global__ __launch_bounds__(256) void gat_agg(
    const unsigned long long* __restrict__ maskW, const u16* __restrict__ featbf,
    const float* __restrict__ el, const float* __restrict__ er,
    const float* __restrict__ gb, float* __restrict__ zout,
    u16* __restrict__ zbh) {
  int wid = threadIdx.x >> 6, lane = threadIdx.x & 63;
  const int NWGQ = (B_ * M_ * N_ / 4) / 8;  // 625
  int orig = blockIdx.x;
  int bid = (orig & 7) * NWGQ + (orig >> 3);  // XCD-chunked, bijective
  int gw = bid * 4 + wid;
  int d = gw % N_, bm = gw / N_;
  int m = bm % M_, b = bm / M_;
  __shared__ int slist_all[4][1024];
  int* slist = slist_all[wid];

  const unsigned long long* mrow = maskW + ((size_t)bm * N_ + d) * NW;
  int cnt = 0;
#pragma unroll
  for (int q = 0; q < NW / 2; ++q) {
    ulonglong2 wp = *(const ulonglong2*)(mrow + q * 2);
    unsigned long long w0 = wp.x, w1 = wp.y;
    if (w0) {
      if ((w0 >> lane) & 1ull) {
        int pos = cnt + (int)__popcll(w0 & ((1ull << lane) - 1ull));
        slist[pos] = q * 128 + lane;
      }
      cnt += (int)__popcll(w0);
    }
    if (w1) {
      if ((w1 >> lane) & 1ull) {
        int pos = cnt + (int)__popcll(w1 & ((1ull << lane) - 1ull));
        slist[pos] = q * 128 + 64 + lane;
      }
      cnt += (int)__popcll(w1);
    }
  }

  int h = lane >> 4;
  float4 bias4 = *(const float4*)(gb + m * HD + lane * 4);
  size_t zoff = ((size_t)(b * N_ + d) * M_ + m) * HD + lane * 4;
  float4 o;
  if (cnt == 0) {
    o.x = bias4.x > 0.f ? bias4.x : (__expf(bias4.x) - 1.f);
    o.y = bias4.y > 0.f ? bias4.y : (__expf(bias4.y) - 1.f);
    o.z = bias4.z > 0.f ? bias4.z : (__expf(bias4.z) - 1.f);
    o.w = bias4.w > 0.f ? bias4.w : (__expf(bias4.w) - 1.f);
  } else {
    if (lane < 4) slist[cnt + lane] = slist[0];  // pad to safe multiple of 4
    size_t bmN = (size_t)bm * N_;
    float erv = er[(bmN + d) * H_ + h];
    const float* elb = el + bmN * H_;
    const u16* fbb = featbf + bmN * HD;
    int lane4 = lane * 4;
    float den0 = 0.f, den1 = 0.f, den2 = 0.f, den3 = 0.f;
    f32x4 A0 = {0.f, 0.f, 0.f, 0.f}, A1 = A0, A2 = A0, A3 = A0;
    for (int i = 0; i < cnt; i += 4) {
      int4 s4 = *(const int4*)&slist[i];
      // issue all 8 loads up front (independent)
      float e0 = elb[(size_t)s4.x * H_ + h];
      float e1 = elb[(size_t)s4.y * H_ + h];
      float e2 = elb[(size_t)s4.z * H_ + h];
      float e3 = elb[(size_t)s4.w * H_ + h];
      ushort4 g0 = *(const ushort4*)(fbb + (size_t)s4.x * HD + lane4);
      ushort4 g1 = *(const ushort4*)(fbb + (size_t)s4.y * HD + lane4);
      ushort4 g2 = *(const ushort4*)(fbb + (size_t)s4.z * HD + lane4);
      ushort4 g3 = *(const ushort4*)(fbb + (size_t)s4.w * HD + lane4);
      float v0 = e0 + erv; v0 = v0 > 0.f ? v0 : 0.2f * v0;
      float v1 = e1 + erv; v1 = v1 > 0.f ? v1 : 0.2f * v1;
      float v2 = e2 + erv; v2 = v2 > 0.f ? v2 : 0.2f * v2;
      float v3 = e3 + erv; v3 = v3 > 0.f ? v3 : 0.2f * v3;
      float w0 = __expf(v0);
      float w1 = __expf(v1) * ((i + 1 < cnt) ? 1.f : 0.f);
      float w2 = __expf(v2) * ((i + 2 < cnt) ? 1.f : 0.f);
      float w3 = __expf(v3) * ((i + 3 < cnt) ? 1.f : 0.f);
      f32x4 f0 = {b2f(g0.x), b2f(g0.y), b2f(g0.z), b2f(g0.w)};
      f32x4 f1 = {b2f(g1.x), b2f(g1.y), b2f(g1.z), b2f(g1.w)};
      f32x4 f2 = {b2f(g2.x), b2f(g2.y), b2f(g2.z), b2f(g2.w)};
      f32x4 f3 = {b2f(g3.x), b2f(g3.y), b2f(g3.z), b2f(g3.w)};
      den0 += w0; den1 += w1; den2 += w2; den3 += w3;
      A0 += w0 * f0; A1 += w1 * f1; A2 += w2 * f2; A3 += w3 * f3;
    }
    float den = (den0 + den1) + (den2 + den3);
    f32x4 A = (A0 + A1) + (A2 + A3);
    float inv = 1.f / den;
    float vx = A[0] * inv + bias4.x;
    float vy = A[1] * inv + bias4.y;
    float vz = A[2] * inv + bias4.z;
    float vw = A[3] * inv + bias4.w;
    o.x = vx > 0.f ? vx : (__expf(vx) - 1.f);
    o.y = vy > 0.f ? vy : (__expf(vy) - 1.f);
    o.z = vz > 0.f ? vz : (__expf(vz) - 1.f);
    o.w = vw > 0.f ? vw : (__expf(vw) - 1.f);
  }
  *(float4*)(zout + zoff) = o;
  ushort4 hh;
  hh.x = bf16_bits(o.x);
  hh.y = bf16_bits(o.y);
  hh.z = bf16_bits(o.z);
  hh.w = bf16_bits(o.w);
  *(ushort4*)(zbh + zoff) = hh;
}

// ---------------------------------------------------------------------------
// Semantic GEMM: p[row] += sum_col tanh(A@W1+b1)[row,col] * W2[col].
// A bf16-only (1 mfma). Epilogue: 16-lane shuffle reduce + atomicAdd into p.
// ---------------------------------------------------------------------------
__global__ __launch_bounds__(256) void gemm_sem(
    const u16* __restrict__ Ah, const u16* __restrict__ Bh,
    const float* __restrict__ bias, const float* __restrict__ W2,
    float* __restrict__ p, int Mrows) {
  __shared__ u16 sA[64][40], sB[64][40];
  int row0 = blockIdx.x * 64, col0 = blockIdx.y * 64;
  int tid = threadIdx.x;
  int arow = tid >> 2, akq = (tid & 3) * 8;
  int wid = tid >> 6, lane = tid & 63;
  int wr = (wid >> 1) * 32, wc = (wid & 1) * 32;
  int lrow = lane & 15, kseg = (lane >> 4) * 8;
  f32x4 zero4 = {0.f, 0.f, 0.f, 0.f};
  f32x4 acc[2][2];
  acc[0][0] = zero4; acc[0][1] = zero4; acc[1][0] = zero4; acc[1][1] = zero4;
  for (int k0 = 0; k0 < HD; k0 += 32) {
    us8 av = {0, 0, 0, 0, 0, 0, 0, 0};
    int gr = row0 + arow;
    if (gr < Mrows) av = *(const us8*)(Ah + (size_t)gr * HD + k0 + akq);
    *(us8*)&sA[arow][akq] = av;
    us8 bv = *(const us8*)(Bh + (size_t)(col0 + arow) * HD + k0 + akq);
    *(us8*)&sB[arow][akq] = bv;
    __syncthreads();
    s16x8 aH[2], bH[2];
#pragma unroll
    for (int i = 0; i < 2; ++i) {
      aH[i] = *(const s16x8*)&sA[wr + 16 * i + lrow][kseg];
      bH[i] = *(const s16x8*)&sB[wc + 16 * i + lrow][kseg];
    }
#pragma unroll
    for (int i = 0; i < 2; ++i)
#pragma unroll
      for (int j = 0; j < 2; ++j)
        acc[i][j] = __builtin_amdgcn_mfma_f32_16x16x32_bf16(aH[i], bH[j], acc[i][j], 0, 0, 0);
    __syncthreads();
  }
#pragma unroll
  for (int i = 0; i < 2; ++i) {
#pragma unroll
    for (int r = 0; r < 4; ++r) {
      float part = 0.f;
#pragma unroll
      for (int j = 0; j < 2; ++j) {
        int ccol = col0 + wc + 16 * j + lrow;
        float v = tanhf(acc[i][j][r] + bias[ccol]);
        part += v * W2[ccol];
      }
#pragma unroll
      for (int s = 1; s < 16; s <<= 1) part += __shfl_xor(part, s, 64);
      int crow = row0 + wr + 16 * i + (lane >> 4) * 4 + r;
      if (lrow == 0 && crow < Mrows) atomicAdd(&p[crow], part);
    }
  }
}

// ---------------------------------------------------------------------------
// beta = softmax_m( sum_{b,n valid} p[b,n,m] / sum(node_nums) )  — 1 block
// ---------------------------------------------------------------------------
__global__ __launch_bounds__(256) void sem_beta(const float* __restrict__ p,
                                                const int* __restrict__ node_nums,
                                                float* __restrict__ beta) {
  __shared__ float red[256][M_];
  int tid = threadIdx.x;
  float loc[M_] = {};
  int nn0 = node_nums[0], nn1 = node_nums[1], nn2 = node_nums[2], nn3 = node_nums[3];
  for (int r = tid; r < B_ * N_ * M_; r += 256) {
    int m = r % M_;
    int bn = r / M_;
    int b = bn / N_, n = bn % N_;
    int nn = (b == 0) ? nn0 : (b == 1) ? nn1 : (b == 2) ? nn2 : nn3;
    if (n < nn) loc[m] += p[r];
  }
  for (int m = 0; m < M_; ++m) red[tid][m] = loc[m];
  __syncthreads();
  for (int st = 128; st > 0; st >>= 1) {
    if (tid < st)
      for (int m = 0; m < M_; ++m) red[tid][m] += red[tid + st][m];
    __syncthreads();
  }
  if (tid == 0) {
    float tot = (float)(nn0 + nn1 + nn2 + nn3);
    float w[M_], mx = -1e30f;
    for (int m = 0; m < M_; ++m) {
      w[m] = red[0][m] / tot;
      mx = fmaxf(mx, w[m]);
    }
    float s = 0.f;
    for (int m = 0; m < M_; ++m) {
      w[m] = __expf(w[m] - mx);
      s += w[m];
    }
    for (int m = 0; m < M_; ++m) beta[m] = w[m] / s;
  }
}

// ---------------------------------------------------------------------------
// h[b,n,hd] = sum_m beta[m] * z[b,n,m,hd]  (fp32 out; L2 GEMM splits itself)
// ---------------------------------------------------------------------------
__global__ __launch_bounds__(256) void sem_combine(const float* __restrict__ zb,
                                                   const float* __restrict__ beta,
                                                   float* __restrict__ hout) {
  int idx = blockIdx.x * 256 + threadIdx.x;
  int hd = idx & (HD - 1);
  int bn = idx >> 8;
  const float* zr = zb + (size_t)bn * M_ * HD + hd;
  float v = beta[0] * zr[0] + beta[1] * zr[HD] + beta[2] * zr[2 * HD] +
            beta[3] * zr[3 * HD] + beta[4] * zr[4 * HD];
  hout[idx] = v;
}

// ---------------------------------------------------------------------------
// Layer-2 combine fused with prediction head: one wave per row.
// ---------------------------------------------------------------------------
__global__ __launch_bounds__(256) void sem_combine_pred(
    const float* __restrict__ zb, const float* __restrict__ beta,
    const float* __restrict__ W, const float* __restrict__ bias,
    const int* __restrict__ node_nums, float* __restrict__ out) {
  int row = blockIdx.x * 4 + (threadIdx.x >> 6);
  int lane = threadIdx.x & 63;
  int b = row / N_, n = row % N_;
  const float* zr = zb + (size_t)row * M_ * HD + lane * 4;
  float b0 = beta[0], b1 = beta[1], b2 = beta[2], b3 = beta[3], b4 = beta[4];
  float4 z0 = *(const float4*)(zr);
  float4 z1 = *(const float4*)(zr + HD);
  float4 z2 = *(const float4*)(zr + 2 * HD);
  float4 z3 = *(const float4*)(zr + 3 * HD);
  float4 z4 = *(const float4*)(zr + 4 * HD);
  float hx = b0 * z0.x + b1 * z1.x + b2 * z2.x + b3 * z3.x + b4 * z4.x;
  float hy = b0 * z0.y + b1 * z1.y + b2 * z2.y + b3 * z3.y + b4 * z4.y;
  float hz = b0 * z0.z + b1 * z1.z + b2 * z2.z + b3 * z3.z + b4 * z4.z;
  float hw = b0 * z0.w + b1 * z1.w + b2 * z2.w + b3 * z3.w + b4 * z4.w;
  int k = lane * 4;
  float res[OUTD];
#pragma unroll
  for (int o = 0; o < OUTD; ++o) {
    float v = hx * W[(k + 0) * OUTD + o] + hy * W[(k + 1) * OUTD + o] +
              hz * W[(k + 2) * OUTD + o] + hw * W[(k + 3) * OUTD + o];
#pragma unroll
    for (int s = 1; s < 64; s <<= 1) v += __shfl_xor(v, s, 64);
    res[o] = v;
  }
  if (lane == 0) {
    float nm = (n < node_nums[b]) ? 1.f : 0.f;
#pragma unroll
    for (int o = 0; o < OUTD; ++o)
      out[(size_t)row * OUTD + o] = (res[o] + bias[o]) * nm;
  }
}

extern "C" void kernel_launch(void* const* d_in, const int* in_sizes, int n_in,
                              void* d_out, int out_size, void* d_ws, size_t ws_size,
                              hipStream_t stream) {
  const float* x = (const float*)d_in[0];
  const float* adj = (const float*)d_in[1];
  const int* node_nums = (const int*)d_in[2];
  const float* fc1 = (const float*)d_in[3];
  const float* al1 = (const float*)d_in[4];
  const float* ar1 = (const float*)d_in[5];
  const float* gb1 = (const float*)d_in[6];
  const float* sW1_1 = (const float*)d_in[7];
  const float* sb1_1 = (const float*)d_in[8];
  const float* sW2_1 = (const float*)d_in[9];
  const float* fc2 = (const float*)d_in[10];
  const float* al2 = (const float*)d_in[11];
  const float* ar2 = (const float*)d_in[12];
  const float* gb2 = (const float*)d_in[13];
  const float* sW1_2 = (const float*)d_in[14];
  const float* sb1_2 = (const float*)d_in[15];
  const float* sW2_2 = (const float*)d_in[16];
  const float* predW = (const float*)d_in[17];
  const float* predb = (const float*)d_in[18];
  float* out = (float*)d_out;

  char* ws = (char*)d_ws;
  size_t off = 0;
  unsigned long long* maskW = (unsigned long long*)(ws + off);
  off += (size_t)B_ * M_ * N_ * NW * 8;
  float* feat = (float*)(ws + off); off += (size_t)B_ * M_ * N_ * HD * 4;
  u16* featbf = (u16*)(ws + off); off += (size_t)B_ * M_ * N_ * HD * 2;
  float* el = (float*)(ws + off); off += (size_t)B_ * M_ * N_ * H_ * 4;
  float* er = (float*)(ws + off); off += (size_t)B_ * M_ * N_ * H_ * 4;
  float* zb = (float*)(ws + off); off += (size_t)B_ * N_ * M_ * HD * 4;
  float* h1 = (float*)(ws + off); off += (size_t)B_ * N_ * HD * 4;
  float* p = (float*)(ws + off); off += (size_t)B_ * N_ * M_ * 4;
  float* beta = (float*)(ws + off); off += 64;
  u16* fc1Th = (u16*)(ws + off); off += (size_t)M_ * HD * FIN * 2;
  u16* fc1Tl = (u16*)(ws + off); off += (size_t)M_ * HD * FIN * 2;
  u16* fc2Th = (u16*)(ws + off); off += (size_t)M_ * HD * HD * 2;
  u16* fc2Tl = (u16*)(ws + off); off += (size_t)M_ * HD * HD * 2;
  u16* sW1Th1 = (u16*)(ws + off); off += (size_t)SH * HD * 2;
  u16* sW1Tl1 = (u16*)(ws + off); off += (size_t)SH * HD * 2;
  u16* sW1Th2 = (u16*)(ws + off); off += (size_t)SH * HD * 2;
  u16* sW1Tl2 = (u16*)(ws + off); off += (size_t)SH * HD * 2;
  u16* zbh = (u16*)(ws + off); off += (size_t)B_ * N_ * M_ * HD * 2;

  const int ROWS = B_ * N_ * M_;  // 20000
  const int PREP_BLOCKS = 5120 + 80 + 320 + 32 + 32;  // 5584

  prep_all<<<dim3(PREP_BLOCKS), 256, 0, stream>>>(
      adj, node_nums, maskW, fc1, fc1Th, fc1Tl, fc2, fc2Th, fc2Tl,
      sW1_1, sW1Th1, sW1Tl1, sW1_2, sW1Th2, sW1Tl2);

  // ---- layer 1 ----
  gemm_mfma3<<<dim3(16, HD / 64, B_ * M_), 256, 0, stream>>>(
      x, M_, (size_t)M_ * N_ * FIN, fc1Th, fc1Tl, (size_t)HD * FIN,
      feat, featbf, (size_t)N_ * HD, N_, FIN, HD);
  elr_kernel<<<dim3(N_ / 4, M_, B_), 256, 0, stream>>>(feat, al1, ar1, el, er, p);
  gat_agg<<<dim3(ROWS / 4), 256, 0, stream>>>(maskW, featbf, el, er, gb1, zb, zbh);
  gemm_sem<<<dim3((ROWS + 63) / 64, SH / 64), 256, 0, stream>>>(
      zbh, sW1Th1, sb1_1, sW2_1, p, ROWS);
  sem_beta<<<dim3(1), 256, 0, stream>>>(p, node_nums, beta);
  sem_combine<<<dim3(B_ * N_ * HD / 256), 256, 0, stream>>>(zb, beta, h1);

  // ---- layer 2 ----
  gemm_mfma3<<<dim3(16, HD / 64, B_ * M_), 256, 0, stream>>>(
      h1, M_, (size_t)N_ * HD, fc2Th, fc2Tl, (size_t)HD * HD,
      feat, featbf, (size_t)N_ * HD, N_, HD, HD);
  elr_kernel<<<dim3(N_ / 4, M_, B_), 256, 0, stream>>>(feat, al2, ar2, el, er, p);
  gat_agg<<<dim3(ROWS / 4), 256, 0, stream>>>(maskW, featbf, el, er, gb2, zb, zbh);
  gemm_sem<<<dim3((ROWS + 63) / 64, SH / 64), 256, 0, stream>>>(
      zbh, sW1Th2, sb1_2, sW2_2, p, ROWS);
  sem_beta<<<dim3(1), 256, 0, stream>>>(p, node_nums, beta);
  sem_combine_pred<<<dim3(B_ * N_ / 4), 256, 0, stream>>>(
      zb, beta, predW, predb, node_nums, out);
}

// Round 11
// 206.667 us; speedup vs baseline: 1.4206x; 1.0211x over previous
//
#include <hip/hip_runtime.h>
#include <hip/hip_bf16.h>

#define B_ 4
#define M_ 5
#define N_ 1000
#define FIN 64
#define H_ 4
#define D_ 64
#define HD 256
#define SH 128
#define OUTD 5
#define NW 16  // u64 words per dest row (1024/64)
#define THRESH_ 0.97f

typedef unsigned short u16;
typedef u16 us8 __attribute__((ext_vector_type(8)));
typedef short s16x8 __attribute__((ext_vector_type(8)));
typedef float f32x4 __attribute__((ext_vector_type(4)));

__device__ inline u16 bf16_bits(float v) {
  __hip_bfloat16 h = __float2bfloat16(v);
  return *reinterpret_cast<u16*>(&h);
}
__device__ inline float bf16_val(u16 b) {
  __hip_bfloat16 h;
  *reinterpret_cast<u16*>(&h) = b;
  return __bfloat162float(h);
}
__device__ inline float b2f(u16 u) {
  union { unsigned int i; float f; } c;
  c.i = ((unsigned int)u) << 16;
  return c.f;
}
__device__ inline void split2(float v, u16& h, u16& l) {
  h = bf16_bits(v);
  l = bf16_bits(v - bf16_val(h));
}

// ---------------------------------------------------------------------------
// prep_all: one launch doing (a) bit-packed transposed edge mask build and
// (b) all weight transpose+split jobs, selected by block range.
// ---------------------------------------------------------------------------
__device__ void splitT_body(const float* __restrict__ s, u16* __restrict__ hiT,
                            u16* __restrict__ loT, int K, int N, int k0, int n0,
                            char* smem) {
  float(*tile)[33] = (float(*)[33])smem;
  int tid = threadIdx.x;
  int kl = tid >> 3, nq = (tid & 7) * 4;
  *(float4*)&tile[kl][nq] = *(const float4*)(s + (size_t)(k0 + kl) * N + n0 + nq);
  __syncthreads();
  int nl = tid >> 3, kq = (tid & 7) * 4;
  ushort4 h, l;
  split2(tile[kq + 0][nl], h.x, l.x);
  split2(tile[kq + 1][nl], h.y, l.y);
  split2(tile[kq + 2][nl], h.z, l.z);
  split2(tile[kq + 3][nl], h.w, l.w);
  size_t o = (size_t)(n0 + nl) * K + k0 + kq;
  *(ushort4*)(hiT + o) = h;
  *(ushort4*)(loT + o) = l;
}

__global__ __launch_bounds__(256) void prep_all(
    const float* __restrict__ adj, const int* __restrict__ node_nums,
    unsigned long long* __restrict__ maskW,
    const float* __restrict__ fc1, u16* __restrict__ fc1Th, u16* __restrict__ fc1Tl,
    const float* __restrict__ fc2, u16* __restrict__ fc2Th, u16* __restrict__ fc2Tl,
    const float* __restrict__ sW1_1, u16* __restrict__ sW1Th1, u16* __restrict__ sW1Tl1,
    const float* __restrict__ sW1_2, u16* __restrict__ sW1Th2, u16* __restrict__ sW1Tl2) {
  __shared__ __align__(16) char smem[4608];
  int bi = blockIdx.x;
  int tid = threadIdx.x;
  if (bi < 5120) {
    // ---- edge-mask build ----
    int bx = bi & 15, by = (bi >> 4) & 15, bm = bi >> 8;
    int b = bm / M_;
    int s0 = bx * 64, d0 = by * 64;
    int nn = node_nums[b];
    unsigned char(*tile)[65] = (unsigned char(*)[65])smem;
    const float* arow = adj + (size_t)bm * N_ * N_;
#pragma unroll
    for (int k = 0; k < 16; ++k) {
      int idx = k * 256 + tid;
      int sl = idx >> 6, dl = idx & 63;
      int s = s0 + sl, d = d0 + dl;
      unsigned char v = 0;
      if (s < nn && d < nn && s < N_ && d < N_)
        v = (arow[(size_t)s * N_ + d] > THRESH_) ? 1 : 0;
      tile[sl][dl] = v;
    }
    __syncthreads();
    int w = tid >> 6, lane = tid & 63;
#pragma unroll
    for (int j = 0; j < 16; ++j) {
      int dl = w * 16 + j;
      bool act = tile[lane][dl] != 0;
      unsigned long long word = __ballot(act);
      int d = d0 + dl;
      if (lane == 0 && d < N_)
        maskW[((size_t)bm * N_ + d) * NW + bx] = word;
    }
    return;
  }
  bi -= 5120;
  if (bi < 80) {  // fc1 (M, FIN, HD) -> (M, HD, FIN) hi/lo
    int kx = bi % 2, ny = (bi / 2) % 8, z = bi / 16;
    splitT_body(fc1 + (size_t)z * FIN * HD, fc1Th + (size_t)z * HD * FIN,
                fc1Tl + (size_t)z * HD * FIN, FIN, HD, kx * 32, ny * 32, smem);
    return;
  }
  bi -= 80;
  if (bi < 320) {  // fc2 (M, HD, HD) -> (M, HD, HD)T hi/lo
    int kx = bi % 8, ny = (bi / 8) % 8, z = bi / 64;
    splitT_body(fc2 + (size_t)z * HD * HD, fc2Th + (size_t)z * HD * HD,
                fc2Tl + (size_t)z * HD * HD, HD, HD, kx * 32, ny * 32, smem);
    return;
  }
  bi -= 320;
  if (bi < 32) {  // sW1_1 (HD, SH) -> (SH, HD) hi/lo
    int kx = bi % 8, ny = bi / 8;
    splitT_body(sW1_1, sW1Th1, sW1Tl1, HD, SH, kx * 32, ny * 32, smem);
    return;
  }
  bi -= 32;
  {  // sW1_2
    int kx = bi % 8, ny = bi / 8;
    splitT_body(sW1_2, sW1Th2, sW1Tl2, HD, SH, kx * 32, ny * 32, smem);
  }
}

// ---------------------------------------------------------------------------
// Split-bf16 MFMA GEMM (feat) with FUSED el/er epilogue.
// A fp32 (in-register hi/lo split), B pre-transposed hi/lo, 3 mfma/product.
// The 64-col tile == one head (D=64), so el/er for this head are computed
// from the fp32 accumulators: per-thread dot with al/ar, shfl-reduce over
// lrow, 2-slot LDS combine across the two wc-waves, one write per row.
// Epilogue also writes bf16 feat copy for gat_agg.
// ---------------------------------------------------------------------------
__global__ __launch_bounds__(256) void gemm_mfma3(
    const float* __restrict__ A, int Mz, size_t aZ,
    const u16* __restrict__ Bh, const u16* __restrict__ Bl, size_t bZ,
    float* __restrict__ C, u16* __restrict__ Cbf, size_t cZ,
    int Mrows, int K, int Nc,
    const float* __restrict__ al, const float* __restrict__ ar,
    float* __restrict__ el, float* __restrict__ er) {
  __shared__ u16 sAh[64][40], sAl[64][40], sBh[64][40], sBl[64][40];
  __shared__ float elbuf[64][2], erbuf[64][2];
  int z = blockIdx.z;
  int b = z / Mz, m = z % Mz;
  const float* Ab = A + (size_t)b * aZ;
  const u16* Bhb = Bh + (size_t)m * bZ;
  const u16* Blb = Bl + (size_t)m * bZ;
  float* Cb = C + (size_t)z * cZ;
  u16* Cfb = Cbf + (size_t)z * cZ;
  int row0 = blockIdx.x * 64, col0 = blockIdx.y * 64;
  int tid = threadIdx.x;
  int arow = tid >> 2, akq = (tid & 3) * 8;
  int wid = tid >> 6, lane = tid & 63;
  int wr = (wid >> 1) * 32, wc = (wid & 1) * 32;
  int lrow = lane & 15, kseg = (lane >> 4) * 8;
  f32x4 zero4 = {0.f, 0.f, 0.f, 0.f};
  f32x4 acc[2][2];
  acc[0][0] = zero4; acc[0][1] = zero4; acc[1][0] = zero4; acc[1][1] = zero4;
  for (int k0 = 0; k0 < K; k0 += 32) {
    float4 a0 = make_float4(0.f, 0.f, 0.f, 0.f), a1 = a0;
    int gr = row0 + arow;
    if (gr < Mrows) {
      const float* ap = Ab + (size_t)gr * K + k0 + akq;
      a0 = *(const float4*)ap;
      a1 = *(const float4*)(ap + 4);
    }
    us8 hv, lv;
    {
      u16 th, tl;
      split2(a0.x, th, tl); hv[0] = th; lv[0] = tl;
      split2(a0.y, th, tl); hv[1] = th; lv[1] = tl;
      split2(a0.z, th, tl); hv[2] = th; lv[2] = tl;
      split2(a0.w, th, tl); hv[3] = th; lv[3] = tl;
      split2(a1.x, th, tl); hv[4] = th; lv[4] = tl;
      split2(a1.y, th, tl); hv[5] = th; lv[5] = tl;
      split2(a1.z, th, tl); hv[6] = th; lv[6] = tl;
      split2(a1.w, th, tl); hv[7] = th; lv[7] = tl;
    }
    *(us8*)&sAh[arow][akq] = hv;
    *(us8*)&sAl[arow][akq] = lv;
    us8 bv = *(const us8*)(Bhb + (size_t)(col0 + arow) * K + k0 + akq);
    us8 blv = *(const us8*)(Blb + (size_t)(col0 + arow) * K + k0 + akq);
    *(us8*)&sBh[arow][akq] = bv;
    *(us8*)&sBl[arow][akq] = blv;
    __syncthreads();
    s16x8 aH[2], aL[2], bH[2], bL[2];
#pragma unroll
    for (int i = 0; i < 2; ++i) {
      aH[i] = *(const s16x8*)&sAh[wr + 16 * i + lrow][kseg];
      aL[i] = *(const s16x8*)&sAl[wr + 16 * i + lrow][kseg];
      bH[i] = *(const s16x8*)&sBh[wc + 16 * i + lrow][kseg];
      bL[i] = *(const s16x8*)&sBl[wc + 16 * i + lrow][kseg];
    }
#pragma unroll
    for (int i = 0; i < 2; ++i)
#pragma unroll
      for (int j = 0; j < 2; ++j) {
        acc[i][j] = __builtin_amdgcn_mfma_f32_16x16x32_bf16(aH[i], bH[j], acc[i][j], 0, 0, 0);
        acc[i][j] = __builtin_amdgcn_mfma_f32_16x16x32_bf16(aH[i], bL[j], acc[i][j], 0, 0, 0);
        acc[i][j] = __builtin_amdgcn_mfma_f32_16x16x32_bf16(aL[i], bH[j], acc[i][j], 0, 0, 0);
      }
    __syncthreads();
  }
  // ---- C write (fp32 + bf16) ----
#pragma unroll
  for (int i = 0; i < 2; ++i)
#pragma unroll
    for (int j = 0; j < 2; ++j) {
      int ccol = col0 + wc + 16 * j + lrow;
#pragma unroll
      for (int r = 0; r < 4; ++r) {
        int crow = row0 + wr + 16 * i + (lane >> 4) * 4 + r;
        if (crow < Mrows) {
          float v = acc[i][j][r];
          Cb[(size_t)crow * Nc + ccol] = v;
          Cfb[(size_t)crow * Nc + ccol] = bf16_bits(v);
        }
      }
    }
  // ---- fused el/er epilogue (this block's 64 cols == one head) ----
  float alv0 = al[m * HD + col0 + wc + lrow];
  float alv1 = al[m * HD + col0 + wc + 16 + lrow];
  float arv0 = ar[m * HD + col0 + wc + lrow];
  float arv1 = ar[m * HD + col0 + wc + 16 + lrow];
#pragma unroll
  for (int i = 0; i < 2; ++i)
#pragma unroll
    for (int r = 0; r < 4; ++r) {
      float pl = acc[i][0][r] * alv0 + acc[i][1][r] * alv1;
      float pr = acc[i][0][r] * arv0 + acc[i][1][r] * arv1;
#pragma unroll
      for (int s = 1; s < 16; s <<= 1) {
        pl += __shfl_xor(pl, s, 64);
        pr += __shfl_xor(pr, s, 64);
      }
      if (lrow == 0) {
        int rl = wr + 16 * i + (lane >> 4) * 4 + r;
        elbuf[rl][wc >> 5] = pl;
        erbuf[rl][wc >> 5] = pr;
      }
    }
  __syncthreads();
  if (tid < 64) {
    int grow = row0 + tid;
    if (grow < Mrows) {
      int h = col0 >> 6;
      size_t bmN = (size_t)(b * M_ + m) * N_;
      el[(bmN + grow) * H_ + h] = elbuf[tid][0] + elbuf[tid][1];
      er[(bmN + grow) * H_ + h] = erbuf[tid][0] + erbuf[tid][1];
    }
  }
}

// ---------------------------------------------------------------------------
// GAT aggregation: one wave per destination, barrier-free, direct exp.
// bf16 feat rows; ulonglong2 mask reads; 4-edge batched inner loop for ILP;
// XCD-chunked block swizzle. Also zeroes p for gemm_sem.
// ---------------------------------------------------------------------------
__global__ __launch_bounds__(256) void gat_agg(
    const unsigned long long* __restrict__ maskW, const u16* __restrict__ featbf,
    const float* __restrict__ el, const float* __restrict__ er,
    const float* __restrict__ gb, float* __restrict__ zout,
    u16* __restrict__ zbh, float* __restrict__ p) {
  int wid = threadIdx.x >> 6, lane = threadIdx.x & 63;
  const int NWGQ = (B_ * M_ * N_ / 4) / 8;  // 625
  int orig = blockIdx.x;
  int bid = (orig & 7) * NWGQ + (orig >> 3);  // XCD-chunked, bijective
  int gw = bid * 4 + wid;
  if (lane == 0) p[gw] = 0.f;
  int d = gw % N_, bm = gw / N_;
  int m = bm % M_, b = bm / M_;
  __shared__ int slist_all[4][1024];
  int* slist = slist_all[wid];

  const unsigned long long* mrow = maskW + ((size_t)bm * N_ + d) * NW;
  int cnt = 0;
#pragma unroll
  for (int q = 0; q < NW / 2; ++q) {
    ulonglong2 wp = *(const ulonglong2*)(mrow + q * 2);
    unsigned long long w0 = wp.x, w1 = wp.y;
    if (w0) {
      if ((w0 >> lane) & 1ull) {
        int pos = cnt + (int)__popcll(w0 & ((1ull << lane) - 1ull));
        slist[pos] = q * 128 + lane;
      }
      cnt += (int)__popcll(w0);
    }
    if (w1) {
      if ((w1 >> lane) & 1ull) {
        int pos = cnt + (int)__popcll(w1 & ((1ull << lane) - 1ull));
        slist[pos] = q * 128 + 64 + lane;
      }
      cnt += (int)__popcll(w1);
    }
  }

  int h = lane >> 4;
  float4 bias4 = *(const float4*)(gb + m * HD + lane * 4);
  size_t zoff = ((size_t)(b * N_ + d) * M_ + m) * HD + lane * 4;
  float4 o;
  if (cnt == 0) {
    o.x = bias4.x > 0.f ? bias4.x : (__expf(bias4.x) - 1.f);
    o.y = bias4.y > 0.f ? bias4.y : (__expf(bias4.y) - 1.f);
    o.z = bias4.z > 0.f ? bias4.z : (__expf(bias4.z) - 1.f);
    o.w = bias4.w > 0.f ? bias4.w : (__expf(bias4.w) - 1.f);
  } else {
    if (lane < 4) slist[cnt + lane] = slist[0];  // pad to safe multiple of 4
    size_t bmN = (size_t)bm * N_;
    float erv = er[(bmN + d) * H_ + h];
    const float* elb = el + bmN * H_;
    const u16* fbb = featbf + bmN * HD;
    int lane4 = lane * 4;
    float den0 = 0.f, den1 = 0.f, den2 = 0.f, den3 = 0.f;
    f32x4 A0 = {0.f, 0.f, 0.f, 0.f}, A1 = A0, A2 = A0, A3 = A0;
    for (int i = 0; i < cnt; i += 4) {
      int4 s4 = *(const int4*)&slist[i];
      float e0 = elb[(size_t)s4.x * H_ + h];
      float e1 = elb[(size_t)s4.y * H_ + h];
      float e2 = elb[(size_t)s4.z * H_ + h];
      float e3 = elb[(size_t)s4.w * H_ + h];
      ushort4 g0 = *(const ushort4*)(fbb + (size_t)s4.x * HD + lane4);
      ushort4 g1 = *(const ushort4*)(fbb + (size_t)s4.y * HD + lane4);
      ushort4 g2 = *(const ushort4*)(fbb + (size_t)s4.z * HD + lane4);
      ushort4 g3 = *(const ushort4*)(fbb + (size_t)s4.w * HD + lane4);
      float v0 = e0 + erv; v0 = v0 > 0.f ? v0 : 0.2f * v0;
      float v1 = e1 + erv; v1 = v1 > 0.f ? v1 : 0.2f * v1;
      float v2 = e2 + erv; v2 = v2 > 0.f ? v2 : 0.2f * v2;
      float v3 = e3 + erv; v3 = v3 > 0.f ? v3 : 0.2f * v3;
      float w0 = __expf(v0);
      float w1 = __expf(v1) * ((i + 1 < cnt) ? 1.f : 0.f);
      float w2 = __expf(v2) * ((i + 2 < cnt) ? 1.f : 0.f);
      float w3 = __expf(v3) * ((i + 3 < cnt) ? 1.f : 0.f);
      f32x4 f0 = {b2f(g0.x), b2f(g0.y), b2f(g0.z), b2f(g0.w)};
      f32x4 f1 = {b2f(g1.x), b2f(g1.y), b2f(g1.z), b2f(g1.w)};
      f32x4 f2 = {b2f(g2.x), b2f(g2.y), b2f(g2.z), b2f(g2.w)};
      f32x4 f3 = {b2f(g3.x), b2f(g3.y), b2f(g3.z), b2f(g3.w)};
      den0 += w0; den1 += w1; den2 += w2; den3 += w3;
      A0 += w0 * f0; A1 += w1 * f1; A2 += w2 * f2; A3 += w3 * f3;
    }
    float den = (den0 + den1) + (den2 + den3);
    f32x4 A = (A0 + A1) + (A2 + A3);
    float inv = 1.f / den;
    float vx = A[0] * inv + bias4.x;
    float vy = A[1] * inv + bias4.y;
    float vz = A[2] * inv + bias4.z;
    float vw = A[3] * inv + bias4.w;
    o.x = vx > 0.f ? vx : (__expf(vx) - 1.f);
    o.y = vy > 0.f ? vy : (__expf(vy) - 1.f);
    o.z = vz > 0.f ? vz : (__expf(vz) - 1.f);
    o.w = vw > 0.f ? vw : (__expf(vw) - 1.f);
  }
  *(float4*)(zout + zoff) = o;
  ushort4 hh;
  hh.x = bf16_bits(o.x);
  hh.y = bf16_bits(o.y);
  hh.z = bf16_bits(o.z);
  hh.w = bf16_bits(o.w);
  *(ushort4*)(zbh + zoff) = hh;
}

// ---------------------------------------------------------------------------
// Semantic GEMM: p[row] += sum_col tanh(A@W1+b1)[row,col] * W2[col].
// A bf16-only (1 mfma). Epilogue: 16-lane shuffle reduce + atomicAdd into p.
// ---------------------------------------------------------------------------
__global__ __launch_bounds__(256) void gemm_sem(
    const u16* __restrict__ Ah, const u16* __restrict__ Bh,
    const float* __restrict__ bias, const float* __restrict__ W2,
    float* __restrict__ p, int Mrows) {
  __shared__ u16 sA[64][40], sB[64][40];
  int row0 = blockIdx.x * 64, col0 = blockIdx.y * 64;
  int tid = threadIdx.x;
  int arow = tid >> 2, akq = (tid & 3) * 8;
  int wid = tid >> 6, lane = tid & 63;
  int wr = (wid >> 1) * 32, wc = (wid & 1) * 32;
  int lrow = lane & 15, kseg = (lane >> 4) * 8;
  f32x4 zero4 = {0.f, 0.f, 0.f, 0.f};
  f32x4 acc[2][2];
  acc[0][0] = zero4; acc[0][1] = zero4; acc[1][0] = zero4; acc[1][1] = zero4;
  for (int k0 = 0; k0 < HD; k0 += 32) {
    us8 av = {0, 0, 0, 0, 0, 0, 0, 0};
    int gr = row0 + arow;
    if (gr < Mrows) av = *(const us8*)(Ah + (size_t)gr * HD + k0 + akq);
    *(us8*)&sA[arow][akq] = av;
    us8 bv = *(const us8*)(Bh + (size_t)(col0 + arow) * HD + k0 + akq);
    *(us8*)&sB[arow][akq] = bv;
    __syncthreads();
    s16x8 aH[2], bH[2];
#pragma unroll
    for (int i = 0; i < 2; ++i) {
      aH[i] = *(const s16x8*)&sA[wr + 16 * i + lrow][kseg];
      bH[i] = *(const s16x8*)&sB[wc + 16 * i + lrow][kseg];
    }
#pragma unroll
    for (int i = 0; i < 2; ++i)
#pragma unroll
      for (int j = 0; j < 2; ++j)
        acc[i][j] = __builtin_amdgcn_mfma_f32_16x16x32_bf16(aH[i], bH[j], acc[i][j], 0, 0, 0);
    __syncthreads();
  }
#pragma unroll
  for (int i = 0; i < 2; ++i) {
#pragma unroll
    for (int r = 0; r < 4; ++r) {
      float part = 0.f;
#pragma unroll
      for (int j = 0; j < 2; ++j) {
        int ccol = col0 + wc + 16 * j + lrow;
        float v = tanhf(acc[i][j][r] + bias[ccol]);
        part += v * W2[ccol];
      }
#pragma unroll
      for (int s = 1; s < 16; s <<= 1) part += __shfl_xor(part, s, 64);
      int crow = row0 + wr + 16 * i + (lane >> 4) * 4 + r;
      if (lrow == 0 && crow < Mrows) atomicAdd(&p[crow], part);
    }
  }
}

// ---------------------------------------------------------------------------
// beta = softmax_m( sum_{b,n valid} p[b,n,m] / sum(node_nums) )  — 1 block
// ---------------------------------------------------------------------------
__global__ __launch_bounds__(256) void sem_beta(const float* __restrict__ p,
                                                const int* __restrict__ node_nums,
                                                float* __restrict__ beta) {
  __shared__ float red[256][M_];
  int tid = threadIdx.x;
  float loc[M_] = {};
  int nn0 = node_nums[0], nn1 = node_nums[1], nn2 = node_nums[2], nn3 = node_nums[3];
  for (int r = tid; r < B_ * N_ * M_; r += 256) {
    int m = r % M_;
    int bn = r / M_;
    int b = bn / N_, n = bn % N_;
    int nn = (b == 0) ? nn0 : (b == 1) ? nn1 : (b == 2) ? nn2 : nn3;
    if (n < nn) loc[m] += p[r];
  }
  for (int m = 0; m < M_; ++m) red[tid][m] = loc[m];
  __syncthreads();
  for (int st = 128; st > 0; st >>= 1) {
    if (tid < st)
      for (int m = 0; m < M_; ++m) red[tid][m] += red[tid + st][m];
    __syncthreads();
  }
  if (tid == 0) {
    float tot = (float)(nn0 + nn1 + nn2 + nn3);
    float w[M_], mx = -1e30f;
    for (int m = 0; m < M_; ++m) {
      w[m] = red[0][m] / tot;
      mx = fmaxf(mx, w[m]);
    }
    float s = 0.f;
    for (int m = 0; m < M_; ++m) {
      w[m] = __expf(w[m] - mx);
      s += w[m];
    }
    for (int m = 0; m < M_; ++m) beta[m] = w[m] / s;
  }
}

// ---------------------------------------------------------------------------
// h[b,n,hd] = sum_m beta[m] * z[b,n,m,hd]
// ---------------------------------------------------------------------------
__global__ __launch_bounds__(256) void sem_combine(const float* __restrict__ zb,
                                                   const float* __restrict__ beta,
                                                   float* __restrict__ hout) {
  int idx = blockIdx.x * 256 + threadIdx.x;
  int hd = idx & (HD - 1);
  int bn = idx >> 8;
  const float* zr = zb + (size_t)bn * M_ * HD + hd;
  float v = beta[0] * zr[0] + beta[1] * zr[HD] + beta[2] * zr[2 * HD] +
            beta[3] * zr[3 * HD] + beta[4] * zr[4 * HD];
  hout[idx] = v;
}

// ---------------------------------------------------------------------------
// Layer-2 combine fused with prediction head: one wave per row.
// ---------------------------------------------------------------------------
__global__ __launch_bounds__(256) void sem_combine_pred(
    const float* __restrict__ zb, const float* __restrict__ beta,
    const float* __restrict__ W, const float* __restrict__ bias,
    const int* __restrict__ node_nums, float* __restrict__ out) {
  int row = blockIdx.x * 4 + (threadIdx.x >> 6);
  int lane = threadIdx.x & 63;
  int b = row / N_, n = row % N_;
  const float* zr = zb + (size_t)row * M_ * HD + lane * 4;
  float b0 = beta[0], b1 = beta[1], b2 = beta[2], b3 = beta[3], b4 = beta[4];
  float4 z0 = *(const float4*)(zr);
  float4 z1 = *(const float4*)(zr + HD);
  float4 z2 = *(const float4*)(zr + 2 * HD);
  float4 z3 = *(const float4*)(zr + 3 * HD);
  float4 z4 = *(const float4*)(zr + 4 * HD);
  float hx = b0 * z0.x + b1 * z1.x + b2 * z2.x + b3 * z3.x + b4 * z4.x;
  float hy = b0 * z0.y + b1 * z1.y + b2 * z2.y + b3 * z3.y + b4 * z4.y;
  float hz = b0 * z0.z + b1 * z1.z + b2 * z2.z + b3 * z3.z + b4 * z4.z;
  float hw = b0 * z0.w + b1 * z1.w + b2 * z2.w + b3 * z3.w + b4 * z4.w;
  int k = lane * 4;
  float res[OUTD];
#pragma unroll
  for (int o = 0; o < OUTD; ++o) {
    float v = hx * W[(k + 0) * OUTD + o] + hy * W[(k + 1) * OUTD + o] +
              hz * W[(k + 2) * OUTD + o] + hw * W[(k + 3) * OUTD + o];
#pragma unroll
    for (int s = 1; s < 64; s <<= 1) v += __shfl_xor(v, s, 64);
    res[o] = v;
  }
  if (lane == 0) {
    float nm = (n < node_nums[b]) ? 1.f : 0.f;
#pragma unroll
    for (int o = 0; o < OUTD; ++o)
      out[(size_t)row * OUTD + o] = (res[o] + bias[o]) * nm;
  }
}

extern "C" void kernel_launch(void* const* d_in, const int* in_sizes, int n_in,
                              void* d_out, int out_size, void* d_ws, size_t ws_size,
                              hipStream_t stream) {
  const float* x = (const float*)d_in[0];
  const float* adj = (const float*)d_in[1];
  const int* node_nums = (const int*)d_in[2];
  const float* fc1 = (const float*)d_in[3];
  const float* al1 = (const float*)d_in[4];
  const float* ar1 = (const float*)d_in[5];
  const float* gb1 = (const float*)d_in[6];
  const float* sW1_1 = (const float*)d_in[7];
  const float* sb1_1 = (const float*)d_in[8];
  const float* sW2_1 = (const float*)d_in[9];
  const float* fc2 = (const float*)d_in[10];
  const float* al2 = (const float*)d_in[11];
  const float* ar2 = (const float*)d_in[12];
  const float* gb2 = (const float*)d_in[13];
  const float* sW1_2 = (const float*)d_in[14];
  const float* sb1_2 = (const float*)d_in[15];
  const float* sW2_2 = (const float*)d_in[16];
  const float* predW = (const float*)d_in[17];
  const float* predb = (const float*)d_in[18];
  float* out = (float*)d_out;

  char* ws = (char*)d_ws;
  size_t off = 0;
  unsigned long long* maskW = (unsigned long long*)(ws + off);
  off += (size_t)B_ * M_ * N_ * NW * 8;
  float* feat = (float*)(ws + off); off += (size_t)B_ * M_ * N_ * HD * 4;
  u16* featbf = (u16*)(ws + off); off += (size_t)B_ * M_ * N_ * HD * 2;
  float* el = (float*)(ws + off); off += (size_t)B_ * M_ * N_ * H_ * 4;
  float* er = (float*)(ws + off); off += (size_t)B_ * M_ * N_ * H_ * 4;
  float* zb = (float*)(ws + off); off += (size_t)B_ * N_ * M_ * HD * 4;
  float* h1 = (float*)(ws + off); off += (size_t)B_ * N_ * HD * 4;
  float* p = (float*)(ws + off); off += (size_t)B_ * N_ * M_ * 4;
  float* beta = (float*)(ws + off); off += 64;
  u16* fc1Th = (u16*)(ws + off); off += (size_t)M_ * HD * FIN * 2;
  u16* fc1Tl = (u16*)(ws + off); off += (size_t)M_ * HD * FIN * 2;
  u16* fc2Th = (u16*)(ws + off); off += (size_t)M_ * HD * HD * 2;
  u16* fc2Tl = (u16*)(ws + off); off += (size_t)M_ * HD * HD * 2;
  u16* sW1Th1 = (u16*)(ws + off); off += (size_t)SH * HD * 2;
  u16* sW1Tl1 = (u16*)(ws + off); off += (size_t)SH * HD * 2;
  u16* sW1Th2 = (u16*)(ws + off); off += (size_t)SH * HD * 2;
  u16* sW1Tl2 = (u16*)(ws + off); off += (size_t)SH * HD * 2;
  u16* zbh = (u16*)(ws + off); off += (size_t)B_ * N_ * M_ * HD * 2;

  const int ROWS = B_ * N_ * M_;  // 20000
  const int PREP_BLOCKS = 5120 + 80 + 320 + 32 + 32;  // 5584

  prep_all<<<dim3(PREP_BLOCKS), 256, 0, stream>>>(
      adj, node_nums, maskW, fc1, fc1Th, fc1Tl, fc2, fc2Th, fc2Tl,
      sW1_1, sW1Th1, sW1Tl1, sW1_2, sW1Th2, sW1Tl2);

  // ---- layer 1 ----
  gemm_mfma3<<<dim3(16, HD / 64, B_ * M_), 256, 0, stream>>>(
      x, M_, (size_t)M_ * N_ * FIN, fc1Th, fc1Tl, (size_t)HD * FIN,
      feat, featbf, (size_t)N_ * HD, N_, FIN, HD, al1, ar1, el, er);
  gat_agg<<<dim3(ROWS / 4), 256, 0, stream>>>(maskW, featbf, el, er, gb1, zb, zbh, p);
  gemm_sem<<<dim3((ROWS + 63) / 64, SH / 64), 256, 0, stream>>>(
      zbh, sW1Th1, sb1_1, sW2_1, p, ROWS);
  sem_beta<<<dim3(1), 256, 0, stream>>>(p, node_nums, beta);
  sem_combine<<<dim3(B_ * N_ * HD / 256), 256, 0, stream>>>(zb, beta, h1);

  // ---- layer 2 ----
  gemm_mfma3<<<dim3(16, HD / 64, B_ * M_), 256, 0, stream>>>(
      h1, M_, (size_t)N_ * HD, fc2Th, fc2Tl, (size_t)HD * HD,
      feat, featbf, (size_t)N_ * HD, N_, HD, HD, al2, ar2, el, er);
  gat_agg<<<dim3(ROWS / 4), 256, 0, stream>>>(maskW, featbf, el, er, gb2, zb, zbh, p);
  gemm_sem<<<dim3((ROWS + 63) / 64, SH / 64), 256, 0, stream>>>(
      zbh, sW1Th2, sb1_2, sW2_2, p, ROWS);
  sem_beta<<<dim3(1), 256, 0, stream>>>(p, node_nums, beta);
  sem_combine_pred<<<dim3(B_ * N_ / 4), 256, 0, stream>>>(
      zb, beta, predW, predb, node_nums, out);
}

// Round 12
// 172.129 us; speedup vs baseline: 1.7057x; 1.2007x over previous
//
#include <hip/hip_runtime.h>
#include <hip/hip_bf16.h>

#define B_ 4
#define M_ 5
#define N_ 1000
#define FIN 64
#define H_ 4
#define D_ 64
#define HD 256
#define SH 128
#define OUTD 5
#define NW 16  // u64 words per dest row (1024/64)
#define THRESH_ 0.97f

typedef unsigned short u16;
typedef u16 us8 __attribute__((ext_vector_type(8)));
typedef short s16x8 __attribute__((ext_vector_type(8)));
typedef float f32x4 __attribute__((ext_vector_type(4)));

__device__ inline u16 bf16_bits(float v) {
  __hip_bfloat16 h = __float2bfloat16(v);
  return *reinterpret_cast<u16*>(&h);
}
__device__ inline float bf16_val(u16 b) {
  __hip_bfloat16 h;
  *reinterpret_cast<u16*>(&h) = b;
  return __bfloat162float(h);
}
__device__ inline float b2f(u16 u) {
  union { unsigned int i; float f; } c;
  c.i = ((unsigned int)u) << 16;
  return c.f;
}
__device__ inline void split2(float v, u16& h, u16& l) {
  h = bf16_bits(v);
  l = bf16_bits(v - bf16_val(h));
}
// beta softmax from the 5 masked sums (computed redundantly, trivial)
__device__ inline void beta_from_sums(const float* __restrict__ psum,
                                      const int* __restrict__ node_nums,
                                      float* bb) {
  float tot = (float)(node_nums[0] + node_nums[1] + node_nums[2] + node_nums[3]);
  float w[M_], mx = -1e30f;
#pragma unroll
  for (int m = 0; m < M_; ++m) {
    w[m] = psum[m] / tot;
    mx = fmaxf(mx, w[m]);
  }
  float s = 0.f;
#pragma unroll
  for (int m = 0; m < M_; ++m) {
    w[m] = __expf(w[m] - mx);
    s += w[m];
  }
  float inv = 1.f / s;
#pragma unroll
  for (int m = 0; m < M_; ++m) bb[m] = w[m] * inv;
}

// ---------------------------------------------------------------------------
// prep_all: one launch doing (a) bit-packed transposed edge mask build and
// (b) all weight transpose+split jobs, selected by block range.
// ---------------------------------------------------------------------------
__device__ void splitT_body(const float* __restrict__ s, u16* __restrict__ hiT,
                            u16* __restrict__ loT, int K, int N, int k0, int n0,
                            char* smem) {
  float(*tile)[33] = (float(*)[33])smem;
  int tid = threadIdx.x;
  int kl = tid >> 3, nq = (tid & 7) * 4;
  *(float4*)&tile[kl][nq] = *(const float4*)(s + (size_t)(k0 + kl) * N + n0 + nq);
  __syncthreads();
  int nl = tid >> 3, kq = (tid & 7) * 4;
  ushort4 h, l;
  split2(tile[kq + 0][nl], h.x, l.x);
  split2(tile[kq + 1][nl], h.y, l.y);
  split2(tile[kq + 2][nl], h.z, l.z);
  split2(tile[kq + 3][nl], h.w, l.w);
  size_t o = (size_t)(n0 + nl) * K + k0 + kq;
  *(ushort4*)(hiT + o) = h;
  *(ushort4*)(loT + o) = l;
}

__global__ __launch_bounds__(256) void prep_all(
    const float* __restrict__ adj, const int* __restrict__ node_nums,
    unsigned long long* __restrict__ maskW,
    const float* __restrict__ fc1, u16* __restrict__ fc1Th, u16* __restrict__ fc1Tl,
    const float* __restrict__ fc2, u16* __restrict__ fc2Th, u16* __restrict__ fc2Tl,
    const float* __restrict__ sW1_1, u16* __restrict__ sW1Th1, u16* __restrict__ sW1Tl1,
    const float* __restrict__ sW1_2, u16* __restrict__ sW1Th2, u16* __restrict__ sW1Tl2) {
  __shared__ __align__(16) char smem[4608];
  int bi = blockIdx.x;
  int tid = threadIdx.x;
  if (bi < 5120) {
    // ---- edge-mask build ----
    int bx = bi & 15, by = (bi >> 4) & 15, bm = bi >> 8;
    int b = bm / M_;
    int s0 = bx * 64, d0 = by * 64;
    int nn = node_nums[b];
    unsigned char(*tile)[65] = (unsigned char(*)[65])smem;
    const float* arow = adj + (size_t)bm * N_ * N_;
#pragma unroll
    for (int k = 0; k < 16; ++k) {
      int idx = k * 256 + tid;
      int sl = idx >> 6, dl = idx & 63;
      int s = s0 + sl, d = d0 + dl;
      unsigned char v = 0;
      if (s < nn && d < nn && s < N_ && d < N_)
        v = (arow[(size_t)s * N_ + d] > THRESH_) ? 1 : 0;
      tile[sl][dl] = v;
    }
    __syncthreads();
    int w = tid >> 6, lane = tid & 63;
#pragma unroll
    for (int j = 0; j < 16; ++j) {
      int dl = w * 16 + j;
      bool act = tile[lane][dl] != 0;
      unsigned long long word = __ballot(act);
      int d = d0 + dl;
      if (lane == 0 && d < N_)
        maskW[((size_t)bm * N_ + d) * NW + bx] = word;
    }
    return;
  }
  bi -= 5120;
  if (bi < 80) {  // fc1 (M, FIN, HD) -> (M, HD, FIN) hi/lo
    int kx = bi % 2, ny = (bi / 2) % 8, z = bi / 16;
    splitT_body(fc1 + (size_t)z * FIN * HD, fc1Th + (size_t)z * HD * FIN,
                fc1Tl + (size_t)z * HD * FIN, FIN, HD, kx * 32, ny * 32, smem);
    return;
  }
  bi -= 80;
  if (bi < 320) {  // fc2 (M, HD, HD) -> (M, HD, HD)T hi/lo
    int kx = bi % 8, ny = (bi / 8) % 8, z = bi / 64;
    splitT_body(fc2 + (size_t)z * HD * HD, fc2Th + (size_t)z * HD * HD,
                fc2Tl + (size_t)z * HD * HD, HD, HD, kx * 32, ny * 32, smem);
    return;
  }
  bi -= 320;
  if (bi < 32) {  // sW1_1 (HD, SH) -> (SH, HD) hi/lo
    int kx = bi % 8, ny = bi / 8;
    splitT_body(sW1_1, sW1Th1, sW1Tl1, HD, SH, kx * 32, ny * 32, smem);
    return;
  }
  bi -= 32;
  {  // sW1_2
    int kx = bi % 8, ny = bi / 8;
    splitT_body(sW1_2, sW1Th2, sW1Tl2, HD, SH, kx * 32, ny * 32, smem);
  }
}

// ---------------------------------------------------------------------------
// Split-bf16 MFMA GEMM (feat) with FUSED el/er epilogue.
// A fp32 (in-register hi/lo split), B pre-transposed hi/lo, 3 mfma/product.
// The 64-col tile == one head (D=64): el/er computed from accumulators.
// Epilogue also writes bf16 feat copy for gat_agg.
// ---------------------------------------------------------------------------
__global__ __launch_bounds__(256) void gemm_mfma3(
    const float* __restrict__ A, int Mz, size_t aZ,
    const u16* __restrict__ Bh, const u16* __restrict__ Bl, size_t bZ,
    float* __restrict__ C, u16* __restrict__ Cbf, size_t cZ,
    int Mrows, int K, int Nc,
    const float* __restrict__ al, const float* __restrict__ ar,
    float* __restrict__ el, float* __restrict__ er) {
  __shared__ u16 sAh[64][40], sAl[64][40], sBh[64][40], sBl[64][40];
  __shared__ float elbuf[64][2], erbuf[64][2];
  int z = blockIdx.z;
  int b = z / Mz, m = z % Mz;
  const float* Ab = A + (size_t)b * aZ;
  const u16* Bhb = Bh + (size_t)m * bZ;
  const u16* Blb = Bl + (size_t)m * bZ;
  float* Cb = C + (size_t)z * cZ;
  u16* Cfb = Cbf + (size_t)z * cZ;
  int row0 = blockIdx.x * 64, col0 = blockIdx.y * 64;
  int tid = threadIdx.x;
  int arow = tid >> 2, akq = (tid & 3) * 8;
  int wid = tid >> 6, lane = tid & 63;
  int wr = (wid >> 1) * 32, wc = (wid & 1) * 32;
  int lrow = lane & 15, kseg = (lane >> 4) * 8;
  f32x4 zero4 = {0.f, 0.f, 0.f, 0.f};
  f32x4 acc[2][2];
  acc[0][0] = zero4; acc[0][1] = zero4; acc[1][0] = zero4; acc[1][1] = zero4;
  for (int k0 = 0; k0 < K; k0 += 32) {
    float4 a0 = make_float4(0.f, 0.f, 0.f, 0.f), a1 = a0;
    int gr = row0 + arow;
    if (gr < Mrows) {
      const float* ap = Ab + (size_t)gr * K + k0 + akq;
      a0 = *(const float4*)ap;
      a1 = *(const float4*)(ap + 4);
    }
    us8 hv, lv;
    {
      u16 th, tl;
      split2(a0.x, th, tl); hv[0] = th; lv[0] = tl;
      split2(a0.y, th, tl); hv[1] = th; lv[1] = tl;
      split2(a0.z, th, tl); hv[2] = th; lv[2] = tl;
      split2(a0.w, th, tl); hv[3] = th; lv[3] = tl;
      split2(a1.x, th, tl); hv[4] = th; lv[4] = tl;
      split2(a1.y, th, tl); hv[5] = th; lv[5] = tl;
      split2(a1.z, th, tl); hv[6] = th; lv[6] = tl;
      split2(a1.w, th, tl); hv[7] = th; lv[7] = tl;
    }
    *(us8*)&sAh[arow][akq] = hv;
    *(us8*)&sAl[arow][akq] = lv;
    us8 bv = *(const us8*)(Bhb + (size_t)(col0 + arow) * K + k0 + akq);
    us8 blv = *(const us8*)(Blb + (size_t)(col0 + arow) * K + k0 + akq);
    *(us8*)&sBh[arow][akq] = bv;
    *(us8*)&sBl[arow][akq] = blv;
    __syncthreads();
    s16x8 aH[2], aL[2], bH[2], bL[2];
#pragma unroll
    for (int i = 0; i < 2; ++i) {
      aH[i] = *(const s16x8*)&sAh[wr + 16 * i + lrow][kseg];
      aL[i] = *(const s16x8*)&sAl[wr + 16 * i + lrow][kseg];
      bH[i] = *(const s16x8*)&sBh[wc + 16 * i + lrow][kseg];
      bL[i] = *(const s16x8*)&sBl[wc + 16 * i + lrow][kseg];
    }
#pragma unroll
    for (int i = 0; i < 2; ++i)
#pragma unroll
      for (int j = 0; j < 2; ++j) {
        acc[i][j] = __builtin_amdgcn_mfma_f32_16x16x32_bf16(aH[i], bH[j], acc[i][j], 0, 0, 0);
        acc[i][j] = __builtin_amdgcn_mfma_f32_16x16x32_bf16(aH[i], bL[j], acc[i][j], 0, 0, 0);
        acc[i][j] = __builtin_amdgcn_mfma_f32_16x16x32_bf16(aL[i], bH[j], acc[i][j], 0, 0, 0);
      }
    __syncthreads();
  }
  // ---- C write (fp32 + bf16) ----
#pragma unroll
  for (int i = 0; i < 2; ++i)
#pragma unroll
    for (int j = 0; j < 2; ++j) {
      int ccol = col0 + wc + 16 * j + lrow;
#pragma unroll
      for (int r = 0; r < 4; ++r) {
        int crow = row0 + wr + 16 * i + (lane >> 4) * 4 + r;
        if (crow < Mrows) {
          float v = acc[i][j][r];
          Cb[(size_t)crow * Nc + ccol] = v;
          Cfb[(size_t)crow * Nc + ccol] = bf16_bits(v);
        }
      }
    }
  // ---- fused el/er epilogue (this block's 64 cols == one head) ----
  float alv0 = al[m * HD + col0 + wc + lrow];
  float alv1 = al[m * HD + col0 + wc + 16 + lrow];
  float arv0 = ar[m * HD + col0 + wc + lrow];
  float arv1 = ar[m * HD + col0 + wc + 16 + lrow];
#pragma unroll
  for (int i = 0; i < 2; ++i)
#pragma unroll
    for (int r = 0; r < 4; ++r) {
      float pl = acc[i][0][r] * alv0 + acc[i][1][r] * alv1;
      float pr = acc[i][0][r] * arv0 + acc[i][1][r] * arv1;
#pragma unroll
      for (int s = 1; s < 16; s <<= 1) {
        pl += __shfl_xor(pl, s, 64);
        pr += __shfl_xor(pr, s, 64);
      }
      if (lrow == 0) {
        int rl = wr + 16 * i + (lane >> 4) * 4 + r;
        elbuf[rl][wc >> 5] = pl;
        erbuf[rl][wc >> 5] = pr;
      }
    }
  __syncthreads();
  if (tid < 64) {
    int grow = row0 + tid;
    if (grow < Mrows) {
      int h = col0 >> 6;
      size_t bmN = (size_t)(b * M_ + m) * N_;
      el[(bmN + grow) * H_ + h] = elbuf[tid][0] + elbuf[tid][1];
      er[(bmN + grow) * H_ + h] = erbuf[tid][0] + erbuf[tid][1];
    }
  }
}

// ---------------------------------------------------------------------------
// GAT aggregation: one wave per destination, barrier-free, direct exp.
// bf16 feat rows; ulonglong2 mask reads; 4-edge batched inner loop;
// XCD-chunked block swizzle. Block 0 zeroes psum for gemm_sem.
// ---------------------------------------------------------------------------
__global__ __launch_bounds__(256) void gat_agg(
    const unsigned long long* __restrict__ maskW, const u16* __restrict__ featbf,
    const float* __restrict__ el, const float* __restrict__ er,
    const float* __restrict__ gb, float* __restrict__ zout,
    u16* __restrict__ zbh, float* __restrict__ psum) {
  int wid = threadIdx.x >> 6, lane = threadIdx.x & 63;
  const int NWGQ = (B_ * M_ * N_ / 4) / 8;  // 625
  int orig = blockIdx.x;
  if (orig == 0 && threadIdx.x < 8) psum[threadIdx.x] = 0.f;
  int bid = (orig & 7) * NWGQ + (orig >> 3);  // XCD-chunked, bijective
  int gw = bid * 4 + wid;
  int d = gw % N_, bm = gw / N_;
  int m = bm % M_, b = bm / M_;
  __shared__ int slist_all[4][1024];
  int* slist = slist_all[wid];

  const unsigned long long* mrow = maskW + ((size_t)bm * N_ + d) * NW;
  int cnt = 0;
#pragma unroll
  for (int q = 0; q < NW / 2; ++q) {
    ulonglong2 wp = *(const ulonglong2*)(mrow + q * 2);
    unsigned long long w0 = wp.x, w1 = wp.y;
    if (w0) {
      if ((w0 >> lane) & 1ull) {
        int pos = cnt + (int)__popcll(w0 & ((1ull << lane) - 1ull));
        slist[pos] = q * 128 + lane;
      }
      cnt += (int)__popcll(w0);
    }
    if (w1) {
      if ((w1 >> lane) & 1ull) {
        int pos = cnt + (int)__popcll(w1 & ((1ull << lane) - 1ull));
        slist[pos] = q * 128 + 64 + lane;
      }
      cnt += (int)__popcll(w1);
    }
  }

  int h = lane >> 4;
  float4 bias4 = *(const float4*)(gb + m * HD + lane * 4);
  size_t zoff = ((size_t)(b * N_ + d) * M_ + m) * HD + lane * 4;
  float4 o;
  if (cnt == 0) {
    o.x = bias4.x > 0.f ? bias4.x : (__expf(bias4.x) - 1.f);
    o.y = bias4.y > 0.f ? bias4.y : (__expf(bias4.y) - 1.f);
    o.z = bias4.z > 0.f ? bias4.z : (__expf(bias4.z) - 1.f);
    o.w = bias4.w > 0.f ? bias4.w : (__expf(bias4.w) - 1.f);
  } else {
    if (lane < 4) slist[cnt + lane] = slist[0];  // pad to safe multiple of 4
    size_t bmN = (size_t)bm * N_;
    float erv = er[(bmN + d) * H_ + h];
    const float* elb = el + bmN * H_;
    const u16* fbb = featbf + bmN * HD;
    int lane4 = lane * 4;
    float den0 = 0.f, den1 = 0.f, den2 = 0.f, den3 = 0.f;
    f32x4 A0 = {0.f, 0.f, 0.f, 0.f}, A1 = A0, A2 = A0, A3 = A0;
    for (int i = 0; i < cnt; i += 4) {
      int4 s4 = *(const int4*)&slist[i];
      float e0 = elb[(size_t)s4.x * H_ + h];
      float e1 = elb[(size_t)s4.y * H_ + h];
      float e2 = elb[(size_t)s4.z * H_ + h];
      float e3 = elb[(size_t)s4.w * H_ + h];
      ushort4 g0 = *(const ushort4*)(fbb + (size_t)s4.x * HD + lane4);
      ushort4 g1 = *(const ushort4*)(fbb + (size_t)s4.y * HD + lane4);
      ushort4 g2 = *(const ushort4*)(fbb + (size_t)s4.z * HD + lane4);
      ushort4 g3 = *(const ushort4*)(fbb + (size_t)s4.w * HD + lane4);
      float v0 = e0 + erv; v0 = v0 > 0.f ? v0 : 0.2f * v0;
      float v1 = e1 + erv; v1 = v1 > 0.f ? v1 : 0.2f * v1;
      float v2 = e2 + erv; v2 = v2 > 0.f ? v2 : 0.2f * v2;
      float v3 = e3 + erv; v3 = v3 > 0.f ? v3 : 0.2f * v3;
      float w0 = __expf(v0);
      float w1 = __expf(v1) * ((i + 1 < cnt) ? 1.f : 0.f);
      float w2 = __expf(v2) * ((i + 2 < cnt) ? 1.f : 0.f);
      float w3 = __expf(v3) * ((i + 3 < cnt) ? 1.f : 0.f);
      f32x4 f0 = {b2f(g0.x), b2f(g0.y), b2f(g0.z), b2f(g0.w)};
      f32x4 f1 = {b2f(g1.x), b2f(g1.y), b2f(g1.z), b2f(g1.w)};
      f32x4 f2 = {b2f(g2.x), b2f(g2.y), b2f(g2.z), b2f(g2.w)};
      f32x4 f3 = {b2f(g3.x), b2f(g3.y), b2f(g3.z), b2f(g3.w)};
      den0 += w0; den1 += w1; den2 += w2; den3 += w3;
      A0 += w0 * f0; A1 += w1 * f1; A2 += w2 * f2; A3 += w3 * f3;
    }
    float den = (den0 + den1) + (den2 + den3);
    f32x4 A = (A0 + A1) + (A2 + A3);
    float inv = 1.f / den;
    float vx = A[0] * inv + bias4.x;
    float vy = A[1] * inv + bias4.y;
    float vz = A[2] * inv + bias4.z;
    float vw = A[3] * inv + bias4.w;
    o.x = vx > 0.f ? vx : (__expf(vx) - 1.f);
    o.y = vy > 0.f ? vy : (__expf(vy) - 1.f);
    o.z = vz > 0.f ? vz : (__expf(vz) - 1.f);
    o.w = vw > 0.f ? vw : (__expf(vw) - 1.f);
  }
  *(float4*)(zout + zoff) = o;
  ushort4 hh;
  hh.x = bf16_bits(o.x);
  hh.y = bf16_bits(o.y);
  hh.z = bf16_bits(o.z);
  hh.w = bf16_bits(o.w);
  *(ushort4*)(zbh + zoff) = hh;
}

// ---------------------------------------------------------------------------
// Semantic GEMM with fused masked per-metapath reduction:
// psum[m] += sum_{rows of m, n<nn} tanh(A@W1+b1)[row,:] . W2
// LDS 5-bin reduction per block + 5 global atomics (no fence; the next
// kernel-boundary orders visibility). Replaces p[] + sem_beta kernel.
// ---------------------------------------------------------------------------
__global__ __launch_bounds__(256) void gemm_sem(
    const u16* __restrict__ Ah, const u16* __restrict__ Bh,
    const float* __restrict__ bias, const float* __restrict__ W2,
    float* __restrict__ psum, const int* __restrict__ node_nums, int Mrows) {
  __shared__ u16 sA[64][40], sB[64][40];
  __shared__ float redm[M_];
  int row0 = blockIdx.x * 64, col0 = blockIdx.y * 64;
  int tid = threadIdx.x;
  int arow = tid >> 2, akq = (tid & 3) * 8;
  int wid = tid >> 6, lane = tid & 63;
  int wr = (wid >> 1) * 32, wc = (wid & 1) * 32;
  int lrow = lane & 15, kseg = (lane >> 4) * 8;
  if (tid < M_) redm[tid] = 0.f;
  f32x4 zero4 = {0.f, 0.f, 0.f, 0.f};
  f32x4 acc[2][2];
  acc[0][0] = zero4; acc[0][1] = zero4; acc[1][0] = zero4; acc[1][1] = zero4;
  for (int k0 = 0; k0 < HD; k0 += 32) {
    us8 av = {0, 0, 0, 0, 0, 0, 0, 0};
    int gr = row0 + arow;
    if (gr < Mrows) av = *(const us8*)(Ah + (size_t)gr * HD + k0 + akq);
    *(us8*)&sA[arow][akq] = av;
    us8 bv = *(const us8*)(Bh + (size_t)(col0 + arow) * HD + k0 + akq);
    *(us8*)&sB[arow][akq] = bv;
    __syncthreads();
    s16x8 aH[2], bH[2];
#pragma unroll
    for (int i = 0; i < 2; ++i) {
      aH[i] = *(const s16x8*)&sA[wr + 16 * i + lrow][kseg];
      bH[i] = *(const s16x8*)&sB[wc + 16 * i + lrow][kseg];
    }
#pragma unroll
    for (int i = 0; i < 2; ++i)
#pragma unroll
      for (int j = 0; j < 2; ++j)
        acc[i][j] = __builtin_amdgcn_mfma_f32_16x16x32_bf16(aH[i], bH[j], acc[i][j], 0, 0, 0);
    __syncthreads();
  }
  int nn0 = node_nums[0], nn1 = node_nums[1], nn2 = node_nums[2], nn3 = node_nums[3];
#pragma unroll
  for (int i = 0; i < 2; ++i) {
#pragma unroll
    for (int r = 0; r < 4; ++r) {
      float part = 0.f;
#pragma unroll
      for (int j = 0; j < 2; ++j) {
        int ccol = col0 + wc + 16 * j + lrow;
        float v = tanhf(acc[i][j][r] + bias[ccol]);
        part += v * W2[ccol];
      }
#pragma unroll
      for (int s = 1; s < 16; s <<= 1) part += __shfl_xor(part, s, 64);
      int crow = row0 + wr + 16 * i + (lane >> 4) * 4 + r;
      if (lrow == 0 && crow < Mrows) {
        int m = crow % M_;
        int bn = crow / M_;
        int bb = bn / N_, n = bn % N_;
        int nn = (bb == 0) ? nn0 : (bb == 1) ? nn1 : (bb == 2) ? nn2 : nn3;
        if (n < nn) atomicAdd(&redm[m], part);
      }
    }
  }
  __syncthreads();
  if (tid < M_) atomicAdd(&psum[tid], redm[tid]);
}

// ---------------------------------------------------------------------------
// h[b,n,hd] = sum_m beta[m] * z[b,n,m,hd]; beta from psum inline.
// ---------------------------------------------------------------------------
__global__ __launch_bounds__(256) void sem_combine(const float* __restrict__ zb,
                                                   const float* __restrict__ psum,
                                                   const int* __restrict__ node_nums,
                                                   float* __restrict__ hout) {
  float bb[M_];
  beta_from_sums(psum, node_nums, bb);
  int idx = blockIdx.x * 256 + threadIdx.x;
  int hd = idx & (HD - 1);
  int bn = idx >> 8;
  const float* zr = zb + (size_t)bn * M_ * HD + hd;
  float v = bb[0] * zr[0] + bb[1] * zr[HD] + bb[2] * zr[2 * HD] +
            bb[3] * zr[3 * HD] + bb[4] * zr[4 * HD];
  hout[idx] = v;
}

// ---------------------------------------------------------------------------
// Layer-2 combine fused with prediction head: one wave per row.
// ---------------------------------------------------------------------------
__global__ __launch_bounds__(256) void sem_combine_pred(
    const float* __restrict__ zb, const float* __restrict__ psum,
    const int* __restrict__ node_nums, const float* __restrict__ W,
    const float* __restrict__ bias, float* __restrict__ out) {
  float bb[M_];
  beta_from_sums(psum, node_nums, bb);
  int row = blockIdx.x * 4 + (threadIdx.x >> 6);
  int lane = threadIdx.x & 63;
  int b = row / N_, n = row % N_;
  const float* zr = zb + (size_t)row * M_ * HD + lane * 4;
  float4 z0 = *(const float4*)(zr);
  float4 z1 = *(const float4*)(zr + HD);
  float4 z2 = *(const float4*)(zr + 2 * HD);
  float4 z3 = *(const float4*)(zr + 3 * HD);
  float4 z4 = *(const float4*)(zr + 4 * HD);
  float hx = bb[0] * z0.x + bb[1] * z1.x + bb[2] * z2.x + bb[3] * z3.x + bb[4] * z4.x;
  float hy = bb[0] * z0.y + bb[1] * z1.y + bb[2] * z2.y + bb[3] * z3.y + bb[4] * z4.y;
  float hz = bb[0] * z0.z + bb[1] * z1.z + bb[2] * z2.z + bb[3] * z3.z + bb[4] * z4.z;
  float hw = bb[0] * z0.w + bb[1] * z1.w + bb[2] * z2.w + bb[3] * z3.w + bb[4] * z4.w;
  int k = lane * 4;
  float res[OUTD];
#pragma unroll
  for (int o = 0; o < OUTD; ++o) {
    float v = hx * W[(k + 0) * OUTD + o] + hy * W[(k + 1) * OUTD + o] +
              hz * W[(k + 2) * OUTD + o] + hw * W[(k + 3) * OUTD + o];
#pragma unroll
    for (int s = 1; s < 64; s <<= 1) v += __shfl_xor(v, s, 64);
    res[o] = v;
  }
  if (lane == 0) {
    float nm = (n < node_nums[b]) ? 1.f : 0.f;
#pragma unroll
    for (int o = 0; o < OUTD; ++o)
      out[(size_t)row * OUTD + o] = (res[o] + bias[o]) * nm;
  }
}

extern "C" void kernel_launch(void* const* d_in, const int* in_sizes, int n_in,
                              void* d_out, int out_size, void* d_ws, size_t ws_size,
                              hipStream_t stream) {
  const float* x = (const float*)d_in[0];
  const float* adj = (const float*)d_in[1];
  const int* node_nums = (const int*)d_in[2];
  const float* fc1 = (const float*)d_in[3];
  const float* al1 = (const float*)d_in[4];
  const float* ar1 = (const float*)d_in[5];
  const float* gb1 = (const float*)d_in[6];
  const float* sW1_1 = (const float*)d_in[7];
  const float* sb1_1 = (const float*)d_in[8];
  const float* sW2_1 = (const float*)d_in[9];
  const float* fc2 = (const float*)d_in[10];
  const float* al2 = (const float*)d_in[11];
  const float* ar2 = (const float*)d_in[12];
  const float* gb2 = (const float*)d_in[13];
  const float* sW1_2 = (const float*)d_in[14];
  const float* sb1_2 = (const float*)d_in[15];
  const float* sW2_2 = (const float*)d_in[16];
  const float* predW = (const float*)d_in[17];
  const float* predb = (const float*)d_in[18];
  float* out = (float*)d_out;

  char* ws = (char*)d_ws;
  size_t off = 0;
  unsigned long long* maskW = (unsigned long long*)(ws + off);
  off += (size_t)B_ * M_ * N_ * NW * 8;
  float* feat = (float*)(ws + off); off += (size_t)B_ * M_ * N_ * HD * 4;
  u16* featbf = (u16*)(ws + off); off += (size_t)B_ * M_ * N_ * HD * 2;
  float* el = (float*)(ws + off); off += (size_t)B_ * M_ * N_ * H_ * 4;
  float* er = (float*)(ws + off); off += (size_t)B_ * M_ * N_ * H_ * 4;
  float* zb = (float*)(ws + off); off += (size_t)B_ * N_ * M_ * HD * 4;
  float* h1 = (float*)(ws + off); off += (size_t)B_ * N_ * HD * 4;
  float* psum = (float*)(ws + off); off += 64;
  u16* fc1Th = (u16*)(ws + off); off += (size_t)M_ * HD * FIN * 2;
  u16* fc1Tl = (u16*)(ws + off); off += (size_t)M_ * HD * FIN * 2;
  u16* fc2Th = (u16*)(ws + off); off += (size_t)M_ * HD * HD * 2;
  u16* fc2Tl = (u16*)(ws + off); off += (size_t)M_ * HD * HD * 2;
  u16* sW1Th1 = (u16*)(ws + off); off += (size_t)SH * HD * 2;
  u16* sW1Tl1 = (u16*)(ws + off); off += (size_t)SH * HD * 2;
  u16* sW1Th2 = (u16*)(ws + off); off += (size_t)SH * HD * 2;
  u16* sW1Tl2 = (u16*)(ws + off); off += (size_t)SH * HD * 2;
  u16* zbh = (u16*)(ws + off); off += (size_t)B_ * N_ * M_ * HD * 2;

  const int ROWS = B_ * N_ * M_;  // 20000
  const int PREP_BLOCKS = 5120 + 80 + 320 + 32 + 32;  // 5584

  prep_all<<<dim3(PREP_BLOCKS), 256, 0, stream>>>(
      adj, node_nums, maskW, fc1, fc1Th, fc1Tl, fc2, fc2Th, fc2Tl,
      sW1_1, sW1Th1, sW1Tl1, sW1_2, sW1Th2, sW1Tl2);

  // ---- layer 1 ----
  gemm_mfma3<<<dim3(16, HD / 64, B_ * M_), 256, 0, stream>>>(
      x, M_, (size_t)M_ * N_ * FIN, fc1Th, fc1Tl, (size_t)HD * FIN,
      feat, featbf, (size_t)N_ * HD, N_, FIN, HD, al1, ar1, el, er);
  gat_agg<<<dim3(ROWS / 4), 256, 0, stream>>>(maskW, featbf, el, er, gb1, zb, zbh, psum);
  gemm_sem<<<dim3((ROWS + 63) / 64, SH / 64), 256, 0, stream>>>(
      zbh, sW1Th1, sb1_1, sW2_1, psum, node_nums, ROWS);
  sem_combine<<<dim3(B_ * N_ * HD / 256), 256, 0, stream>>>(zb, psum, node_nums, h1);

  // ---- layer 2 ----
  gemm_mfma3<<<dim3(16, HD / 64, B_ * M_), 256, 0, stream>>>(
      h1, M_, (size_t)N_ * HD, fc2Th, fc2Tl, (size_t)HD * HD,
      feat, featbf, (size_t)N_ * HD, N_, HD, HD, al2, ar2, el, er);
  gat_agg<<<dim3(ROWS / 4), 256, 0, stream>>>(maskW, featbf, el, er, gb2, zb, zbh, psum);
  gemm_sem<<<dim3((ROWS + 63) / 64, SH / 64), 256, 0, stream>>>(
      zbh, sW1Th2, sb1_2, sW2_2, psum, node_nums, ROWS);
  sem_combine_pred<<<dim3(B_ * N_ / 4), 256, 0, stream>>>(
      zb, psum, node_nums, predW, predb, out);
}

// Round 13
// 164.776 us; speedup vs baseline: 1.7818x; 1.0446x over previous
//
#include <hip/hip_runtime.h>
#include <hip/hip_bf16.h>

#define B_ 4
#define M_ 5
#define N_ 1000
#define FIN 64
#define H_ 4
#define D_ 64
#define HD 256
#define SH 128
#define OUTD 5
#define NW 16  // u64 words per dest row (1024/64)
#define THRESH_ 0.97f

typedef unsigned short u16;
typedef u16 us8 __attribute__((ext_vector_type(8)));
typedef short s16x8 __attribute__((ext_vector_type(8)));
typedef float f32x4 __attribute__((ext_vector_type(4)));

__device__ inline u16 bf16_bits(float v) {
  __hip_bfloat16 h = __float2bfloat16(v);
  return *reinterpret_cast<u16*>(&h);
}
__device__ inline float bf16_val(u16 b) {
  __hip_bfloat16 h;
  *reinterpret_cast<u16*>(&h) = b;
  return __bfloat162float(h);
}
__device__ inline float b2f(u16 u) {
  union { unsigned int i; float f; } c;
  c.i = ((unsigned int)u) << 16;
  return c.f;
}
__device__ inline void split2(float v, u16& h, u16& l) {
  h = bf16_bits(v);
  l = bf16_bits(v - bf16_val(h));
}
// beta softmax from the 5 masked sums (computed redundantly, trivial)
__device__ inline void beta_from_sums(const float* __restrict__ psum,
                                      const int* __restrict__ node_nums,
                                      float* bb) {
  float tot = (float)(node_nums[0] + node_nums[1] + node_nums[2] + node_nums[3]);
  float w[M_], mx = -1e30f;
#pragma unroll
  for (int m = 0; m < M_; ++m) {
    w[m] = psum[m] / tot;
    mx = fmaxf(mx, w[m]);
  }
  float s = 0.f;
#pragma unroll
  for (int m = 0; m < M_; ++m) {
    w[m] = __expf(w[m] - mx);
    s += w[m];
  }
  float inv = 1.f / s;
#pragma unroll
  for (int m = 0; m < M_; ++m) bb[m] = w[m] * inv;
}

// ---------------------------------------------------------------------------
// prep_all: one launch doing (a) bit-packed transposed edge mask build and
// (b) all weight transpose+split jobs, selected by block range.
// ---------------------------------------------------------------------------
__device__ void splitT_body(const float* __restrict__ s, u16* __restrict__ hiT,
                            u16* __restrict__ loT, int K, int N, int k0, int n0,
                            char* smem) {
  float(*tile)[33] = (float(*)[33])smem;
  int tid = threadIdx.x;
  int kl = tid >> 3, nq = (tid & 7) * 4;
  *(float4*)&tile[kl][nq] = *(const float4*)(s + (size_t)(k0 + kl) * N + n0 + nq);
  __syncthreads();
  int nl = tid >> 3, kq = (tid & 7) * 4;
  ushort4 h, l;
  split2(tile[kq + 0][nl], h.x, l.x);
  split2(tile[kq + 1][nl], h.y, l.y);
  split2(tile[kq + 2][nl], h.z, l.z);
  split2(tile[kq + 3][nl], h.w, l.w);
  size_t o = (size_t)(n0 + nl) * K + k0 + kq;
  *(ushort4*)(hiT + o) = h;
  *(ushort4*)(loT + o) = l;
}

__global__ __launch_bounds__(256) void prep_all(
    const float* __restrict__ adj, const int* __restrict__ node_nums,
    unsigned long long* __restrict__ maskW,
    const float* __restrict__ fc1, u16* __restrict__ fc1Th, u16* __restrict__ fc1Tl,
    const float* __restrict__ fc2, u16* __restrict__ fc2Th, u16* __restrict__ fc2Tl,
    const float* __restrict__ sW1_1, u16* __restrict__ sW1Th1, u16* __restrict__ sW1Tl1,
    const float* __restrict__ sW1_2, u16* __restrict__ sW1Th2, u16* __restrict__ sW1Tl2) {
  __shared__ __align__(16) char smem[4608];
  int bi = blockIdx.x;
  int tid = threadIdx.x;
  if (bi < 5120) {
    // ---- edge-mask build ----
    int bx = bi & 15, by = (bi >> 4) & 15, bm = bi >> 8;
    int b = bm / M_;
    int s0 = bx * 64, d0 = by * 64;
    int nn = node_nums[b];
    unsigned char(*tile)[65] = (unsigned char(*)[65])smem;
    const float* arow = adj + (size_t)bm * N_ * N_;
#pragma unroll
    for (int k = 0; k < 16; ++k) {
      int idx = k * 256 + tid;
      int sl = idx >> 6, dl = idx & 63;
      int s = s0 + sl, d = d0 + dl;
      unsigned char v = 0;
      if (s < nn && d < nn && s < N_ && d < N_)
        v = (arow[(size_t)s * N_ + d] > THRESH_) ? 1 : 0;
      tile[sl][dl] = v;
    }
    __syncthreads();
    int w = tid >> 6, lane = tid & 63;
#pragma unroll
    for (int j = 0; j < 16; ++j) {
      int dl = w * 16 + j;
      bool act = tile[lane][dl] != 0;
      unsigned long long word = __ballot(act);
      int d = d0 + dl;
      if (lane == 0 && d < N_)
        maskW[((size_t)bm * N_ + d) * NW + bx] = word;
    }
    return;
  }
  bi -= 5120;
  if (bi < 80) {  // fc1 (M, FIN, HD) -> (M, HD, FIN) hi/lo
    int kx = bi % 2, ny = (bi / 2) % 8, z = bi / 16;
    splitT_body(fc1 + (size_t)z * FIN * HD, fc1Th + (size_t)z * HD * FIN,
                fc1Tl + (size_t)z * HD * FIN, FIN, HD, kx * 32, ny * 32, smem);
    return;
  }
  bi -= 80;
  if (bi < 320) {  // fc2 (M, HD, HD) -> (M, HD, HD)T hi/lo
    int kx = bi % 8, ny = (bi / 8) % 8, z = bi / 64;
    splitT_body(fc2 + (size_t)z * HD * HD, fc2Th + (size_t)z * HD * HD,
                fc2Tl + (size_t)z * HD * HD, HD, HD, kx * 32, ny * 32, smem);
    return;
  }
  bi -= 320;
  if (bi < 32) {  // sW1_1 (HD, SH) -> (SH, HD) hi/lo
    int kx = bi % 8, ny = bi / 8;
    splitT_body(sW1_1, sW1Th1, sW1Tl1, HD, SH, kx * 32, ny * 32, smem);
    return;
  }
  bi -= 32;
  {  // sW1_2
    int kx = bi % 8, ny = bi / 8;
    splitT_body(sW1_2, sW1Th2, sW1Tl2, HD, SH, kx * 32, ny * 32, smem);
  }
}

// ---------------------------------------------------------------------------
// Split-bf16 MFMA GEMM (feat) with FUSED el/er epilogue.
// A fp32 (in-register hi/lo split), B pre-transposed hi/lo, 3 mfma/product.
// Writes ONLY bf16 feat (fp32 copy was dead) + el/er from accumulators.
// ---------------------------------------------------------------------------
__global__ __launch_bounds__(256) void gemm_mfma3(
    const float* __restrict__ A, int Mz, size_t aZ,
    const u16* __restrict__ Bh, const u16* __restrict__ Bl, size_t bZ,
    u16* __restrict__ Cbf, size_t cZ,
    int Mrows, int K, int Nc,
    const float* __restrict__ al, const float* __restrict__ ar,
    float* __restrict__ el, float* __restrict__ er) {
  __shared__ u16 sAh[64][40], sAl[64][40], sBh[64][40], sBl[64][40];
  __shared__ float elbuf[64][2], erbuf[64][2];
  int z = blockIdx.z;
  int b = z / Mz, m = z % Mz;
  const float* Ab = A + (size_t)b * aZ;
  const u16* Bhb = Bh + (size_t)m * bZ;
  const u16* Blb = Bl + (size_t)m * bZ;
  u16* Cfb = Cbf + (size_t)z * cZ;
  int row0 = blockIdx.x * 64, col0 = blockIdx.y * 64;
  int tid = threadIdx.x;
  int arow = tid >> 2, akq = (tid & 3) * 8;
  int wid = tid >> 6, lane = tid & 63;
  int wr = (wid >> 1) * 32, wc = (wid & 1) * 32;
  int lrow = lane & 15, kseg = (lane >> 4) * 8;
  f32x4 zero4 = {0.f, 0.f, 0.f, 0.f};
  f32x4 acc[2][2];
  acc[0][0] = zero4; acc[0][1] = zero4; acc[1][0] = zero4; acc[1][1] = zero4;
  for (int k0 = 0; k0 < K; k0 += 32) {
    float4 a0 = make_float4(0.f, 0.f, 0.f, 0.f), a1 = a0;
    int gr = row0 + arow;
    if (gr < Mrows) {
      const float* ap = Ab + (size_t)gr * K + k0 + akq;
      a0 = *(const float4*)ap;
      a1 = *(const float4*)(ap + 4);
    }
    us8 hv, lv;
    {
      u16 th, tl;
      split2(a0.x, th, tl); hv[0] = th; lv[0] = tl;
      split2(a0.y, th, tl); hv[1] = th; lv[1] = tl;
      split2(a0.z, th, tl); hv[2] = th; lv[2] = tl;
      split2(a0.w, th, tl); hv[3] = th; lv[3] = tl;
      split2(a1.x, th, tl); hv[4] = th; lv[4] = tl;
      split2(a1.y, th, tl); hv[5] = th; lv[5] = tl;
      split2(a1.z, th, tl); hv[6] = th; lv[6] = tl;
      split2(a1.w, th, tl); hv[7] = th; lv[7] = tl;
    }
    *(us8*)&sAh[arow][akq] = hv;
    *(us8*)&sAl[arow][akq] = lv;
    us8 bv = *(const us8*)(Bhb + (size_t)(col0 + arow) * K + k0 + akq);
    us8 blv = *(const us8*)(Blb + (size_t)(col0 + arow) * K + k0 + akq);
    *(us8*)&sBh[arow][akq] = bv;
    *(us8*)&sBl[arow][akq] = blv;
    __syncthreads();
    s16x8 aH[2], aL[2], bH[2], bL[2];
#pragma unroll
    for (int i = 0; i < 2; ++i) {
      aH[i] = *(const s16x8*)&sAh[wr + 16 * i + lrow][kseg];
      aL[i] = *(const s16x8*)&sAl[wr + 16 * i + lrow][kseg];
      bH[i] = *(const s16x8*)&sBh[wc + 16 * i + lrow][kseg];
      bL[i] = *(const s16x8*)&sBl[wc + 16 * i + lrow][kseg];
    }
#pragma unroll
    for (int i = 0; i < 2; ++i)
#pragma unroll
      for (int j = 0; j < 2; ++j) {
        acc[i][j] = __builtin_amdgcn_mfma_f32_16x16x32_bf16(aH[i], bH[j], acc[i][j], 0, 0, 0);
        acc[i][j] = __builtin_amdgcn_mfma_f32_16x16x32_bf16(aH[i], bL[j], acc[i][j], 0, 0, 0);
        acc[i][j] = __builtin_amdgcn_mfma_f32_16x16x32_bf16(aL[i], bH[j], acc[i][j], 0, 0, 0);
      }
    __syncthreads();
  }
  // ---- C write (bf16 only) ----
#pragma unroll
  for (int i = 0; i < 2; ++i)
#pragma unroll
    for (int j = 0; j < 2; ++j) {
      int ccol = col0 + wc + 16 * j + lrow;
#pragma unroll
      for (int r = 0; r < 4; ++r) {
        int crow = row0 + wr + 16 * i + (lane >> 4) * 4 + r;
        if (crow < Mrows)
          Cfb[(size_t)crow * Nc + ccol] = bf16_bits(acc[i][j][r]);
      }
    }
  // ---- fused el/er epilogue (this block's 64 cols == one head) ----
  float alv0 = al[m * HD + col0 + wc + lrow];
  float alv1 = al[m * HD + col0 + wc + 16 + lrow];
  float arv0 = ar[m * HD + col0 + wc + lrow];
  float arv1 = ar[m * HD + col0 + wc + 16 + lrow];
#pragma unroll
  for (int i = 0; i < 2; ++i)
#pragma unroll
    for (int r = 0; r < 4; ++r) {
      float pl = acc[i][0][r] * alv0 + acc[i][1][r] * alv1;
      float pr = acc[i][0][r] * arv0 + acc[i][1][r] * arv1;
#pragma unroll
      for (int s = 1; s < 16; s <<= 1) {
        pl += __shfl_xor(pl, s, 64);
        pr += __shfl_xor(pr, s, 64);
      }
      if (lrow == 0) {
        int rl = wr + 16 * i + (lane >> 4) * 4 + r;
        elbuf[rl][wc >> 5] = pl;
        erbuf[rl][wc >> 5] = pr;
      }
    }
  __syncthreads();
  if (tid < 64) {
    int grow = row0 + tid;
    if (grow < Mrows) {
      int h = col0 >> 6;
      size_t bmN = (size_t)(b * M_ + m) * N_;
      el[(bmN + grow) * H_ + h] = elbuf[tid][0] + elbuf[tid][1];
      er[(bmN + grow) * H_ + h] = erbuf[tid][0] + erbuf[tid][1];
    }
  }
}

// ---------------------------------------------------------------------------
// GAT aggregation: one wave per destination, barrier-free, direct exp.
// bf16 feat rows; ulonglong2 mask reads; 4-edge batched loop; XCD swizzle.
// Writes ONLY bf16 z (fp32 copy was dropped). u16 slist (8 KB LDS).
// ---------------------------------------------------------------------------
__global__ __launch_bounds__(256) void gat_agg(
    const unsigned long long* __restrict__ maskW, const u16* __restrict__ featbf,
    const float* __restrict__ el, const float* __restrict__ er,
    const float* __restrict__ gb, u16* __restrict__ zbh,
    float* __restrict__ psum) {
  int wid = threadIdx.x >> 6, lane = threadIdx.x & 63;
  const int NWGQ = (B_ * M_ * N_ / 4) / 8;  // 625
  int orig = blockIdx.x;
  if (orig == 0 && threadIdx.x < 8) psum[threadIdx.x] = 0.f;
  int bid = (orig & 7) * NWGQ + (orig >> 3);  // XCD-chunked, bijective
  int gw = bid * 4 + wid;
  int d = gw % N_, bm = gw / N_;
  int m = bm % M_, b = bm / M_;
  __shared__ u16 slist_all[4][1032];
  u16* slist = slist_all[wid];

  const unsigned long long* mrow = maskW + ((size_t)bm * N_ + d) * NW;
  int cnt = 0;
#pragma unroll
  for (int q = 0; q < NW / 2; ++q) {
    ulonglong2 wp = *(const ulonglong2*)(mrow + q * 2);
    unsigned long long w0 = wp.x, w1 = wp.y;
    if (w0) {
      if ((w0 >> lane) & 1ull) {
        int pos = cnt + (int)__popcll(w0 & ((1ull << lane) - 1ull));
        slist[pos] = (u16)(q * 128 + lane);
      }
      cnt += (int)__popcll(w0);
    }
    if (w1) {
      if ((w1 >> lane) & 1ull) {
        int pos = cnt + (int)__popcll(w1 & ((1ull << lane) - 1ull));
        slist[pos] = (u16)(q * 128 + 64 + lane);
      }
      cnt += (int)__popcll(w1);
    }
  }

  int h = lane >> 4;
  float4 bias4 = *(const float4*)(gb + m * HD + lane * 4);
  size_t zoff = ((size_t)(b * N_ + d) * M_ + m) * HD + lane * 4;
  float4 o;
  if (cnt == 0) {
    o.x = bias4.x > 0.f ? bias4.x : (__expf(bias4.x) - 1.f);
    o.y = bias4.y > 0.f ? bias4.y : (__expf(bias4.y) - 1.f);
    o.z = bias4.z > 0.f ? bias4.z : (__expf(bias4.z) - 1.f);
    o.w = bias4.w > 0.f ? bias4.w : (__expf(bias4.w) - 1.f);
  } else {
    if (lane < 4) slist[cnt + lane] = slist[0];  // pad to safe multiple of 4
    size_t bmN = (size_t)bm * N_;
    float erv = er[(bmN + d) * H_ + h];
    const float* elb = el + bmN * H_;
    const u16* fbb = featbf + bmN * HD;
    int lane4 = lane * 4;
    float den0 = 0.f, den1 = 0.f, den2 = 0.f, den3 = 0.f;
    f32x4 A0 = {0.f, 0.f, 0.f, 0.f}, A1 = A0, A2 = A0, A3 = A0;
    for (int i = 0; i < cnt; i += 4) {
      ushort4 s4 = *(const ushort4*)&slist[i];
      float e0 = elb[(size_t)s4.x * H_ + h];
      float e1 = elb[(size_t)s4.y * H_ + h];
      float e2 = elb[(size_t)s4.z * H_ + h];
      float e3 = elb[(size_t)s4.w * H_ + h];
      ushort4 g0 = *(const ushort4*)(fbb + (size_t)s4.x * HD + lane4);
      ushort4 g1 = *(const ushort4*)(fbb + (size_t)s4.y * HD + lane4);
      ushort4 g2 = *(const ushort4*)(fbb + (size_t)s4.z * HD + lane4);
      ushort4 g3 = *(const ushort4*)(fbb + (size_t)s4.w * HD + lane4);
      float v0 = e0 + erv; v0 = v0 > 0.f ? v0 : 0.2f * v0;
      float v1 = e1 + erv; v1 = v1 > 0.f ? v1 : 0.2f * v1;
      float v2 = e2 + erv; v2 = v2 > 0.f ? v2 : 0.2f * v2;
      float v3 = e3 + erv; v3 = v3 > 0.f ? v3 : 0.2f * v3;
      float w0 = __expf(v0);
      float w1 = __expf(v1) * ((i + 1 < cnt) ? 1.f : 0.f);
      float w2 = __expf(v2) * ((i + 2 < cnt) ? 1.f : 0.f);
      float w3 = __expf(v3) * ((i + 3 < cnt) ? 1.f : 0.f);
      f32x4 f0 = {b2f(g0.x), b2f(g0.y), b2f(g0.z), b2f(g0.w)};
      f32x4 f1 = {b2f(g1.x), b2f(g1.y), b2f(g1.z), b2f(g1.w)};
      f32x4 f2 = {b2f(g2.x), b2f(g2.y), b2f(g2.z), b2f(g2.w)};
      f32x4 f3 = {b2f(g3.x), b2f(g3.y), b2f(g3.z), b2f(g3.w)};
      den0 += w0; den1 += w1; den2 += w2; den3 += w3;
      A0 += w0 * f0; A1 += w1 * f1; A2 += w2 * f2; A3 += w3 * f3;
    }
    float den = (den0 + den1) + (den2 + den3);
    f32x4 A = (A0 + A1) + (A2 + A3);
    float inv = 1.f / den;
    o.x = A[0] * inv + bias4.x;
    o.y = A[1] * inv + bias4.y;
    o.z = A[2] * inv + bias4.z;
    o.w = A[3] * inv + bias4.w;
    o.x = o.x > 0.f ? o.x : (__expf(o.x) - 1.f);
    o.y = o.y > 0.f ? o.y : (__expf(o.y) - 1.f);
    o.z = o.z > 0.f ? o.z : (__expf(o.z) - 1.f);
    o.w = o.w > 0.f ? o.w : (__expf(o.w) - 1.f);
  }
  ushort4 hh;
  hh.x = bf16_bits(o.x);
  hh.y = bf16_bits(o.y);
  hh.z = bf16_bits(o.z);
  hh.w = bf16_bits(o.w);
  *(ushort4*)(zbh + zoff) = hh;
}

// ---------------------------------------------------------------------------
// Semantic GEMM with fused masked per-metapath reduction:
// psum[m] += sum_{rows of m, n<nn} tanh(A@W1+b1)[row,:] . W2
// ---------------------------------------------------------------------------
__global__ __launch_bounds__(256) void gemm_sem(
    const u16* __restrict__ Ah, const u16* __restrict__ Bh,
    const float* __restrict__ bias, const float* __restrict__ W2,
    float* __restrict__ psum, const int* __restrict__ node_nums, int Mrows) {
  __shared__ u16 sA[64][40], sB[64][40];
  __shared__ float redm[M_];
  int row0 = blockIdx.x * 64, col0 = blockIdx.y * 64;
  int tid = threadIdx.x;
  int arow = tid >> 2, akq = (tid & 3) * 8;
  int wid = tid >> 6, lane = tid & 63;
  int wr = (wid >> 1) * 32, wc = (wid & 1) * 32;
  int lrow = lane & 15, kseg = (lane >> 4) * 8;
  if (tid < M_) redm[tid] = 0.f;
  f32x4 zero4 = {0.f, 0.f, 0.f, 0.f};
  f32x4 acc[2][2];
  acc[0][0] = zero4; acc[0][1] = zero4; acc[1][0] = zero4; acc[1][1] = zero4;
  for (int k0 = 0; k0 < HD; k0 += 32) {
    us8 av = {0, 0, 0, 0, 0, 0, 0, 0};
    int gr = row0 + arow;
    if (gr < Mrows) av = *(const us8*)(Ah + (size_t)gr * HD + k0 + akq);
    *(us8*)&sA[arow][akq] = av;
    us8 bv = *(const us8*)(Bh + (size_t)(col0 + arow) * HD + k0 + akq);
    *(us8*)&sB[arow][akq] = bv;
    __syncthreads();
    s16x8 aH[2], bH[2];
#pragma unroll
    for (int i = 0; i < 2; ++i) {
      aH[i] = *(const s16x8*)&sA[wr + 16 * i + lrow][kseg];
      bH[i] = *(const s16x8*)&sB[wc + 16 * i + lrow][kseg];
    }
#pragma unroll
    for (int i = 0; i < 2; ++i)
#pragma unroll
      for (int j = 0; j < 2; ++j)
        acc[i][j] = __builtin_amdgcn_mfma_f32_16x16x32_bf16(aH[i], bH[j], acc[i][j], 0, 0, 0);
    __syncthreads();
  }
  int nn0 = node_nums[0], nn1 = node_nums[1], nn2 = node_nums[2], nn3 = node_nums[3];
#pragma unroll
  for (int i = 0; i < 2; ++i) {
#pragma unroll
    for (int r = 0; r < 4; ++r) {
      float part = 0.f;
#pragma unroll
      for (int j = 0; j < 2; ++j) {
        int ccol = col0 + wc + 16 * j + lrow;
        float v = tanhf(acc[i][j][r] + bias[ccol]);
        part += v * W2[ccol];
      }
#pragma unroll
      for (int s = 1; s < 16; s <<= 1) part += __shfl_xor(part, s, 64);
      int crow = row0 + wr + 16 * i + (lane >> 4) * 4 + r;
      if (lrow == 0 && crow < Mrows) {
        int m = crow % M_;
        int bn = crow / M_;
        int bb = bn / N_, n = bn % N_;
        int nn = (bb == 0) ? nn0 : (bb == 1) ? nn1 : (bb == 2) ? nn2 : nn3;
        if (n < nn) atomicAdd(&redm[m], part);
      }
    }
  }
  __syncthreads();
  if (tid < M_) atomicAdd(&psum[tid], redm[tid]);
}

// ---------------------------------------------------------------------------
// h[b,n,hd] = sum_m beta[m] * z[b,n,m,hd]; z read as bf16, h written fp32.
// Vectorized 4 elems/thread.
// ---------------------------------------------------------------------------
__global__ __launch_bounds__(256) void sem_combine(const u16* __restrict__ zbh,
                                                   const float* __restrict__ psum,
                                                   const int* __restrict__ node_nums,
                                                   float* __restrict__ hout) {
  float bb[M_];
  beta_from_sums(psum, node_nums, bb);
  int q = blockIdx.x * 256 + threadIdx.x;  // over B*N*HD/4
  int hd4 = (q & 63) * 4;
  int bn = q >> 6;
  const u16* zr = zbh + (size_t)bn * M_ * HD + hd4;
  f32x4 acc = {0.f, 0.f, 0.f, 0.f};
#pragma unroll
  for (int m = 0; m < M_; ++m) {
    ushort4 g = *(const ushort4*)(zr + m * HD);
    f32x4 f = {b2f(g.x), b2f(g.y), b2f(g.z), b2f(g.w)};
    acc += bb[m] * f;
  }
  *(f32x4*)(hout + (size_t)bn * HD + hd4) = acc;
}

// ---------------------------------------------------------------------------
// Layer-2 combine fused with prediction head: one wave per row. z read bf16.
// ---------------------------------------------------------------------------
__global__ __launch_bounds__(256) void sem_combine_pred(
    const u16* __restrict__ zbh, const float* __restrict__ psum,
    const int* __restrict__ node_nums, const float* __restrict__ W,
    const float* __restrict__ bias, float* __restrict__ out) {
  float bb[M_];
  beta_from_sums(psum, node_nums, bb);
  int row = blockIdx.x * 4 + (threadIdx.x >> 6);
  int lane = threadIdx.x & 63;
  int b = row / N_, n = row % N_;
  const u16* zr = zbh + (size_t)row * M_ * HD + lane * 4;
  float hx = 0.f, hy = 0.f, hz = 0.f, hw = 0.f;
#pragma unroll
  for (int m = 0; m < M_; ++m) {
    ushort4 g = *(const ushort4*)(zr + m * HD);
    hx += bb[m] * b2f(g.x);
    hy += bb[m] * b2f(g.y);
    hz += bb[m] * b2f(g.z);
    hw += bb[m] * b2f(g.w);
  }
  int k = lane * 4;
  float res[OUTD];
#pragma unroll
  for (int o = 0; o < OUTD; ++o) {
    float v = hx * W[(k + 0) * OUTD + o] + hy * W[(k + 1) * OUTD + o] +
              hz * W[(k + 2) * OUTD + o] + hw * W[(k + 3) * OUTD + o];
#pragma unroll
    for (int s = 1; s < 64; s <<= 1) v += __shfl_xor(v, s, 64);
    res[o] = v;
  }
  if (lane == 0) {
    float nm = (n < node_nums[b]) ? 1.f : 0.f;
#pragma unroll
    for (int o = 0; o < OUTD; ++o)
      out[(size_t)row * OUTD + o] = (res[o] + bias[o]) * nm;
  }
}

extern "C" void kernel_launch(void* const* d_in, const int* in_sizes, int n_in,
                              void* d_out, int out_size, void* d_ws, size_t ws_size,
                              hipStream_t stream) {
  const float* x = (const float*)d_in[0];
  const float* adj = (const float*)d_in[1];
  const int* node_nums = (const int*)d_in[2];
  const float* fc1 = (const float*)d_in[3];
  const float* al1 = (const float*)d_in[4];
  const float* ar1 = (const float*)d_in[5];
  const float* gb1 = (const float*)d_in[6];
  const float* sW1_1 = (const float*)d_in[7];
  const float* sb1_1 = (const float*)d_in[8];
  const float* sW2_1 = (const float*)d_in[9];
  const float* fc2 = (const float*)d_in[10];
  const float* al2 = (const float*)d_in[11];
  const float* ar2 = (const float*)d_in[12];
  const float* gb2 = (const float*)d_in[13];
  const float* sW1_2 = (const float*)d_in[14];
  const float* sb1_2 = (const float*)d_in[15];
  const float* sW2_2 = (const float*)d_in[16];
  const float* predW = (const float*)d_in[17];
  const float* predb = (const float*)d_in[18];
  float* out = (float*)d_out;

  char* ws = (char*)d_ws;
  size_t off = 0;
  unsigned long long* maskW = (unsigned long long*)(ws + off);
  off += (size_t)B_ * M_ * N_ * NW * 8;
  u16* featbf = (u16*)(ws + off); off += (size_t)B_ * M_ * N_ * HD * 2;
  float* el = (float*)(ws + off); off += (size_t)B_ * M_ * N_ * H_ * 4;
  float* er = (float*)(ws + off); off += (size_t)B_ * M_ * N_ * H_ * 4;
  u16* zbh = (u16*)(ws + off); off += (size_t)B_ * N_ * M_ * HD * 2;
  float* h1 = (float*)(ws + off); off += (size_t)B_ * N_ * HD * 4;
  float* psum = (float*)(ws + off); off += 64;
  u16* fc1Th = (u16*)(ws + off); off += (size_t)M_ * HD * FIN * 2;
  u16* fc1Tl = (u16*)(ws + off); off += (size_t)M_ * HD * FIN * 2;
  u16* fc2Th = (u16*)(ws + off); off += (size_t)M_ * HD * HD * 2;
  u16* fc2Tl = (u16*)(ws + off); off += (size_t)M_ * HD * HD * 2;
  u16* sW1Th1 = (u16*)(ws + off); off += (size_t)SH * HD * 2;
  u16* sW1Tl1 = (u16*)(ws + off); off += (size_t)SH * HD * 2;
  u16* sW1Th2 = (u16*)(ws + off); off += (size_t)SH * HD * 2;
  u16* sW1Tl2 = (u16*)(ws + off); off += (size_t)SH * HD * 2;

  const int ROWS = B_ * N_ * M_;  // 20000
  const int PREP_BLOCKS = 5120 + 80 + 320 + 32 + 32;  // 5584

  prep_all<<<dim3(PREP_BLOCKS), 256, 0, stream>>>(
      adj, node_nums, maskW, fc1, fc1Th, fc1Tl, fc2, fc2Th, fc2Tl,
      sW1_1, sW1Th1, sW1Tl1, sW1_2, sW1Th2, sW1Tl2);

  // ---- layer 1 ----
  gemm_mfma3<<<dim3(16, HD / 64, B_ * M_), 256, 0, stream>>>(
      x, M_, (size_t)M_ * N_ * FIN, fc1Th, fc1Tl, (size_t)HD * FIN,
      featbf, (size_t)N_ * HD, N_, FIN, HD, al1, ar1, el, er);
  gat_agg<<<dim3(ROWS / 4), 256, 0, stream>>>(maskW, featbf, el, er, gb1, zbh, psum);
  gemm_sem<<<dim3((ROWS + 63) / 64, SH / 64), 256, 0, stream>>>(
      zbh, sW1Th1, sb1_1, sW2_1, psum, node_nums, ROWS);
  sem_combine<<<dim3(B_ * N_ * HD / 1024), 256, 0, stream>>>(zbh, psum, node_nums, h1);

  // ---- layer 2 ----
  gemm_mfma3<<<dim3(16, HD / 64, B_ * M_), 256, 0, stream>>>(
      h1, M_, (size_t)N_ * HD, fc2Th, fc2Tl, (size_t)HD * HD,
      featbf, (size_t)N_ * HD, N_, HD, HD, al2, ar2, el, er);
  gat_agg<<<dim3(ROWS / 4), 256, 0, stream>>>(maskW, featbf, el, er, gb2, zbh, psum);
  gemm_sem<<<dim3((ROWS + 63) / 64, SH / 64), 256, 0, stream>>>(
      zbh, sW1Th2, sb1_2, sW2_2, psum, node_nums, ROWS);
  sem_combine_pred<<<dim3(B_ * N_ / 4), 256, 0, stream>>>(
      zbh, psum, node_nums, predW, predb, out);
}